// Round 3
// baseline (929.149 us; speedup 1.0000x reference)
//
#include <hip/hip_runtime.h>
#include <hip/hip_bf16.h>
#include <math.h>

#define B_ 2
#define T_ 2048
#define D_ 1024
#define H_ 16
#define DH_ 64
#define M_ (B_*T_)   // 4096 rows
#define NC_ 32       // chunks per sequence (T/64)
#define CS_ 64       // chunk size
#define NCH_ (B_*H_*NC_)  // 1024 chunk-heads

typedef __attribute__((ext_vector_type(4))) float floatx4;
typedef __attribute__((ext_vector_type(8))) short short8;

__device__ __forceinline__ ushort f2bf(float f) {
  union { float f; unsigned u; } c; c.f = f;
  unsigned r = (c.u + 0x7FFFu + ((c.u >> 16) & 1u)) >> 16;  // RNE
  return (ushort)r;
}
__device__ __forceinline__ float siluf(float u) {
  return u / (1.f + __expf(-u));
}
__device__ __forceinline__ float f4get(const float4& v, int j) {
  return j == 0 ? v.x : j == 1 ? v.y : j == 2 ? v.z : v.w;
}

// ---------- cast f32 -> bf16, n4 = n/4 ----------
__global__ void cast_kernel(const float* __restrict__ in, ushort* __restrict__ out, int n4) {
  int i = blockIdx.x * blockDim.x + threadIdx.x;
  if (i >= n4) return;
  float4 v = ((const float4*)in)[i];
  ushort4 o;
  o.x = f2bf(v.x); o.y = f2bf(v.y); o.z = f2bf(v.z); o.w = f2bf(v.w);
  ((ushort4*)out)[i] = o;
}

// ---------- transpose + cast: W[K][N] f32 -> Wt[N][K] bf16 ----------
__global__ void transpose_cast_kernel(const float* __restrict__ W, ushort* __restrict__ Wt,
                                      int K, int N) {
  __shared__ float tile[32][33];
  int tx = threadIdx.x, ty = threadIdx.y;
  int n0 = blockIdx.x * 32, k0 = blockIdx.y * 32;
  #pragma unroll
  for (int i = 0; i < 32; i += 8)
    tile[ty + i][tx] = W[(size_t)(k0 + ty + i) * N + n0 + tx];
  __syncthreads();
  #pragma unroll
  for (int i = 0; i < 32; i += 8)
    Wt[(size_t)(n0 + ty + i) * K + k0 + tx] = f2bf(tile[tx][ty + i]);
}

// ---------- m97-style bf16 MFMA GEMM: C[M][N] = A[M][K]*B[K][N], Bt = B^T [N][K] ----------
// 128x128 tile, 256 threads (4 waves in 2x2 quadrants), BK=32, global_load_lds width 16.
__global__ __launch_bounds__(256) void gemm128_kernel(
    const ushort* __restrict__ A, const ushort* __restrict__ Bt,
    float* __restrict__ C, int M, int N, int K) {
  __shared__ ushort lA[128 * 32];   // [row][32 k] bf16, no pad (global_load_lds needs contiguity)
  __shared__ ushort lB[128 * 32];
  int tid = threadIdx.x;
  int wave = tid >> 6, lane = tid & 63;
  int wm = wave >> 1, wn = wave & 1;
  int m16 = lane & 15, q4 = lane >> 4;
  int bm = blockIdx.x, bn = blockIdx.y;
  floatx4 acc[4][4] = {};
  int srow = tid >> 2;   // 0..63
  int sk8 = tid & 3;     // 16B chunk in row
  const ushort* Ag = A + (size_t)(bm * 128 + srow) * K + sk8 * 8;
  const ushort* Bg = Bt + (size_t)(bn * 128 + srow) * K + sk8 * 8;
  ushort* lAp = lA + tid * 8;   // wave-uniform base + lane*16B
  ushort* lBp = lB + tid * 8;
  for (int k0 = 0; k0 < K; k0 += 32) {
    __builtin_amdgcn_global_load_lds(
        (const __attribute__((address_space(1))) void*)(Ag + k0),
        (__attribute__((address_space(3))) void*)lAp, 16, 0, 0);
    __builtin_amdgcn_global_load_lds(
        (const __attribute__((address_space(1))) void*)(Ag + (size_t)64 * K + k0),
        (__attribute__((address_space(3))) void*)(lAp + 2048), 16, 0, 0);
    __builtin_amdgcn_global_load_lds(
        (const __attribute__((address_space(1))) void*)(Bg + k0),
        (__attribute__((address_space(3))) void*)lBp, 16, 0, 0);
    __builtin_amdgcn_global_load_lds(
        (const __attribute__((address_space(1))) void*)(Bg + (size_t)64 * K + k0),
        (__attribute__((address_space(3))) void*)(lBp + 2048), 16, 0, 0);
    __syncthreads();
    short8 af[4], bf[4];
    #pragma unroll
    for (int i = 0; i < 4; i++) {
      af[i] = *(short8*)&lA[(wm * 64 + i * 16 + m16) * 32 + q4 * 8];
      bf[i] = *(short8*)&lB[(wn * 64 + i * 16 + m16) * 32 + q4 * 8];
    }
    #pragma unroll
    for (int mi = 0; mi < 4; mi++)
      #pragma unroll
      for (int nj = 0; nj < 4; nj++)
        acc[mi][nj] = __builtin_amdgcn_mfma_f32_16x16x32_bf16(af[mi], bf[nj], acc[mi][nj], 0, 0, 0);
    __syncthreads();
  }
  float* Cb = C + (size_t)(bm * 128) * N + bn * 128;
  #pragma unroll
  for (int mi = 0; mi < 4; mi++) {
    #pragma unroll
    for (int nj = 0; nj < 4; nj++) {
      #pragma unroll
      for (int i = 0; i < 4; i++) {
        int row = wm * 64 + mi * 16 + q4 * 4 + i;
        int col = wn * 64 + nj * 16 + m16;
        Cb[(size_t)row * N + col] = acc[mi][nj][i];
      }
    }
  }
}

// ---------- beta = sigmoid(x @ Wb) ----------
__global__ __launch_bounds__(256) void beta_kernel(const float* __restrict__ x,
                                                   const float* __restrict__ Wb,
                                                   float* __restrict__ beta) {
  __shared__ __align__(16) float xs[D_];
  int row = blockIdx.x;
  int tid = threadIdx.x;
  ((float4*)xs)[tid] = ((const float4*)(x + (size_t)row * D_))[tid];
  __syncthreads();
  int h = tid >> 4;
  int seg = tid & 15;
  float s = 0.f;
  #pragma unroll 8
  for (int i = 0; i < 64; i++) {
    int kk = seg * 64 + i;
    s += xs[kk] * Wb[(size_t)kk * H_ + h];
  }
  #pragma unroll
  for (int off = 8; off; off >>= 1) s += __shfl_down(s, off, 16);
  if (seg == 0) beta[(size_t)row * H_ + h] = 1.f / (1.f + __expf(-s));
}

// ---------- causal depthwise conv(K=4) + silu, l2norm for q,k ----------
__global__ __launch_bounds__(256) void conv_kernel(
    const float* __restrict__ qpre, const float* __restrict__ kpre, const float* __restrict__ vpre,
    const float* __restrict__ cq, const float* __restrict__ ck, const float* __restrict__ cv,
    float* __restrict__ qo, float* __restrict__ ko, float* __restrict__ vo) {
  int row = blockIdx.x;
  int t = row & (T_ - 1);
  int tid = threadIdx.x;
  int c0 = tid * 4;
  float4 zf = {0.f, 0.f, 0.f, 0.f};
  float4 xq[4], xk[4], xv[4];
  #pragma unroll
  for (int i = 0; i < 4; i++) {
    int tt = t - 3 + i;
    if (tt >= 0) {
      xq[i] = *(const float4*)(qpre + (size_t)(row - 3 + i) * D_ + c0);
      xk[i] = *(const float4*)(kpre + (size_t)(row - 3 + i) * D_ + c0);
      xv[i] = *(const float4*)(vpre + (size_t)(row - 3 + i) * D_ + c0);
    } else { xq[i] = zf; xk[i] = zf; xv[i] = zf; }
  }
  float yq[4], yk[4], yv[4];
  float pq = 0.f, pk = 0.f;
  #pragma unroll
  for (int j = 0; j < 4; j++) {
    float4 wq = ((const float4*)cq)[c0 + j];
    float4 wk = ((const float4*)ck)[c0 + j];
    float4 wv = ((const float4*)cv)[c0 + j];
    float sq = 0.f, sk = 0.f, sv = 0.f;
    #pragma unroll
    for (int i = 0; i < 4; i++) {
      sq += f4get(wq, i) * f4get(xq[i], j);
      sk += f4get(wk, i) * f4get(xk[i], j);
      sv += f4get(wv, i) * f4get(xv[i], j);
    }
    yq[j] = siluf(sq); yk[j] = siluf(sk); yv[j] = siluf(sv);
    pq += yq[j] * yq[j]; pk += yk[j] * yk[j];
  }
  #pragma unroll
  for (int off = 1; off < 16; off <<= 1) {
    pq += __shfl_xor(pq, off, 16);
    pk += __shfl_xor(pk, off, 16);
  }
  float rq = rsqrtf(pq + 1e-6f), rk = rsqrtf(pk + 1e-6f);
  float4 oq = {yq[0]*rq, yq[1]*rq, yq[2]*rq, yq[3]*rq};
  float4 okk = {yk[0]*rk, yk[1]*rk, yk[2]*rk, yk[3]*rk};
  float4 ov = {yv[0], yv[1], yv[2], yv[3]};
  *(float4*)(qo + (size_t)row * D_ + c0) = oq;
  *(float4*)(ko + (size_t)row * D_ + c0) = okk;
  *(float4*)(vo + (size_t)row * D_ + c0) = ov;
}

// ================= chunked delta rule =================
// prep1: per chunk-head, A = strict_tril(diag(b) K K^T); solve (I+A)Wk = diag(b)K,
//        (I+A)U0 = diag(b)V by right-looking forward substitution.
__global__ __launch_bounds__(256) void prep1_kernel(
    const float* __restrict__ kn, const float* __restrict__ vn,
    const float* __restrict__ beta,
    float* __restrict__ Wkbuf, float* __restrict__ U0buf) {
  __shared__ float Ksh[64][68];
  __shared__ float AT[64 * 64];   // AT[s][t] = A[t][s]
  __shared__ float Xs[64][68];
  __shared__ float bsh[64];
  int ch = blockIdx.x;
  int b = ch >> 9, h = (ch >> 5) & 15, c = ch & 31;
  int tid = threadIdx.x;
  int t = tid >> 2, seg = tid & 3;
  const float* krow = kn + ((size_t)(b * T_ + c * 64 + t)) * D_ + h * 64;
  #pragma unroll
  for (int g = 0; g < 4; g++)
    *(float4*)&Ksh[t][seg * 16 + 4 * g] = *(const float4*)&krow[seg * 16 + 4 * g];
  if (tid < 64) bsh[tid] = beta[((size_t)(b * T_ + c * 64 + tid)) * H_ + h];
  __syncthreads();
  {
    int s0 = seg * 16;
    float acc[16];
    #pragma unroll
    for (int r = 0; r < 16; r++) acc[r] = 0.f;
    for (int d4 = 0; d4 < 16; d4++) {
      float4 kt = *(float4*)&Ksh[t][d4 * 4];
      #pragma unroll
      for (int r = 0; r < 16; r++) {
        float4 ks = *(float4*)&Ksh[s0 + r][d4 * 4];
        acc[r] += kt.x * ks.x + kt.y * ks.y + kt.z * ks.z + kt.w * ks.w;
      }
    }
    float bt = bsh[t];
    #pragma unroll
    for (int r = 0; r < 16; r++) {
      int s = s0 + r;
      AT[s * 64 + t] = (t > s) ? bt * acc[r] : 0.f;
    }
  }
  __syncthreads();
  for (int pass = 0; pass < 2; pass++) {
    float bt = bsh[t];
    if (pass == 0) {
      #pragma unroll
      for (int g = 0; g < 4; g++) {
        float4 kv = *(float4*)&Ksh[t][seg * 16 + 4 * g];
        float4 xv = {bt * kv.x, bt * kv.y, bt * kv.z, bt * kv.w};
        *(float4*)&Xs[t][seg * 16 + 4 * g] = xv;
      }
    } else {
      const float* vrow = vn + ((size_t)(b * T_ + c * 64 + t)) * D_ + h * 64;
      #pragma unroll
      for (int g = 0; g < 4; g++) {
        float4 vv = *(const float4*)&vrow[seg * 16 + 4 * g];
        float4 xv = {bt * vv.x, bt * vv.y, bt * vv.z, bt * vv.w};
        *(float4*)&Xs[t][seg * 16 + 4 * g] = xv;
      }
    }
    __syncthreads();
    for (int i = 0; i < 63; i++) {
      if (t > i) {
        float a = AT[i * 64 + t];
        #pragma unroll
        for (int g = 0; g < 4; g++) {
          float4 xi = *(float4*)&Xs[i][seg * 16 + 4 * g];
          float4 xt = *(float4*)&Xs[t][seg * 16 + 4 * g];
          xt.x -= a * xi.x; xt.y -= a * xi.y; xt.z -= a * xi.z; xt.w -= a * xi.w;
          *(float4*)&Xs[t][seg * 16 + 4 * g] = xt;
        }
      }
      __syncthreads();
    }
    float* outb = (pass == 0) ? Wkbuf : U0buf;
    #pragma unroll
    for (int g = 0; g < 4; g++)
      *(float4*)&outb[(size_t)ch * 4096 + t * 64 + seg * 16 + 4 * g] =
          *(float4*)&Xs[t][seg * 16 + 4 * g];
    __syncthreads();
  }
}

// prep2a: L = tril(Q K^T) (incl diagonal)
__global__ __launch_bounds__(256) void prep2a_kernel(
    const float* __restrict__ qn, const float* __restrict__ kn,
    float* __restrict__ Lbuf) {
  __shared__ float Qsh[64][68];
  __shared__ float Ksh[64][68];
  int ch = blockIdx.x;
  int b = ch >> 9, h = (ch >> 5) & 15, c = ch & 31;
  int tid = threadIdx.x;
  int t = tid >> 2, seg = tid & 3;
  const float* qrow = qn + ((size_t)(b * T_ + c * 64 + t)) * D_ + h * 64;
  const float* krow = kn + ((size_t)(b * T_ + c * 64 + t)) * D_ + h * 64;
  #pragma unroll
  for (int g = 0; g < 4; g++) {
    *(float4*)&Qsh[t][seg * 16 + 4 * g] = *(const float4*)&qrow[seg * 16 + 4 * g];
    *(float4*)&Ksh[t][seg * 16 + 4 * g] = *(const float4*)&krow[seg * 16 + 4 * g];
  }
  __syncthreads();
  int s0 = seg * 16;
  float acc[16];
  #pragma unroll
  for (int r = 0; r < 16; r++) acc[r] = 0.f;
  for (int d4 = 0; d4 < 16; d4++) {
    float4 qt = *(float4*)&Qsh[t][d4 * 4];
    #pragma unroll
    for (int r = 0; r < 16; r++) {
      float4 ks = *(float4*)&Ksh[s0 + r][d4 * 4];
      acc[r] += qt.x * ks.x + qt.y * ks.y + qt.z * ks.z + qt.w * ks.w;
    }
  }
  #pragma unroll
  for (int g = 0; g < 4; g++) {
    float4 ov;
    ov.x = (s0 + 4*g + 0 <= t) ? acc[4*g+0] : 0.f;
    ov.y = (s0 + 4*g + 1 <= t) ? acc[4*g+1] : 0.f;
    ov.z = (s0 + 4*g + 2 <= t) ? acc[4*g+2] : 0.f;
    ov.w = (s0 + 4*g + 3 <= t) ? acc[4*g+3] : 0.f;
    *(float4*)&Lbuf[(size_t)ch * 4096 + t * 64 + s0 + 4 * g] = ov;
  }
}

// prep2b: O0 = L U0 ; Qeff = Q - L Wk (Qeff written in-place over qn)
__global__ __launch_bounds__(256) void prep2b_kernel(
    const float* __restrict__ Lbuf, const float* __restrict__ Wkbuf,
    const float* __restrict__ U0buf, float* qn,
    float* __restrict__ O0buf) {
  __shared__ float Lsh[64][68];
  __shared__ float Wksh[64][68];
  __shared__ float U0sh[64][68];
  int ch = blockIdx.x;
  int b = ch >> 9, h = (ch >> 5) & 15, c = ch & 31;
  int tid = threadIdx.x;
  int t = tid >> 2, seg = tid & 3;
  #pragma unroll
  for (int g = 0; g < 4; g++) {
    int o = t * 64 + seg * 16 + 4 * g;
    *(float4*)&Lsh[t][seg * 16 + 4 * g]  = *(const float4*)&Lbuf[(size_t)ch * 4096 + o];
    *(float4*)&Wksh[t][seg * 16 + 4 * g] = *(const float4*)&Wkbuf[(size_t)ch * 4096 + o];
    *(float4*)&U0sh[t][seg * 16 + 4 * g] = *(const float4*)&U0buf[(size_t)ch * 4096 + o];
  }
  __syncthreads();
  int j0 = seg * 16;
  float o0[16], lw[16];
  #pragma unroll
  for (int r = 0; r < 16; r++) { o0[r] = 0.f; lw[r] = 0.f; }
  for (int s = 0; s <= t; s++) {
    float l = Lsh[t][s];
    #pragma unroll
    for (int g = 0; g < 4; g++) {
      float4 u = *(float4*)&U0sh[s][j0 + 4 * g];
      float4 w = *(float4*)&Wksh[s][j0 + 4 * g];
      o0[4*g+0] += l * u.x; o0[4*g+1] += l * u.y; o0[4*g+2] += l * u.z; o0[4*g+3] += l * u.w;
      lw[4*g+0] += l * w.x; lw[4*g+1] += l * w.y; lw[4*g+2] += l * w.z; lw[4*g+3] += l * w.w;
    }
  }
  float* qrow = qn + ((size_t)(b * T_ + c * 64 + t)) * D_ + h * 64;
  #pragma unroll
  for (int g = 0; g < 4; g++) {
    float4 qv = *(const float4*)&qrow[j0 + 4 * g];
    qv.x -= lw[4*g+0]; qv.y -= lw[4*g+1]; qv.z -= lw[4*g+2]; qv.w -= lw[4*g+3];
    *(float4*)&qrow[j0 + 4 * g] = qv;
    float4 ov = {o0[4*g+0], o0[4*g+1], o0[4*g+2], o0[4*g+3]};
    *(float4*)&O0buf[(size_t)ch * 4096 + t * 64 + j0 + 4 * g] = ov;
  }
}

// prep2c: P = I - K^T Wk -> Pbuf; Z = K^T U0 -> written in-place over kn chunk
__global__ __launch_bounds__(256) void prep2c_kernel(
    float* kn, const float* __restrict__ Wkbuf,
    const float* __restrict__ U0buf, float* __restrict__ Pbuf) {
  __shared__ float Ksh[64][68];
  __shared__ float Wksh[64][68];
  __shared__ float U0sh[64][68];
  int ch = blockIdx.x;
  int b = ch >> 9, h = (ch >> 5) & 15, c = ch & 31;
  int tid = threadIdx.x;
  int t = tid >> 2, seg = tid & 3;
  const float* krow = kn + ((size_t)(b * T_ + c * 64 + t)) * D_ + h * 64;
  #pragma unroll
  for (int g = 0; g < 4; g++) {
    int o = t * 64 + seg * 16 + 4 * g;
    *(float4*)&Ksh[t][seg * 16 + 4 * g]  = *(const float4*)&krow[seg * 16 + 4 * g];
    *(float4*)&Wksh[t][seg * 16 + 4 * g] = *(const float4*)&Wkbuf[(size_t)ch * 4096 + o];
    *(float4*)&U0sh[t][seg * 16 + 4 * g] = *(const float4*)&U0buf[(size_t)ch * 4096 + o];
  }
  __syncthreads();
  int d = t;            // dk row
  int e0 = seg * 16;    // column block
  float accP[16], accZ[16];
  #pragma unroll
  for (int r = 0; r < 16; r++) { accP[r] = 0.f; accZ[r] = 0.f; }
  for (int s = 0; s < 64; s++) {
    float kv = Ksh[s][d];
    #pragma unroll
    for (int g = 0; g < 4; g++) {
      float4 w = *(float4*)&Wksh[s][e0 + 4 * g];
      float4 u = *(float4*)&U0sh[s][e0 + 4 * g];
      accP[4*g+0] += kv * w.x; accP[4*g+1] += kv * w.y; accP[4*g+2] += kv * w.z; accP[4*g+3] += kv * w.w;
      accZ[4*g+0] += kv * u.x; accZ[4*g+1] += kv * u.y; accZ[4*g+2] += kv * u.z; accZ[4*g+3] += kv * u.w;
    }
  }
  float* zrow = kn + ((size_t)(b * T_ + c * 64 + d)) * D_ + h * 64;
  #pragma unroll
  for (int g = 0; g < 4; g++) {
    float4 pv;
    pv.x = ((e0 + 4*g + 0) == d ? 1.f : 0.f) - accP[4*g+0];
    pv.y = ((e0 + 4*g + 1) == d ? 1.f : 0.f) - accP[4*g+1];
    pv.z = ((e0 + 4*g + 2) == d ? 1.f : 0.f) - accP[4*g+2];
    pv.w = ((e0 + 4*g + 3) == d ? 1.f : 0.f) - accP[4*g+3];
    *(float4*)&Pbuf[(size_t)ch * 4096 + d * 64 + e0 + 4 * g] = pv;
    float4 zv = {accZ[4*g+0], accZ[4*g+1], accZ[4*g+2], accZ[4*g+3]};
    *(float4*)&zrow[e0 + 4 * g] = zv;
  }
}

// ---------- state scan only: S_{c+1} = P_c S_c + Z_c, store all S_c ----------
// 128 blocks = (b,h,js); block owns columns js*16..js*16+15 of S.
// Thread (lane=d, wave jg) owns S[d][js*16+jg*4+r], r=0..3.
__global__ __launch_bounds__(256) void state_kernel(
    const float* __restrict__ kn /*Z*/, const float* __restrict__ Pbuf,
    float* __restrict__ Sbuf) {
  __shared__ float ST[16][68];    // ST[jloc][e] = S[e][js*16+jloc]
  int bid = blockIdx.x;
  int js = bid & 3, h = (bid >> 2) & 15, b = bid >> 6;
  int lane = threadIdx.x & 63;    // d
  int jg = threadIdx.x >> 6;      // wave -> jloc = jg*4+r
  int bh = b * H_ + h;
  float s_cur[4] = {0.f, 0.f, 0.f, 0.f};
  float4 p[16]; float4 z;
  {
    const float4* Prow = (const float4*)&Pbuf[(size_t)(bh * NC_) * 4096 + lane * 64];
    #pragma unroll
    for (int e4 = 0; e4 < 16; e4++) p[e4] = Prow[e4];
    z = *(const float4*)&kn[((size_t)(b * T_ + lane)) * D_ + h * 64 + js * 16 + jg * 4];
  }
  for (int c = 0; c < NC_; c++) {
    int ch = bh * NC_ + c;
    float4 sv = {s_cur[0], s_cur[1], s_cur[2], s_cur[3]};
    *(float4*)&Sbuf[(size_t)ch * 4096 + lane * 64 + js * 16 + jg * 4] = sv;
    #pragma unroll
    for (int r = 0; r < 4; r++) ST[jg * 4 + r][lane] = s_cur[r];
    __syncthreads();
    // prefetch next chunk's P,Z while computing
    float4 pn[16]; float4 zn;
    if (c + 1 < NC_) {
      const float4* Prow = (const float4*)&Pbuf[(size_t)(ch + 1) * 4096 + lane * 64];
      #pragma unroll
      for (int e4 = 0; e4 < 16; e4++) pn[e4] = Prow[e4];
      zn = *(const float4*)&kn[((size_t)(b * T_ + (c + 1) * 64 + lane)) * D_ + h * 64 + js * 16 + jg * 4];
    }
    float acc[4] = {z.x, z.y, z.z, z.w};
    #pragma unroll 4
    for (int e4 = 0; e4 < 16; e4++) {
      float4 pv = p[e4];
      #pragma unroll
      for (int r = 0; r < 4; r++) {
        float4 s4 = *(float4*)&ST[jg * 4 + r][e4 * 4];   // wave-broadcast
        acc[r] += pv.x * s4.x + pv.y * s4.y + pv.z * s4.z + pv.w * s4.w;
      }
    }
    __syncthreads();
    #pragma unroll
    for (int r = 0; r < 4; r++) s_cur[r] = acc[r];
    if (c + 1 < NC_) {
      #pragma unroll
      for (int e4 = 0; e4 < 16; e4++) p[e4] = pn[e4];
      z = zn;
    }
  }
}

// ---------- O = O0 + Qeff*S_c, fused per-head RMSNorm + bf16 cast ----------
// 1024 blocks (chunk-heads). Thread (t=tid&63, jg=tid>>6) owns O[t][jg*16..+15].
__global__ __launch_bounds__(256) void ophase_kernel(
    const float* __restrict__ qn /*Qeff*/, const float* __restrict__ Sbuf,
    const float* __restrict__ O0buf, const float* __restrict__ rms_g,
    ushort* __restrict__ ob) {
  __shared__ float Ssh[64][68];
  __shared__ float part[64][4];
  int ch = blockIdx.x;
  int b = ch >> 9, h = (ch >> 5) & 15, c = ch & 31;
  int tid = threadIdx.x;
  int t = tid & 63, jg = tid >> 6;
  #pragma unroll
  for (int g4 = 0; g4 < 4; g4++) {
    int idx = tid + g4 * 256;
    int row = idx >> 4, c4 = idx & 15;
    *(float4*)&Ssh[row][c4 * 4] = *(const float4*)&Sbuf[(size_t)ch * 4096 + idx * 4];
  }
  const float4* qrow = (const float4*)&qn[((size_t)(b * T_ + c * 64 + t)) * D_ + h * 64];
  float4 q[16];
  #pragma unroll
  for (int d4 = 0; d4 < 16; d4++) q[d4] = qrow[d4];
  float4 acc[4];
  #pragma unroll
  for (int g = 0; g < 4; g++)
    acc[g] = *(const float4*)&O0buf[(size_t)ch * 4096 + t * 64 + jg * 16 + g * 4];
  __syncthreads();
  for (int d4 = 0; d4 < 16; d4++) {
    float4 qv = q[d4];
    #pragma unroll
    for (int i = 0; i < 4; i++) {
      float qs = f4get(qv, i);
      #pragma unroll
      for (int g = 0; g < 4; g++) {
        float4 s4 = *(float4*)&Ssh[d4 * 4 + i][jg * 16 + g * 4];  // wave-broadcast
        acc[g].x += qs * s4.x; acc[g].y += qs * s4.y;
        acc[g].z += qs * s4.z; acc[g].w += qs * s4.w;
      }
    }
  }
  float ss = 0.f;
  #pragma unroll
  for (int g = 0; g < 4; g++)
    ss += acc[g].x * acc[g].x + acc[g].y * acc[g].y + acc[g].z * acc[g].z + acc[g].w * acc[g].w;
  part[t][jg] = ss;
  __syncthreads();
  float tot = part[t][0] + part[t][1] + part[t][2] + part[t][3];
  float sc = rsqrtf(tot * (1.f / 64.f) + 1e-6f);
  ushort* orow = &ob[((size_t)(b * T_ + c * 64 + t)) * D_ + h * 64];
  #pragma unroll
  for (int g = 0; g < 4; g++) {
    float4 g4 = *(const float4*)&rms_g[jg * 16 + g * 4];
    ushort4 r;
    r.x = f2bf(acc[g].x * sc * g4.x); r.y = f2bf(acc[g].y * sc * g4.y);
    r.z = f2bf(acc[g].z * sc * g4.z); r.w = f2bf(acc[g].w * sc * g4.w);
    *(ushort4*)&orow[jg * 16 + g * 4] = r;
  }
}

extern "C" void kernel_launch(void* const* d_in, const int* in_sizes, int n_in,
                              void* d_out, int out_size, void* d_ws, size_t ws_size,
                              hipStream_t stream) {
  const float* x  = (const float*)d_in[0];
  const float* Wq = (const float*)d_in[1];
  const float* Wk = (const float*)d_in[2];
  const float* Wv = (const float*)d_in[3];
  const float* Wb = (const float*)d_in[4];
  const float* cq = (const float*)d_in[5];
  const float* ck = (const float*)d_in[6];
  const float* cv = (const float*)d_in[7];
  const float* rg = (const float*)d_in[8];
  const float* Wo = (const float*)d_in[9];
  float* out = (float*)d_out;
  char* ws = (char*)d_ws;
  const size_t MiB = 1ull << 20;
  ushort* xb   = (ushort*)(ws + 0);         // dead after QKV gemms
  ushort* Wqt  = (ushort*)(ws + 8 * MiB);
  ushort* Wkt  = (ushort*)(ws + 10 * MiB);
  ushort* Wvt  = (ushort*)(ws + 12 * MiB);
  ushort* Wot  = (ushort*)(ws + 14 * MiB);  // live to end
  float* qpre  = (float*)(ws + 16 * MiB);   // dead after conv
  float* kpre  = (float*)(ws + 32 * MiB);
  float* vpre  = (float*)(ws + 48 * MiB);
  float* qn    = (float*)(ws + 64 * MiB);   // then Qeff in-place
  float* kn    = (float*)(ws + 80 * MiB);   // then Z in-place
  float* vn    = (float*)(ws + 96 * MiB);   // dead after prep1
  float* beta  = (float*)(ws + 112 * MiB);  // 256 KiB
  float* Wkbuf = (float*)(ws + 16 * MiB);   // over qpre, dead after prep2c
  float* U0buf = (float*)(ws + 32 * MiB);   // over kpre
  float* Lbuf  = (float*)(ws + 48 * MiB);   // over vpre; later P
  float* O0buf = (float*)(ws + 96 * MiB);   // over vn (after prep1)
  float* Sbuf  = (float*)(ws + 16 * MiB);   // over Wkbuf (dead after prep2c)
  ushort* ob   = (ushort*)(ws + 0);         // over xb (after QKV gemms)

  hipLaunchKernelGGL(cast_kernel, dim3(M_ * D_ / 4 / 256), dim3(256), 0, stream,
                     x, xb, M_ * D_ / 4);
  dim3 tb(32, 8);
  hipLaunchKernelGGL(transpose_cast_kernel, dim3(32, 32), tb, 0, stream, Wq, Wqt, D_, D_);
  hipLaunchKernelGGL(transpose_cast_kernel, dim3(32, 32), tb, 0, stream, Wk, Wkt, D_, D_);
  hipLaunchKernelGGL(transpose_cast_kernel, dim3(32, 32), tb, 0, stream, Wv, Wvt, D_, D_);
  hipLaunchKernelGGL(transpose_cast_kernel, dim3(32, 32), tb, 0, stream, Wo, Wot, D_, D_);

  dim3 gg(M_ / 128, D_ / 128);
  hipLaunchKernelGGL(gemm128_kernel, gg, dim3(256), 0, stream, xb, Wqt, qpre, M_, D_, D_);
  hipLaunchKernelGGL(gemm128_kernel, gg, dim3(256), 0, stream, xb, Wkt, kpre, M_, D_, D_);
  hipLaunchKernelGGL(gemm128_kernel, gg, dim3(256), 0, stream, xb, Wvt, vpre, M_, D_, D_);

  hipLaunchKernelGGL(beta_kernel, dim3(M_), dim3(256), 0, stream, x, Wb, beta);
  hipLaunchKernelGGL(conv_kernel, dim3(M_), dim3(256), 0, stream,
                     qpre, kpre, vpre, cq, ck, cv, qn, kn, vn);

  hipLaunchKernelGGL(prep1_kernel, dim3(NCH_), dim3(256), 0, stream,
                     kn, vn, beta, Wkbuf, U0buf);
  hipLaunchKernelGGL(prep2a_kernel, dim3(NCH_), dim3(256), 0, stream, qn, kn, Lbuf);
  hipLaunchKernelGGL(prep2b_kernel, dim3(NCH_), dim3(256), 0, stream,
                     Lbuf, Wkbuf, U0buf, qn, O0buf);
  hipLaunchKernelGGL(prep2c_kernel, dim3(NCH_), dim3(256), 0, stream,
                     kn, Wkbuf, U0buf, Lbuf);
  hipLaunchKernelGGL(state_kernel, dim3(B_ * H_ * 4), dim3(256), 0, stream,
                     kn, Lbuf, Sbuf);
  hipLaunchKernelGGL(ophase_kernel, dim3(NCH_), dim3(256), 0, stream,
                     qn, Sbuf, O0buf, rg, ob);
  hipLaunchKernelGGL(gemm128_kernel, gg, dim3(256), 0, stream, ob, Wot, out, M_, D_, D_);
}

// Round 4
// 779.215 us; speedup vs baseline: 1.1924x; 1.1924x over previous
//
#include <hip/hip_runtime.h>
#include <hip/hip_bf16.h>
#include <math.h>

#define B_ 2
#define T_ 2048
#define D_ 1024
#define H_ 16
#define DH_ 64
#define M_ (B_*T_)   // 4096 rows
#define NC_ 32       // chunks per sequence (T/64)
#define CS_ 64       // chunk size
#define NCH_ (B_*H_*NC_)  // 1024 chunk-heads

typedef __attribute__((ext_vector_type(4))) float floatx4;
typedef __attribute__((ext_vector_type(8))) short short8;

__device__ __forceinline__ ushort f2bf(float f) {
  union { float f; unsigned u; } c; c.f = f;
  unsigned r = (c.u + 0x7FFFu + ((c.u >> 16) & 1u)) >> 16;  // RNE
  return (ushort)r;
}
__device__ __forceinline__ float siluf(float u) {
  return u / (1.f + __expf(-u));
}
__device__ __forceinline__ float f4get(const float4& v, int j) {
  return j == 0 ? v.x : j == 1 ? v.y : j == 2 ? v.z : v.w;
}

// ---------- cast f32 -> bf16, n4 = n/4 ----------
__global__ void cast_kernel(const float* __restrict__ in, ushort* __restrict__ out, int n4) {
  int i = blockIdx.x * blockDim.x + threadIdx.x;
  if (i >= n4) return;
  float4 v = ((const float4*)in)[i];
  ushort4 o;
  o.x = f2bf(v.x); o.y = f2bf(v.y); o.z = f2bf(v.z); o.w = f2bf(v.w);
  ((ushort4*)out)[i] = o;
}

// ---------- transpose + cast: W[K][N] f32 -> Wt[N][K] bf16 ----------
__global__ void transpose_cast_kernel(const float* __restrict__ W, ushort* __restrict__ Wt,
                                      int K, int N) {
  __shared__ float tile[32][33];
  int tx = threadIdx.x, ty = threadIdx.y;
  int n0 = blockIdx.x * 32, k0 = blockIdx.y * 32;
  #pragma unroll
  for (int i = 0; i < 32; i += 8)
    tile[ty + i][tx] = W[(size_t)(k0 + ty + i) * N + n0 + tx];
  __syncthreads();
  #pragma unroll
  for (int i = 0; i < 32; i += 8)
    Wt[(size_t)(n0 + ty + i) * K + k0 + tx] = f2bf(tile[tx][ty + i]);
}

// ---------- m97-style bf16 MFMA GEMM: C[M][N] = A[M][K]*B[K][N], Bt = B^T [N][K] ----------
__global__ __launch_bounds__(256) void gemm128_kernel(
    const ushort* __restrict__ A, const ushort* __restrict__ Bt,
    float* __restrict__ C, int M, int N, int K) {
  __shared__ ushort lA[128 * 32];
  __shared__ ushort lB[128 * 32];
  int tid = threadIdx.x;
  int wave = tid >> 6, lane = tid & 63;
  int wm = wave >> 1, wn = wave & 1;
  int m16 = lane & 15, q4 = lane >> 4;
  int bm = blockIdx.x, bn = blockIdx.y;
  floatx4 acc[4][4] = {};
  int srow = tid >> 2;
  int sk8 = tid & 3;
  const ushort* Ag = A + (size_t)(bm * 128 + srow) * K + sk8 * 8;
  const ushort* Bg = Bt + (size_t)(bn * 128 + srow) * K + sk8 * 8;
  ushort* lAp = lA + tid * 8;
  ushort* lBp = lB + tid * 8;
  for (int k0 = 0; k0 < K; k0 += 32) {
    __builtin_amdgcn_global_load_lds(
        (const __attribute__((address_space(1))) void*)(Ag + k0),
        (__attribute__((address_space(3))) void*)lAp, 16, 0, 0);
    __builtin_amdgcn_global_load_lds(
        (const __attribute__((address_space(1))) void*)(Ag + (size_t)64 * K + k0),
        (__attribute__((address_space(3))) void*)(lAp + 2048), 16, 0, 0);
    __builtin_amdgcn_global_load_lds(
        (const __attribute__((address_space(1))) void*)(Bg + k0),
        (__attribute__((address_space(3))) void*)lBp, 16, 0, 0);
    __builtin_amdgcn_global_load_lds(
        (const __attribute__((address_space(1))) void*)(Bg + (size_t)64 * K + k0),
        (__attribute__((address_space(3))) void*)(lBp + 2048), 16, 0, 0);
    __syncthreads();
    short8 af[4], bf[4];
    #pragma unroll
    for (int i = 0; i < 4; i++) {
      af[i] = *(short8*)&lA[(wm * 64 + i * 16 + m16) * 32 + q4 * 8];
      bf[i] = *(short8*)&lB[(wn * 64 + i * 16 + m16) * 32 + q4 * 8];
    }
    #pragma unroll
    for (int mi = 0; mi < 4; mi++)
      #pragma unroll
      for (int nj = 0; nj < 4; nj++)
        acc[mi][nj] = __builtin_amdgcn_mfma_f32_16x16x32_bf16(af[mi], bf[nj], acc[mi][nj], 0, 0, 0);
    __syncthreads();
  }
  float* Cb = C + (size_t)(bm * 128) * N + bn * 128;
  #pragma unroll
  for (int mi = 0; mi < 4; mi++) {
    #pragma unroll
    for (int nj = 0; nj < 4; nj++) {
      #pragma unroll
      for (int i = 0; i < 4; i++) {
        int row = wm * 64 + mi * 16 + q4 * 4 + i;
        int col = wn * 64 + nj * 16 + m16;
        Cb[(size_t)row * N + col] = acc[mi][nj][i];
      }
    }
  }
}

// ---------- beta = sigmoid(x @ Wb) ----------
__global__ __launch_bounds__(256) void beta_kernel(const float* __restrict__ x,
                                                   const float* __restrict__ Wb,
                                                   float* __restrict__ beta) {
  __shared__ __align__(16) float xs[D_];
  int row = blockIdx.x;
  int tid = threadIdx.x;
  ((float4*)xs)[tid] = ((const float4*)(x + (size_t)row * D_))[tid];
  __syncthreads();
  int h = tid >> 4;
  int seg = tid & 15;
  float s = 0.f;
  #pragma unroll 8
  for (int i = 0; i < 64; i++) {
    int kk = seg * 64 + i;
    s += xs[kk] * Wb[(size_t)kk * H_ + h];
  }
  #pragma unroll
  for (int off = 8; off; off >>= 1) s += __shfl_down(s, off, 16);
  if (seg == 0) beta[(size_t)row * H_ + h] = 1.f / (1.f + __expf(-s));
}

// ---------- causal depthwise conv(K=4) + silu, l2norm for q,k ----------
__global__ __launch_bounds__(256) void conv_kernel(
    const float* __restrict__ qpre, const float* __restrict__ kpre, const float* __restrict__ vpre,
    const float* __restrict__ cq, const float* __restrict__ ck, const float* __restrict__ cv,
    float* __restrict__ qo, float* __restrict__ ko, float* __restrict__ vo) {
  int row = blockIdx.x;
  int t = row & (T_ - 1);
  int tid = threadIdx.x;
  int c0 = tid * 4;
  float4 zf = {0.f, 0.f, 0.f, 0.f};
  float4 xq[4], xk[4], xv[4];
  #pragma unroll
  for (int i = 0; i < 4; i++) {
    int tt = t - 3 + i;
    if (tt >= 0) {
      xq[i] = *(const float4*)(qpre + (size_t)(row - 3 + i) * D_ + c0);
      xk[i] = *(const float4*)(kpre + (size_t)(row - 3 + i) * D_ + c0);
      xv[i] = *(const float4*)(vpre + (size_t)(row - 3 + i) * D_ + c0);
    } else { xq[i] = zf; xk[i] = zf; xv[i] = zf; }
  }
  float yq[4], yk[4], yv[4];
  float pq = 0.f, pk = 0.f;
  #pragma unroll
  for (int j = 0; j < 4; j++) {
    float4 wq = ((const float4*)cq)[c0 + j];
    float4 wk = ((const float4*)ck)[c0 + j];
    float4 wv = ((const float4*)cv)[c0 + j];
    float sq = 0.f, sk = 0.f, sv = 0.f;
    #pragma unroll
    for (int i = 0; i < 4; i++) {
      sq += f4get(wq, i) * f4get(xq[i], j);
      sk += f4get(wk, i) * f4get(xk[i], j);
      sv += f4get(wv, i) * f4get(xv[i], j);
    }
    yq[j] = siluf(sq); yk[j] = siluf(sk); yv[j] = siluf(sv);
    pq += yq[j] * yq[j]; pk += yk[j] * yk[j];
  }
  #pragma unroll
  for (int off = 1; off < 16; off <<= 1) {
    pq += __shfl_xor(pq, off, 16);
    pk += __shfl_xor(pk, off, 16);
  }
  float rq = rsqrtf(pq + 1e-6f), rk = rsqrtf(pk + 1e-6f);
  float4 oq = {yq[0]*rq, yq[1]*rq, yq[2]*rq, yq[3]*rq};
  float4 okk = {yk[0]*rk, yk[1]*rk, yk[2]*rk, yk[3]*rk};
  float4 ov = {yv[0], yv[1], yv[2], yv[3]};
  *(float4*)(qo + (size_t)row * D_ + c0) = oq;
  *(float4*)(ko + (size_t)row * D_ + c0) = okk;
  *(float4*)(vo + (size_t)row * D_ + c0) = ov;
}

// ================= chunked delta rule =================
// prep1: A = strict_tril(diag(b)KK^T); solve (I+A)Wk = diag(b)K and (I+A)U0 = diag(b)V
// simultaneously, via panel-blocked forward substitution (16-row panels, intra-panel
// solve by one wave with shuffles — register-exact, 8 barriers total).
__global__ __launch_bounds__(256) void prep1_kernel(
    const float* __restrict__ kn, const float* __restrict__ vn,
    const float* __restrict__ beta,
    float* __restrict__ Wkbuf, float* __restrict__ U0buf) {
  __shared__ float Ksh[64][68];
  __shared__ float AT[64 * 64];   // AT[i*64+t] = A[t][i] for t>i, else 0
  __shared__ float XPK[16][68];
  __shared__ float XPV[16][68];
  __shared__ float bsh[64];
  int ch = blockIdx.x;
  int b = ch >> 9, h = (ch >> 5) & 15, c = ch & 31;
  int tid = threadIdx.x;
  int t = tid >> 2, seg = tid & 3;
  const float* krow = kn + ((size_t)(b * T_ + c * 64 + t)) * D_ + h * 64;
  #pragma unroll
  for (int g = 0; g < 4; g++)
    *(float4*)&Ksh[t][seg * 16 + 4 * g] = *(const float4*)&krow[seg * 16 + 4 * g];
  if (tid < 64) bsh[tid] = beta[((size_t)(b * T_ + c * 64 + tid)) * H_ + h];
  __syncthreads();
  {
    int s0 = seg * 16;
    float acc[16];
    #pragma unroll
    for (int r = 0; r < 16; r++) acc[r] = 0.f;
    for (int d4 = 0; d4 < 16; d4++) {
      float4 kt = *(float4*)&Ksh[t][d4 * 4];
      #pragma unroll
      for (int r = 0; r < 16; r++) {
        float4 ks = *(float4*)&Ksh[s0 + r][d4 * 4];
        acc[r] += kt.x * ks.x + kt.y * ks.y + kt.z * ks.z + kt.w * ks.w;
      }
    }
    float bt = bsh[t];
    #pragma unroll
    for (int r = 0; r < 16; r++) {
      int s = s0 + r;
      AT[s * 64 + t] = (t > s) ? bt * acc[r] : 0.f;
    }
  }
  // init X = diag(b)K | diag(b)V in registers
  float xk[16], xv[16];
  {
    float bt = bsh[t];
    const float* vrow = vn + ((size_t)(b * T_ + c * 64 + t)) * D_ + h * 64;
    #pragma unroll
    for (int g = 0; g < 4; g++) {
      float4 kv = *(float4*)&Ksh[t][seg * 16 + 4 * g];
      float4 vv = *(const float4*)&vrow[seg * 16 + 4 * g];
      xk[4*g+0] = bt * kv.x; xk[4*g+1] = bt * kv.y; xk[4*g+2] = bt * kv.z; xk[4*g+3] = bt * kv.w;
      xv[4*g+0] = bt * vv.x; xv[4*g+1] = bt * vv.y; xv[4*g+2] = bt * vv.z; xv[4*g+3] = bt * vv.w;
    }
  }
  __syncthreads();   // AT ready
  int wave = tid >> 6, lane = tid & 63;
  int r_loc = lane >> 2;
  for (int p = 0; p < 4; p++) {
    if (wave == p) {
      float a[16];
      #pragma unroll
      for (int i2 = 0; i2 < 16; i2++) a[i2] = AT[(p * 16 + i2) * 64 + t];
      #pragma unroll
      for (int i2 = 0; i2 < 16; i2++) {
        int src = i2 * 4 + (lane & 3);
        #pragma unroll
        for (int cc = 0; cc < 16; cc++) {
          float xki = __shfl(xk[cc], src, 64);
          float xvi = __shfl(xv[cc], src, 64);
          if (r_loc > i2) {
            xk[cc] = fmaf(-a[i2], xki, xk[cc]);
            xv[cc] = fmaf(-a[i2], xvi, xv[cc]);
          }
        }
      }
      #pragma unroll
      for (int g = 0; g < 4; g++) {
        float4 k4 = {xk[4*g+0], xk[4*g+1], xk[4*g+2], xk[4*g+3]};
        float4 v4 = {xv[4*g+0], xv[4*g+1], xv[4*g+2], xv[4*g+3]};
        *(float4*)&XPK[r_loc][seg * 16 + 4 * g] = k4;
        *(float4*)&XPV[r_loc][seg * 16 + 4 * g] = v4;
      }
    }
    __syncthreads();
    if (wave > p) {
      float a[16];
      #pragma unroll
      for (int i2 = 0; i2 < 16; i2++) a[i2] = AT[(p * 16 + i2) * 64 + t];
      #pragma unroll
      for (int i2 = 0; i2 < 16; i2++) {
        float ai = a[i2];
        #pragma unroll
        for (int g = 0; g < 4; g++) {
          float4 xk4 = *(float4*)&XPK[i2][seg * 16 + 4 * g];
          float4 xv4 = *(float4*)&XPV[i2][seg * 16 + 4 * g];
          xk[4*g+0] -= ai * xk4.x; xk[4*g+1] -= ai * xk4.y;
          xk[4*g+2] -= ai * xk4.z; xk[4*g+3] -= ai * xk4.w;
          xv[4*g+0] -= ai * xv4.x; xv[4*g+1] -= ai * xv4.y;
          xv[4*g+2] -= ai * xv4.z; xv[4*g+3] -= ai * xv4.w;
        }
      }
    }
    __syncthreads();
  }
  #pragma unroll
  for (int g = 0; g < 4; g++) {
    float4 k4 = {xk[4*g+0], xk[4*g+1], xk[4*g+2], xk[4*g+3]};
    float4 v4 = {xv[4*g+0], xv[4*g+1], xv[4*g+2], xv[4*g+3]};
    *(float4*)&Wkbuf[(size_t)ch * 4096 + t * 64 + seg * 16 + 4 * g] = k4;
    *(float4*)&U0buf[(size_t)ch * 4096 + t * 64 + seg * 16 + 4 * g] = v4;
  }
}

// prep2a: L = tril(Q K^T) (incl diagonal)
__global__ __launch_bounds__(256) void prep2a_kernel(
    const float* __restrict__ qn, const float* __restrict__ kn,
    float* __restrict__ Lbuf) {
  __shared__ float Qsh[64][68];
  __shared__ float Ksh[64][68];
  int ch = blockIdx.x;
  int b = ch >> 9, h = (ch >> 5) & 15, c = ch & 31;
  int tid = threadIdx.x;
  int t = tid >> 2, seg = tid & 3;
  const float* qrow = qn + ((size_t)(b * T_ + c * 64 + t)) * D_ + h * 64;
  const float* krow = kn + ((size_t)(b * T_ + c * 64 + t)) * D_ + h * 64;
  #pragma unroll
  for (int g = 0; g < 4; g++) {
    *(float4*)&Qsh[t][seg * 16 + 4 * g] = *(const float4*)&qrow[seg * 16 + 4 * g];
    *(float4*)&Ksh[t][seg * 16 + 4 * g] = *(const float4*)&krow[seg * 16 + 4 * g];
  }
  __syncthreads();
  int s0 = seg * 16;
  float acc[16];
  #pragma unroll
  for (int r = 0; r < 16; r++) acc[r] = 0.f;
  for (int d4 = 0; d4 < 16; d4++) {
    float4 qt = *(float4*)&Qsh[t][d4 * 4];
    #pragma unroll
    for (int r = 0; r < 16; r++) {
      float4 ks = *(float4*)&Ksh[s0 + r][d4 * 4];
      acc[r] += qt.x * ks.x + qt.y * ks.y + qt.z * ks.z + qt.w * ks.w;
    }
  }
  #pragma unroll
  for (int g = 0; g < 4; g++) {
    float4 ov;
    ov.x = (s0 + 4*g + 0 <= t) ? acc[4*g+0] : 0.f;
    ov.y = (s0 + 4*g + 1 <= t) ? acc[4*g+1] : 0.f;
    ov.z = (s0 + 4*g + 2 <= t) ? acc[4*g+2] : 0.f;
    ov.w = (s0 + 4*g + 3 <= t) ? acc[4*g+3] : 0.f;
    *(float4*)&Lbuf[(size_t)ch * 4096 + t * 64 + s0 + 4 * g] = ov;
  }
}

// prep2b: O0 = L U0 ; Qeff = Q - L Wk (in-place over qn)
__global__ __launch_bounds__(256) void prep2b_kernel(
    const float* __restrict__ Lbuf, const float* __restrict__ Wkbuf,
    const float* __restrict__ U0buf, float* qn,
    float* __restrict__ O0buf) {
  __shared__ float Lsh[64][68];
  __shared__ float Wksh[64][68];
  __shared__ float U0sh[64][68];
  int ch = blockIdx.x;
  int b = ch >> 9, h = (ch >> 5) & 15, c = ch & 31;
  int tid = threadIdx.x;
  int t = tid >> 2, seg = tid & 3;
  #pragma unroll
  for (int g = 0; g < 4; g++) {
    int o = t * 64 + seg * 16 + 4 * g;
    *(float4*)&Lsh[t][seg * 16 + 4 * g]  = *(const float4*)&Lbuf[(size_t)ch * 4096 + o];
    *(float4*)&Wksh[t][seg * 16 + 4 * g] = *(const float4*)&Wkbuf[(size_t)ch * 4096 + o];
    *(float4*)&U0sh[t][seg * 16 + 4 * g] = *(const float4*)&U0buf[(size_t)ch * 4096 + o];
  }
  __syncthreads();
  int j0 = seg * 16;
  float o0[16], lw[16];
  #pragma unroll
  for (int r = 0; r < 16; r++) { o0[r] = 0.f; lw[r] = 0.f; }
  for (int s = 0; s <= t; s++) {
    float l = Lsh[t][s];
    #pragma unroll
    for (int g = 0; g < 4; g++) {
      float4 u = *(float4*)&U0sh[s][j0 + 4 * g];
      float4 w = *(float4*)&Wksh[s][j0 + 4 * g];
      o0[4*g+0] += l * u.x; o0[4*g+1] += l * u.y; o0[4*g+2] += l * u.z; o0[4*g+3] += l * u.w;
      lw[4*g+0] += l * w.x; lw[4*g+1] += l * w.y; lw[4*g+2] += l * w.z; lw[4*g+3] += l * w.w;
    }
  }
  float* qrow = qn + ((size_t)(b * T_ + c * 64 + t)) * D_ + h * 64;
  #pragma unroll
  for (int g = 0; g < 4; g++) {
    float4 qv = *(const float4*)&qrow[j0 + 4 * g];
    qv.x -= lw[4*g+0]; qv.y -= lw[4*g+1]; qv.z -= lw[4*g+2]; qv.w -= lw[4*g+3];
    *(float4*)&qrow[j0 + 4 * g] = qv;
    float4 ov = {o0[4*g+0], o0[4*g+1], o0[4*g+2], o0[4*g+3]};
    *(float4*)&O0buf[(size_t)ch * 4096 + t * 64 + j0 + 4 * g] = ov;
  }
}

// prep2c (TRANSPOSED outputs): Pt[e][d] = I - Wk^T K  -> Pbuf rows e (coalesced)
//                              Zt[j][d] = U0^T K      -> kn rows j (coalesced)
__global__ __launch_bounds__(256) void prep2c_kernel(
    float* kn, const float* __restrict__ Wkbuf,
    const float* __restrict__ U0buf, float* __restrict__ Pbuf) {
  __shared__ float Ksh[64][68];
  __shared__ float Wksh[64][68];
  __shared__ float U0sh[64][68];
  int ch = blockIdx.x;
  int b = ch >> 9, h = (ch >> 5) & 15, c = ch & 31;
  int tid = threadIdx.x;
  int t = tid >> 2, seg = tid & 3;   // t = output row (e for Pt, j for Zt)
  const float* krow = kn + ((size_t)(b * T_ + c * 64 + t)) * D_ + h * 64;
  #pragma unroll
  for (int g = 0; g < 4; g++) {
    int o = t * 64 + seg * 16 + 4 * g;
    *(float4*)&Ksh[t][seg * 16 + 4 * g]  = *(const float4*)&krow[seg * 16 + 4 * g];
    *(float4*)&Wksh[t][seg * 16 + 4 * g] = *(const float4*)&Wkbuf[(size_t)ch * 4096 + o];
    *(float4*)&U0sh[t][seg * 16 + 4 * g] = *(const float4*)&U0buf[(size_t)ch * 4096 + o];
  }
  __syncthreads();
  int d0 = seg * 16;
  float accP[16], accZ[16];
  #pragma unroll
  for (int r = 0; r < 16; r++) { accP[r] = 0.f; accZ[r] = 0.f; }
  for (int s = 0; s < 64; s++) {
    float w = Wksh[s][t];
    float u = U0sh[s][t];
    #pragma unroll
    for (int g = 0; g < 4; g++) {
      float4 k4 = *(float4*)&Ksh[s][d0 + 4 * g];
      accP[4*g+0] += w * k4.x; accP[4*g+1] += w * k4.y; accP[4*g+2] += w * k4.z; accP[4*g+3] += w * k4.w;
      accZ[4*g+0] += u * k4.x; accZ[4*g+1] += u * k4.y; accZ[4*g+2] += u * k4.z; accZ[4*g+3] += u * k4.w;
    }
  }
  float* zrow = kn + ((size_t)(b * T_ + c * 64 + t)) * D_ + h * 64;
  #pragma unroll
  for (int g = 0; g < 4; g++) {
    float4 pv;
    pv.x = ((d0 + 4*g + 0) == t ? 1.f : 0.f) - accP[4*g+0];
    pv.y = ((d0 + 4*g + 1) == t ? 1.f : 0.f) - accP[4*g+1];
    pv.z = ((d0 + 4*g + 2) == t ? 1.f : 0.f) - accP[4*g+2];
    pv.w = ((d0 + 4*g + 3) == t ? 1.f : 0.f) - accP[4*g+3];
    *(float4*)&Pbuf[(size_t)ch * 4096 + t * 64 + d0 + 4 * g] = pv;
    float4 zv = {accZ[4*g+0], accZ[4*g+1], accZ[4*g+2], accZ[4*g+3]};
    *(float4*)&zrow[d0 + 4 * g] = zv;
  }
}

// ---------- state scan: S_{c+1} = P_c S_c + Z_c; store S_c transposed [ch][j][d] ----------
// 128 blocks = (b,h,js). Thread (d=lane, jq) owns S[d][js*16+jq*4 .. +3].
__global__ __launch_bounds__(256) void state_kernel(
    const float* __restrict__ kn /*Zt*/, const float* __restrict__ Pbuf /*Pt*/,
    float* __restrict__ Sbuf) {
  __shared__ float PT[64][68];    // PT[e][d] = P[d][e]
  __shared__ float STt[16][68];   // STt[jl][e] = S[e][js*16+jl]
  int bid = blockIdx.x;
  int js = bid & 3, h = (bid >> 2) & 15, b = bid >> 6;
  int bh = b * H_ + h;
  int tid = threadIdx.x;
  int d = tid & 63, jq = tid >> 6;
  int j0 = jq * 4;
  float s[4] = {0.f, 0.f, 0.f, 0.f};
  float4 pn[4];
  #pragma unroll
  for (int g = 0; g < 4; g++)
    pn[g] = *(const float4*)&Pbuf[(size_t)(bh * NC_) * 4096 + (size_t)(tid + g * 256) * 4];
  for (int c = 0; c < NC_; c++) {
    size_t ch = (size_t)bh * NC_ + c;
    #pragma unroll
    for (int i = 0; i < 4; i++) {
      Sbuf[ch * 4096 + (size_t)(js * 16 + j0 + i) * 64 + d] = s[i];  // coalesced 256B rows
      STt[j0 + i][d] = s[i];
    }
    #pragma unroll
    for (int g = 0; g < 4; g++) {
      int idx = tid + g * 256;
      *(float4*)&PT[idx >> 4][(idx & 15) * 4] = pn[g];
    }
    __syncthreads();
    if (c + 1 < NC_) {
      #pragma unroll
      for (int g = 0; g < 4; g++)
        pn[g] = *(const float4*)&Pbuf[(ch + 1) * 4096 + (size_t)(tid + g * 256) * 4];
    }
    float acc[4];
    #pragma unroll
    for (int i = 0; i < 4; i++)
      acc[i] = kn[((size_t)(b * T_ + c * 64 + js * 16 + j0 + i)) * D_ + h * 64 + d];
    #pragma unroll 4
    for (int e4 = 0; e4 < 16; e4++) {
      float p0 = PT[e4 * 4 + 0][d];
      float p1 = PT[e4 * 4 + 1][d];
      float p2 = PT[e4 * 4 + 2][d];
      float p3 = PT[e4 * 4 + 3][d];
      #pragma unroll
      for (int i = 0; i < 4; i++) {
        float4 st = *(float4*)&STt[j0 + i][e4 * 4];   // wave-uniform broadcast
        acc[i] += p0 * st.x + p1 * st.y + p2 * st.z + p3 * st.w;
      }
    }
    __syncthreads();
    #pragma unroll
    for (int i = 0; i < 4; i++) s[i] = acc[i];
  }
}

// ---------- O = O0 + Qeff*S_c (S transposed layout), fused RMSNorm + bf16 cast ----------
__global__ __launch_bounds__(256) void ophase_kernel(
    const float* __restrict__ qn /*Qeff*/, const float* __restrict__ Sbuf,
    const float* __restrict__ O0buf, const float* __restrict__ rms_g,
    ushort* __restrict__ ob) {
  __shared__ float Ssht[64][68];   // Ssht[j][d]
  __shared__ float part[64][4];
  int ch = blockIdx.x;
  int b = ch >> 9, h = (ch >> 5) & 15, c = ch & 31;
  int tid = threadIdx.x;
  int t = tid & 63, jg = tid >> 6;
  #pragma unroll
  for (int g4 = 0; g4 < 4; g4++) {
    int idx = tid + g4 * 256;
    *(float4*)&Ssht[idx >> 4][(idx & 15) * 4] =
        *(const float4*)&Sbuf[(size_t)ch * 4096 + (size_t)idx * 4];
  }
  const float4* qrow = (const float4*)&qn[((size_t)(b * T_ + c * 64 + t)) * D_ + h * 64];
  float4 q[16];
  #pragma unroll
  for (int d4 = 0; d4 < 16; d4++) q[d4] = qrow[d4];
  float o[16];
  #pragma unroll
  for (int g = 0; g < 4; g++) {
    float4 o4 = *(const float4*)&O0buf[(size_t)ch * 4096 + t * 64 + jg * 16 + g * 4];
    o[4*g+0] = o4.x; o[4*g+1] = o4.y; o[4*g+2] = o4.z; o[4*g+3] = o4.w;
  }
  __syncthreads();
  #pragma unroll
  for (int r = 0; r < 16; r++) {
    int j = jg * 16 + r;
    float s = 0.f;
    #pragma unroll 4
    for (int d4 = 0; d4 < 16; d4++) {
      float4 s4 = *(float4*)&Ssht[j][d4 * 4];   // wave-uniform broadcast
      float4 q4 = q[d4];
      s += q4.x * s4.x + q4.y * s4.y + q4.z * s4.z + q4.w * s4.w;
    }
    o[r] += s;
  }
  float ss = 0.f;
  #pragma unroll
  for (int r = 0; r < 16; r++) ss += o[r] * o[r];
  part[t][jg] = ss;
  __syncthreads();
  float tot = part[t][0] + part[t][1] + part[t][2] + part[t][3];
  float sc = rsqrtf(tot * (1.f / 64.f) + 1e-6f);
  ushort* orow = &ob[((size_t)(b * T_ + c * 64 + t)) * D_ + h * 64];
  #pragma unroll
  for (int g = 0; g < 4; g++) {
    float4 g4 = *(const float4*)&rms_g[jg * 16 + g * 4];
    ushort4 r4;
    r4.x = f2bf(o[4*g+0] * sc * g4.x); r4.y = f2bf(o[4*g+1] * sc * g4.y);
    r4.z = f2bf(o[4*g+2] * sc * g4.z); r4.w = f2bf(o[4*g+3] * sc * g4.w);
    *(ushort4*)&orow[jg * 16 + g * 4] = r4;
  }
}

extern "C" void kernel_launch(void* const* d_in, const int* in_sizes, int n_in,
                              void* d_out, int out_size, void* d_ws, size_t ws_size,
                              hipStream_t stream) {
  const float* x  = (const float*)d_in[0];
  const float* Wq = (const float*)d_in[1];
  const float* Wk = (const float*)d_in[2];
  const float* Wv = (const float*)d_in[3];
  const float* Wb = (const float*)d_in[4];
  const float* cq = (const float*)d_in[5];
  const float* ck = (const float*)d_in[6];
  const float* cv = (const float*)d_in[7];
  const float* rg = (const float*)d_in[8];
  const float* Wo = (const float*)d_in[9];
  float* out = (float*)d_out;
  char* ws = (char*)d_ws;
  const size_t MiB = 1ull << 20;
  ushort* xb   = (ushort*)(ws + 0);         // dead after QKV gemms
  ushort* Wqt  = (ushort*)(ws + 8 * MiB);
  ushort* Wkt  = (ushort*)(ws + 10 * MiB);
  ushort* Wvt  = (ushort*)(ws + 12 * MiB);
  ushort* Wot  = (ushort*)(ws + 14 * MiB);  // live to end
  float* qpre  = (float*)(ws + 16 * MiB);   // dead after conv
  float* kpre  = (float*)(ws + 32 * MiB);
  float* vpre  = (float*)(ws + 48 * MiB);
  float* qn    = (float*)(ws + 64 * MiB);   // then Qeff in-place
  float* kn    = (float*)(ws + 80 * MiB);   // then Zt in-place
  float* vn    = (float*)(ws + 96 * MiB);   // dead after prep1
  float* beta  = (float*)(ws + 112 * MiB);  // 256 KiB
  float* Wkbuf = (float*)(ws + 16 * MiB);   // over qpre, dead after prep2c
  float* U0buf = (float*)(ws + 32 * MiB);   // over kpre
  float* Lbuf  = (float*)(ws + 48 * MiB);   // over vpre; later Pt
  float* O0buf = (float*)(ws + 96 * MiB);   // over vn (after prep1)
  float* Sbuf  = (float*)(ws + 16 * MiB);   // over Wkbuf (dead after prep2c)
  ushort* ob   = (ushort*)(ws + 0);         // over xb (after QKV gemms)

  hipLaunchKernelGGL(cast_kernel, dim3(M_ * D_ / 4 / 256), dim3(256), 0, stream,
                     x, xb, M_ * D_ / 4);
  dim3 tb(32, 8);
  hipLaunchKernelGGL(transpose_cast_kernel, dim3(32, 32), tb, 0, stream, Wq, Wqt, D_, D_);
  hipLaunchKernelGGL(transpose_cast_kernel, dim3(32, 32), tb, 0, stream, Wk, Wkt, D_, D_);
  hipLaunchKernelGGL(transpose_cast_kernel, dim3(32, 32), tb, 0, stream, Wv, Wvt, D_, D_);
  hipLaunchKernelGGL(transpose_cast_kernel, dim3(32, 32), tb, 0, stream, Wo, Wot, D_, D_);

  dim3 gg(M_ / 128, D_ / 128);
  hipLaunchKernelGGL(gemm128_kernel, gg, dim3(256), 0, stream, xb, Wqt, qpre, M_, D_, D_);
  hipLaunchKernelGGL(gemm128_kernel, gg, dim3(256), 0, stream, xb, Wkt, kpre, M_, D_, D_);
  hipLaunchKernelGGL(gemm128_kernel, gg, dim3(256), 0, stream, xb, Wvt, vpre, M_, D_, D_);

  hipLaunchKernelGGL(beta_kernel, dim3(M_), dim3(256), 0, stream, x, Wb, beta);
  hipLaunchKernelGGL(conv_kernel, dim3(M_), dim3(256), 0, stream,
                     qpre, kpre, vpre, cq, ck, cv, qn, kn, vn);

  hipLaunchKernelGGL(prep1_kernel, dim3(NCH_), dim3(256), 0, stream,
                     kn, vn, beta, Wkbuf, U0buf);
  hipLaunchKernelGGL(prep2a_kernel, dim3(NCH_), dim3(256), 0, stream, qn, kn, Lbuf);
  hipLaunchKernelGGL(prep2b_kernel, dim3(NCH_), dim3(256), 0, stream,
                     Lbuf, Wkbuf, U0buf, qn, O0buf);
  hipLaunchKernelGGL(prep2c_kernel, dim3(NCH_), dim3(256), 0, stream,
                     kn, Wkbuf, U0buf, Lbuf);
  hipLaunchKernelGGL(state_kernel, dim3(B_ * H_ * 4), dim3(256), 0, stream,
                     kn, Lbuf, Sbuf);
  hipLaunchKernelGGL(ophase_kernel, dim3(NCH_), dim3(256), 0, stream,
                     qn, Sbuf, O0buf, rg, ob);
  hipLaunchKernelGGL(gemm128_kernel, gg, dim3(256), 0, stream, ob, Wot, out, M_, D_, D_);
}

// Round 5
// 635.737 us; speedup vs baseline: 1.4615x; 1.2257x over previous
//
#include <hip/hip_runtime.h>
#include <hip/hip_bf16.h>
#include <math.h>

#define B_ 2
#define T_ 2048
#define D_ 1024
#define H_ 16
#define DH_ 64
#define M_ (B_*T_)   // 4096 rows
#define NC_ 32       // chunks per sequence (T/64)
#define CS_ 64       // chunk size
#define NCH_ (B_*H_*NC_)  // 1024 chunk-heads

typedef __attribute__((ext_vector_type(4))) float floatx4;
typedef __attribute__((ext_vector_type(8))) short short8;

__device__ __forceinline__ ushort f2bf(float f) {
  union { float f; unsigned u; } c; c.f = f;
  unsigned r = (c.u + 0x7FFFu + ((c.u >> 16) & 1u)) >> 16;  // RNE
  return (ushort)r;
}
__device__ __forceinline__ float siluf(float u) {
  return u / (1.f + __expf(-u));
}
__device__ __forceinline__ float f4get(const float4& v, int j) {
  return j == 0 ? v.x : j == 1 ? v.y : j == 2 ? v.z : v.w;
}

// ---------- cast f32 -> bf16, n4 = n/4 ----------
__global__ void cast_kernel(const float* __restrict__ in, ushort* __restrict__ out, int n4) {
  int i = blockIdx.x * blockDim.x + threadIdx.x;
  if (i >= n4) return;
  float4 v = ((const float4*)in)[i];
  ushort4 o;
  o.x = f2bf(v.x); o.y = f2bf(v.y); o.z = f2bf(v.z); o.w = f2bf(v.w);
  ((ushort4*)out)[i] = o;
}

// ---------- transpose + cast: W[K][N] f32 -> Wt[N][K] bf16 ----------
__global__ void transpose_cast_kernel(const float* __restrict__ W, ushort* __restrict__ Wt,
                                      int K, int N) {
  __shared__ float tile[32][33];
  int tx = threadIdx.x, ty = threadIdx.y;
  int n0 = blockIdx.x * 32, k0 = blockIdx.y * 32;
  #pragma unroll
  for (int i = 0; i < 32; i += 8)
    tile[ty + i][tx] = W[(size_t)(k0 + ty + i) * N + n0 + tx];
  __syncthreads();
  #pragma unroll
  for (int i = 0; i < 32; i += 8)
    Wt[(size_t)(n0 + ty + i) * K + k0 + tx] = f2bf(tile[tx][ty + i]);
}

// ---------- m97-style bf16 MFMA GEMM: C[M][N] = A[M][K]*B[K][N], Bt = B^T [N][K] ----------
__global__ __launch_bounds__(256) void gemm128_kernel(
    const ushort* __restrict__ A, const ushort* __restrict__ Bt,
    float* __restrict__ C, int M, int N, int K) {
  __shared__ ushort lA[128 * 32];
  __shared__ ushort lB[128 * 32];
  int tid = threadIdx.x;
  int wave = tid >> 6, lane = tid & 63;
  int wm = wave >> 1, wn = wave & 1;
  int m16 = lane & 15, q4 = lane >> 4;
  int bm = blockIdx.x, bn = blockIdx.y;
  floatx4 acc[4][4] = {};
  int srow = tid >> 2;
  int sk8 = tid & 3;
  const ushort* Ag = A + (size_t)(bm * 128 + srow) * K + sk8 * 8;
  const ushort* Bg = Bt + (size_t)(bn * 128 + srow) * K + sk8 * 8;
  ushort* lAp = lA + tid * 8;
  ushort* lBp = lB + tid * 8;
  for (int k0 = 0; k0 < K; k0 += 32) {
    __builtin_amdgcn_global_load_lds(
        (const __attribute__((address_space(1))) void*)(Ag + k0),
        (__attribute__((address_space(3))) void*)lAp, 16, 0, 0);
    __builtin_amdgcn_global_load_lds(
        (const __attribute__((address_space(1))) void*)(Ag + (size_t)64 * K + k0),
        (__attribute__((address_space(3))) void*)(lAp + 2048), 16, 0, 0);
    __builtin_amdgcn_global_load_lds(
        (const __attribute__((address_space(1))) void*)(Bg + k0),
        (__attribute__((address_space(3))) void*)lBp, 16, 0, 0);
    __builtin_amdgcn_global_load_lds(
        (const __attribute__((address_space(1))) void*)(Bg + (size_t)64 * K + k0),
        (__attribute__((address_space(3))) void*)(lBp + 2048), 16, 0, 0);
    __syncthreads();
    short8 af[4], bf[4];
    #pragma unroll
    for (int i = 0; i < 4; i++) {
      af[i] = *(short8*)&lA[(wm * 64 + i * 16 + m16) * 32 + q4 * 8];
      bf[i] = *(short8*)&lB[(wn * 64 + i * 16 + m16) * 32 + q4 * 8];
    }
    #pragma unroll
    for (int mi = 0; mi < 4; mi++)
      #pragma unroll
      for (int nj = 0; nj < 4; nj++)
        acc[mi][nj] = __builtin_amdgcn_mfma_f32_16x16x32_bf16(af[mi], bf[nj], acc[mi][nj], 0, 0, 0);
    __syncthreads();
  }
  float* Cb = C + (size_t)(bm * 128) * N + bn * 128;
  #pragma unroll
  for (int mi = 0; mi < 4; mi++) {
    #pragma unroll
    for (int nj = 0; nj < 4; nj++) {
      #pragma unroll
      for (int i = 0; i < 4; i++) {
        int row = wm * 64 + mi * 16 + q4 * 4 + i;
        int col = wn * 64 + nj * 16 + m16;
        Cb[(size_t)row * N + col] = acc[mi][nj][i];
      }
    }
  }
}

// ---------- beta = sigmoid(x @ Wb) ----------
__global__ __launch_bounds__(256) void beta_kernel(const float* __restrict__ x,
                                                   const float* __restrict__ Wb,
                                                   float* __restrict__ beta) {
  __shared__ __align__(16) float xs[D_];
  int row = blockIdx.x;
  int tid = threadIdx.x;
  ((float4*)xs)[tid] = ((const float4*)(x + (size_t)row * D_))[tid];
  __syncthreads();
  int h = tid >> 4;
  int seg = tid & 15;
  float s = 0.f;
  #pragma unroll 8
  for (int i = 0; i < 64; i++) {
    int kk = seg * 64 + i;
    s += xs[kk] * Wb[(size_t)kk * H_ + h];
  }
  #pragma unroll
  for (int off = 8; off; off >>= 1) s += __shfl_down(s, off, 16);
  if (seg == 0) beta[(size_t)row * H_ + h] = 1.f / (1.f + __expf(-s));
}

// ---------- causal depthwise conv(K=4) + silu, l2norm for q,k ----------
__global__ __launch_bounds__(256) void conv_kernel(
    const float* __restrict__ qpre, const float* __restrict__ kpre, const float* __restrict__ vpre,
    const float* __restrict__ cq, const float* __restrict__ ck, const float* __restrict__ cv,
    float* __restrict__ qo, float* __restrict__ ko, float* __restrict__ vo) {
  int row = blockIdx.x;
  int t = row & (T_ - 1);
  int tid = threadIdx.x;
  int c0 = tid * 4;
  float4 zf = {0.f, 0.f, 0.f, 0.f};
  float4 xq[4], xk[4], xv[4];
  #pragma unroll
  for (int i = 0; i < 4; i++) {
    int tt = t - 3 + i;
    if (tt >= 0) {
      xq[i] = *(const float4*)(qpre + (size_t)(row - 3 + i) * D_ + c0);
      xk[i] = *(const float4*)(kpre + (size_t)(row - 3 + i) * D_ + c0);
      xv[i] = *(const float4*)(vpre + (size_t)(row - 3 + i) * D_ + c0);
    } else { xq[i] = zf; xk[i] = zf; xv[i] = zf; }
  }
  float yq[4], yk[4], yv[4];
  float pq = 0.f, pk = 0.f;
  #pragma unroll
  for (int j = 0; j < 4; j++) {
    float4 wq = ((const float4*)cq)[c0 + j];
    float4 wk = ((const float4*)ck)[c0 + j];
    float4 wv = ((const float4*)cv)[c0 + j];
    float sq = 0.f, sk = 0.f, sv = 0.f;
    #pragma unroll
    for (int i = 0; i < 4; i++) {
      sq += f4get(wq, i) * f4get(xq[i], j);
      sk += f4get(wk, i) * f4get(xk[i], j);
      sv += f4get(wv, i) * f4get(xv[i], j);
    }
    yq[j] = siluf(sq); yk[j] = siluf(sk); yv[j] = siluf(sv);
    pq += yq[j] * yq[j]; pk += yk[j] * yk[j];
  }
  #pragma unroll
  for (int off = 1; off < 16; off <<= 1) {
    pq += __shfl_xor(pq, off, 16);
    pk += __shfl_xor(pk, off, 16);
  }
  float rq = rsqrtf(pq + 1e-6f), rk = rsqrtf(pk + 1e-6f);
  float4 oq = {yq[0]*rq, yq[1]*rq, yq[2]*rq, yq[3]*rq};
  float4 okk = {yk[0]*rk, yk[1]*rk, yk[2]*rk, yk[3]*rk};
  float4 ov = {yv[0], yv[1], yv[2], yv[3]};
  *(float4*)(qo + (size_t)row * D_ + c0) = oq;
  *(float4*)(ko + (size_t)row * D_ + c0) = okk;
  *(float4*)(vo + (size_t)row * D_ + c0) = ov;
}

// ================= chunked delta rule =================
// prep1: A = strict_tril(diag(b)KK^T); solve (I+A)Wk = diag(b)K and (I+A)U0 = diag(b)V
// simultaneously, via panel-blocked forward substitution (16-row panels, intra-panel
// solve by one wave with shuffles — register-exact, 8 barriers total).
__global__ __launch_bounds__(256) void prep1_kernel(
    const float* __restrict__ kn, const float* __restrict__ vn,
    const float* __restrict__ beta,
    float* __restrict__ Wkbuf, float* __restrict__ U0buf) {
  __shared__ float Ksh[64][68];
  __shared__ float AT[64 * 64];   // AT[i*64+t] = A[t][i] for t>i, else 0
  __shared__ float XPK[16][68];
  __shared__ float XPV[16][68];
  __shared__ float bsh[64];
  int ch = blockIdx.x;
  int b = ch >> 9, h = (ch >> 5) & 15, c = ch & 31;
  int tid = threadIdx.x;
  int t = tid >> 2, seg = tid & 3;
  const float* krow = kn + ((size_t)(b * T_ + c * 64 + t)) * D_ + h * 64;
  #pragma unroll
  for (int g = 0; g < 4; g++)
    *(float4*)&Ksh[t][seg * 16 + 4 * g] = *(const float4*)&krow[seg * 16 + 4 * g];
  if (tid < 64) bsh[tid] = beta[((size_t)(b * T_ + c * 64 + tid)) * H_ + h];
  __syncthreads();
  {
    int s0 = seg * 16;
    float acc[16];
    #pragma unroll
    for (int r = 0; r < 16; r++) acc[r] = 0.f;
    for (int d4 = 0; d4 < 16; d4++) {
      float4 kt = *(float4*)&Ksh[t][d4 * 4];
      #pragma unroll
      for (int r = 0; r < 16; r++) {
        float4 ks = *(float4*)&Ksh[s0 + r][d4 * 4];
        acc[r] += kt.x * ks.x + kt.y * ks.y + kt.z * ks.z + kt.w * ks.w;
      }
    }
    float bt = bsh[t];
    #pragma unroll
    for (int r = 0; r < 16; r++) {
      int s = s0 + r;
      AT[s * 64 + t] = (t > s) ? bt * acc[r] : 0.f;
    }
  }
  // init X = diag(b)K | diag(b)V in registers
  float xk[16], xv[16];
  {
    float bt = bsh[t];
    const float* vrow = vn + ((size_t)(b * T_ + c * 64 + t)) * D_ + h * 64;
    #pragma unroll
    for (int g = 0; g < 4; g++) {
      float4 kv = *(float4*)&Ksh[t][seg * 16 + 4 * g];
      float4 vv = *(const float4*)&vrow[seg * 16 + 4 * g];
      xk[4*g+0] = bt * kv.x; xk[4*g+1] = bt * kv.y; xk[4*g+2] = bt * kv.z; xk[4*g+3] = bt * kv.w;
      xv[4*g+0] = bt * vv.x; xv[4*g+1] = bt * vv.y; xv[4*g+2] = bt * vv.z; xv[4*g+3] = bt * vv.w;
    }
  }
  __syncthreads();   // AT ready
  int wave = tid >> 6, lane = tid & 63;
  int r_loc = lane >> 2;
  for (int p = 0; p < 4; p++) {
    if (wave == p) {
      float a[16];
      #pragma unroll
      for (int i2 = 0; i2 < 16; i2++) a[i2] = AT[(p * 16 + i2) * 64 + t];
      #pragma unroll
      for (int i2 = 0; i2 < 16; i2++) {
        int src = i2 * 4 + (lane & 3);
        #pragma unroll
        for (int cc = 0; cc < 16; cc++) {
          float xki = __shfl(xk[cc], src, 64);
          float xvi = __shfl(xv[cc], src, 64);
          if (r_loc > i2) {
            xk[cc] = fmaf(-a[i2], xki, xk[cc]);
            xv[cc] = fmaf(-a[i2], xvi, xv[cc]);
          }
        }
      }
      #pragma unroll
      for (int g = 0; g < 4; g++) {
        float4 k4 = {xk[4*g+0], xk[4*g+1], xk[4*g+2], xk[4*g+3]};
        float4 v4 = {xv[4*g+0], xv[4*g+1], xv[4*g+2], xv[4*g+3]};
        *(float4*)&XPK[r_loc][seg * 16 + 4 * g] = k4;
        *(float4*)&XPV[r_loc][seg * 16 + 4 * g] = v4;
      }
    }
    __syncthreads();
    if (wave > p) {
      float a[16];
      #pragma unroll
      for (int i2 = 0; i2 < 16; i2++) a[i2] = AT[(p * 16 + i2) * 64 + t];
      #pragma unroll
      for (int i2 = 0; i2 < 16; i2++) {
        float ai = a[i2];
        #pragma unroll
        for (int g = 0; g < 4; g++) {
          float4 xk4 = *(float4*)&XPK[i2][seg * 16 + 4 * g];
          float4 xv4 = *(float4*)&XPV[i2][seg * 16 + 4 * g];
          xk[4*g+0] -= ai * xk4.x; xk[4*g+1] -= ai * xk4.y;
          xk[4*g+2] -= ai * xk4.z; xk[4*g+3] -= ai * xk4.w;
          xv[4*g+0] -= ai * xv4.x; xv[4*g+1] -= ai * xv4.y;
          xv[4*g+2] -= ai * xv4.z; xv[4*g+3] -= ai * xv4.w;
        }
      }
    }
    __syncthreads();
  }
  #pragma unroll
  for (int g = 0; g < 4; g++) {
    float4 k4 = {xk[4*g+0], xk[4*g+1], xk[4*g+2], xk[4*g+3]};
    float4 v4 = {xv[4*g+0], xv[4*g+1], xv[4*g+2], xv[4*g+3]};
    *(float4*)&Wkbuf[(size_t)ch * 4096 + t * 64 + seg * 16 + 4 * g] = k4;
    *(float4*)&U0buf[(size_t)ch * 4096 + t * 64 + seg * 16 + 4 * g] = v4;
  }
}

// prep2a: L = tril(Q K^T) (incl diagonal)
__global__ __launch_bounds__(256) void prep2a_kernel(
    const float* __restrict__ qn, const float* __restrict__ kn,
    float* __restrict__ Lbuf) {
  __shared__ float Qsh[64][68];
  __shared__ float Ksh[64][68];
  int ch = blockIdx.x;
  int b = ch >> 9, h = (ch >> 5) & 15, c = ch & 31;
  int tid = threadIdx.x;
  int t = tid >> 2, seg = tid & 3;
  const float* qrow = qn + ((size_t)(b * T_ + c * 64 + t)) * D_ + h * 64;
  const float* krow = kn + ((size_t)(b * T_ + c * 64 + t)) * D_ + h * 64;
  #pragma unroll
  for (int g = 0; g < 4; g++) {
    *(float4*)&Qsh[t][seg * 16 + 4 * g] = *(const float4*)&qrow[seg * 16 + 4 * g];
    *(float4*)&Ksh[t][seg * 16 + 4 * g] = *(const float4*)&krow[seg * 16 + 4 * g];
  }
  __syncthreads();
  int s0 = seg * 16;
  float acc[16];
  #pragma unroll
  for (int r = 0; r < 16; r++) acc[r] = 0.f;
  for (int d4 = 0; d4 < 16; d4++) {
    float4 qt = *(float4*)&Qsh[t][d4 * 4];
    #pragma unroll
    for (int r = 0; r < 16; r++) {
      float4 ks = *(float4*)&Ksh[s0 + r][d4 * 4];
      acc[r] += qt.x * ks.x + qt.y * ks.y + qt.z * ks.z + qt.w * ks.w;
    }
  }
  #pragma unroll
  for (int g = 0; g < 4; g++) {
    float4 ov;
    ov.x = (s0 + 4*g + 0 <= t) ? acc[4*g+0] : 0.f;
    ov.y = (s0 + 4*g + 1 <= t) ? acc[4*g+1] : 0.f;
    ov.z = (s0 + 4*g + 2 <= t) ? acc[4*g+2] : 0.f;
    ov.w = (s0 + 4*g + 3 <= t) ? acc[4*g+3] : 0.f;
    *(float4*)&Lbuf[(size_t)ch * 4096 + t * 64 + s0 + 4 * g] = ov;
  }
}

// prep2b: O0 = L U0 ; Qeff = Q - L Wk (in-place over qn)
__global__ __launch_bounds__(256) void prep2b_kernel(
    const float* __restrict__ Lbuf, const float* __restrict__ Wkbuf,
    const float* __restrict__ U0buf, float* qn,
    float* __restrict__ O0buf) {
  __shared__ float Lsh[64][68];
  __shared__ float Wksh[64][68];
  __shared__ float U0sh[64][68];
  int ch = blockIdx.x;
  int b = ch >> 9, h = (ch >> 5) & 15, c = ch & 31;
  int tid = threadIdx.x;
  int t = tid >> 2, seg = tid & 3;
  #pragma unroll
  for (int g = 0; g < 4; g++) {
    int o = t * 64 + seg * 16 + 4 * g;
    *(float4*)&Lsh[t][seg * 16 + 4 * g]  = *(const float4*)&Lbuf[(size_t)ch * 4096 + o];
    *(float4*)&Wksh[t][seg * 16 + 4 * g] = *(const float4*)&Wkbuf[(size_t)ch * 4096 + o];
    *(float4*)&U0sh[t][seg * 16 + 4 * g] = *(const float4*)&U0buf[(size_t)ch * 4096 + o];
  }
  __syncthreads();
  int j0 = seg * 16;
  float o0[16], lw[16];
  #pragma unroll
  for (int r = 0; r < 16; r++) { o0[r] = 0.f; lw[r] = 0.f; }
  for (int s = 0; s <= t; s++) {
    float l = Lsh[t][s];
    #pragma unroll
    for (int g = 0; g < 4; g++) {
      float4 u = *(float4*)&U0sh[s][j0 + 4 * g];
      float4 w = *(float4*)&Wksh[s][j0 + 4 * g];
      o0[4*g+0] += l * u.x; o0[4*g+1] += l * u.y; o0[4*g+2] += l * u.z; o0[4*g+3] += l * u.w;
      lw[4*g+0] += l * w.x; lw[4*g+1] += l * w.y; lw[4*g+2] += l * w.z; lw[4*g+3] += l * w.w;
    }
  }
  float* qrow = qn + ((size_t)(b * T_ + c * 64 + t)) * D_ + h * 64;
  #pragma unroll
  for (int g = 0; g < 4; g++) {
    float4 qv = *(const float4*)&qrow[j0 + 4 * g];
    qv.x -= lw[4*g+0]; qv.y -= lw[4*g+1]; qv.z -= lw[4*g+2]; qv.w -= lw[4*g+3];
    *(float4*)&qrow[j0 + 4 * g] = qv;
    float4 ov = {o0[4*g+0], o0[4*g+1], o0[4*g+2], o0[4*g+3]};
    *(float4*)&O0buf[(size_t)ch * 4096 + t * 64 + j0 + 4 * g] = ov;
  }
}

// prep2c (TRANSPOSED outputs): Pt[e][d] = I - Wk^T K  -> Pbuf rows e (coalesced)
//                              Zt[j][d] = U0^T K      -> kn rows j (coalesced)
__global__ __launch_bounds__(256) void prep2c_kernel(
    float* kn, const float* __restrict__ Wkbuf,
    const float* __restrict__ U0buf, float* __restrict__ Pbuf) {
  __shared__ float Ksh[64][68];
  __shared__ float Wksh[64][68];
  __shared__ float U0sh[64][68];
  int ch = blockIdx.x;
  int b = ch >> 9, h = (ch >> 5) & 15, c = ch & 31;
  int tid = threadIdx.x;
  int t = tid >> 2, seg = tid & 3;   // t = output row (e for Pt, j for Zt)
  const float* krow = kn + ((size_t)(b * T_ + c * 64 + t)) * D_ + h * 64;
  #pragma unroll
  for (int g = 0; g < 4; g++) {
    int o = t * 64 + seg * 16 + 4 * g;
    *(float4*)&Ksh[t][seg * 16 + 4 * g]  = *(const float4*)&krow[seg * 16 + 4 * g];
    *(float4*)&Wksh[t][seg * 16 + 4 * g] = *(const float4*)&Wkbuf[(size_t)ch * 4096 + o];
    *(float4*)&U0sh[t][seg * 16 + 4 * g] = *(const float4*)&U0buf[(size_t)ch * 4096 + o];
  }
  __syncthreads();
  int d0 = seg * 16;
  float accP[16], accZ[16];
  #pragma unroll
  for (int r = 0; r < 16; r++) { accP[r] = 0.f; accZ[r] = 0.f; }
  for (int s = 0; s < 64; s++) {
    float w = Wksh[s][t];
    float u = U0sh[s][t];
    #pragma unroll
    for (int g = 0; g < 4; g++) {
      float4 k4 = *(float4*)&Ksh[s][d0 + 4 * g];
      accP[4*g+0] += w * k4.x; accP[4*g+1] += w * k4.y; accP[4*g+2] += w * k4.z; accP[4*g+3] += w * k4.w;
      accZ[4*g+0] += u * k4.x; accZ[4*g+1] += u * k4.y; accZ[4*g+2] += u * k4.z; accZ[4*g+3] += u * k4.w;
    }
  }
  float* zrow = kn + ((size_t)(b * T_ + c * 64 + t)) * D_ + h * 64;
  #pragma unroll
  for (int g = 0; g < 4; g++) {
    float4 pv;
    pv.x = ((d0 + 4*g + 0) == t ? 1.f : 0.f) - accP[4*g+0];
    pv.y = ((d0 + 4*g + 1) == t ? 1.f : 0.f) - accP[4*g+1];
    pv.z = ((d0 + 4*g + 2) == t ? 1.f : 0.f) - accP[4*g+2];
    pv.w = ((d0 + 4*g + 3) == t ? 1.f : 0.f) - accP[4*g+3];
    *(float4*)&Pbuf[(size_t)ch * 4096 + t * 64 + d0 + 4 * g] = pv;
    float4 zv = {accZ[4*g+0], accZ[4*g+1], accZ[4*g+2], accZ[4*g+3]};
    *(float4*)&zrow[d0 + 4 * g] = zv;
  }
}

// ---------- state scan: S_{c+1} = P_c S_c + Z_c; store S_c transposed [ch][j][d] ----------
// 128 blocks = (b,h,js). Thread (d=lane, jq) owns S[d][js*16+jq*4 .. +3].
__global__ __launch_bounds__(256) void state_kernel(
    const float* __restrict__ kn /*Zt*/, const float* __restrict__ Pbuf /*Pt*/,
    float* __restrict__ Sbuf) {
  __shared__ float PT[64][68];    // PT[e][d] = P[d][e]
  __shared__ float STt[16][68];   // STt[jl][e] = S[e][js*16+jl]
  int bid = blockIdx.x;
  int js = bid & 3, h = (bid >> 2) & 15, b = bid >> 6;
  int bh = b * H_ + h;
  int tid = threadIdx.x;
  int d = tid & 63, jq = tid >> 6;
  int j0 = jq * 4;
  float s[4] = {0.f, 0.f, 0.f, 0.f};
  float4 pn[4];
  #pragma unroll
  for (int g = 0; g < 4; g++)
    pn[g] = *(const float4*)&Pbuf[(size_t)(bh * NC_) * 4096 + (size_t)(tid + g * 256) * 4];
  for (int c = 0; c < NC_; c++) {
    size_t ch = (size_t)bh * NC_ + c;
    #pragma unroll
    for (int i = 0; i < 4; i++) {
      Sbuf[ch * 4096 + (size_t)(js * 16 + j0 + i) * 64 + d] = s[i];  // coalesced 256B rows
      STt[j0 + i][d] = s[i];
    }
    #pragma unroll
    for (int g = 0; g < 4; g++) {
      int idx = tid + g * 256;
      *(float4*)&PT[idx >> 4][(idx & 15) * 4] = pn[g];
    }
    __syncthreads();
    if (c + 1 < NC_) {
      #pragma unroll
      for (int g = 0; g < 4; g++)
        pn[g] = *(const float4*)&Pbuf[(ch + 1) * 4096 + (size_t)(tid + g * 256) * 4];
    }
    float acc[4];
    #pragma unroll
    for (int i = 0; i < 4; i++)
      acc[i] = kn[((size_t)(b * T_ + c * 64 + js * 16 + j0 + i)) * D_ + h * 64 + d];
    #pragma unroll 4
    for (int e4 = 0; e4 < 16; e4++) {
      float p0 = PT[e4 * 4 + 0][d];
      float p1 = PT[e4 * 4 + 1][d];
      float p2 = PT[e4 * 4 + 2][d];
      float p3 = PT[e4 * 4 + 3][d];
      #pragma unroll
      for (int i = 0; i < 4; i++) {
        float4 st = *(float4*)&STt[j0 + i][e4 * 4];   // wave-uniform broadcast
        acc[i] += p0 * st.x + p1 * st.y + p2 * st.z + p3 * st.w;
      }
    }
    __syncthreads();
    #pragma unroll
    for (int i = 0; i < 4; i++) s[i] = acc[i];
  }
}

// ---------- O = O0 + Qeff*S_c (S transposed layout), fused RMSNorm + bf16 cast ----------
// No per-thread q array (spilled in prev version): q staged in LDS transposed,
// S read as wave-uniform broadcasts, only o[16] accumulators live in registers.
__global__ __launch_bounds__(256) void ophase_kernel(
    const float* __restrict__ qn /*Qeff*/, const float* __restrict__ Sbuf,
    const float* __restrict__ O0buf, const float* __restrict__ rms_g,
    ushort* __restrict__ ob) {
  __shared__ float Ssht[64][68];   // Ssht[j][d] = S[d][j]
  __shared__ float QshT[64][65];   // QshT[d][t] = q[t][d]; stride 65 -> conflict-free lane reads
  __shared__ float part[64][4];
  int ch = blockIdx.x;
  int b = ch >> 9, h = (ch >> 5) & 15, c = ch & 31;
  int tid = threadIdx.x;
  int t = tid & 63, jg = tid >> 6;
  #pragma unroll
  for (int g = 0; g < 4; g++) {
    int idx = tid + g * 256;
    *(float4*)&Ssht[idx >> 4][(idx & 15) * 4] =
        *(const float4*)&Sbuf[(size_t)ch * 4096 + (size_t)idx * 4];
  }
  #pragma unroll
  for (int g = 0; g < 4; g++) {
    int idx = tid + g * 256;
    int row = idx >> 4, c4 = idx & 15;
    float4 qv = *(const float4*)&qn[((size_t)(b * T_ + c * 64 + row)) * D_ + h * 64 + c4 * 4];
    QshT[c4 * 4 + 0][row] = qv.x;
    QshT[c4 * 4 + 1][row] = qv.y;
    QshT[c4 * 4 + 2][row] = qv.z;
    QshT[c4 * 4 + 3][row] = qv.w;
  }
  float o[16];
  #pragma unroll
  for (int g = 0; g < 4; g++) {
    float4 o4 = *(const float4*)&O0buf[(size_t)ch * 4096 + t * 64 + jg * 16 + g * 4];
    o[4*g+0] = o4.x; o[4*g+1] = o4.y; o[4*g+2] = o4.z; o[4*g+3] = o4.w;
  }
  __syncthreads();
  for (int d4 = 0; d4 < 16; d4++) {
    float q0 = QshT[d4 * 4 + 0][t];
    float q1 = QshT[d4 * 4 + 1][t];
    float q2 = QshT[d4 * 4 + 2][t];
    float q3 = QshT[d4 * 4 + 3][t];
    #pragma unroll
    for (int r = 0; r < 16; r++) {
      float4 s4 = *(float4*)&Ssht[jg * 16 + r][d4 * 4];   // wave-uniform broadcast
      o[r] += q0 * s4.x + q1 * s4.y + q2 * s4.z + q3 * s4.w;
    }
  }
  float ss = 0.f;
  #pragma unroll
  for (int r = 0; r < 16; r++) ss += o[r] * o[r];
  part[t][jg] = ss;
  __syncthreads();
  float tot = part[t][0] + part[t][1] + part[t][2] + part[t][3];
  float sc = rsqrtf(tot * (1.f / 64.f) + 1e-6f);
  ushort* orow = &ob[((size_t)(b * T_ + c * 64 + t)) * D_ + h * 64];
  #pragma unroll
  for (int g = 0; g < 4; g++) {
    float4 g4 = *(const float4*)&rms_g[jg * 16 + g * 4];
    ushort4 r4;
    r4.x = f2bf(o[4*g+0] * sc * g4.x); r4.y = f2bf(o[4*g+1] * sc * g4.y);
    r4.z = f2bf(o[4*g+2] * sc * g4.z); r4.w = f2bf(o[4*g+3] * sc * g4.w);
    *(ushort4*)&orow[jg * 16 + g * 4] = r4;
  }
}

extern "C" void kernel_launch(void* const* d_in, const int* in_sizes, int n_in,
                              void* d_out, int out_size, void* d_ws, size_t ws_size,
                              hipStream_t stream) {
  const float* x  = (const float*)d_in[0];
  const float* Wq = (const float*)d_in[1];
  const float* Wk = (const float*)d_in[2];
  const float* Wv = (const float*)d_in[3];
  const float* Wb = (const float*)d_in[4];
  const float* cq = (const float*)d_in[5];
  const float* ck = (const float*)d_in[6];
  const float* cv = (const float*)d_in[7];
  const float* rg = (const float*)d_in[8];
  const float* Wo = (const float*)d_in[9];
  float* out = (float*)d_out;
  char* ws = (char*)d_ws;
  const size_t MiB = 1ull << 20;
  ushort* xb   = (ushort*)(ws + 0);         // dead after QKV gemms
  ushort* Wqt  = (ushort*)(ws + 8 * MiB);
  ushort* Wkt  = (ushort*)(ws + 10 * MiB);
  ushort* Wvt  = (ushort*)(ws + 12 * MiB);
  ushort* Wot  = (ushort*)(ws + 14 * MiB);  // live to end
  float* qpre  = (float*)(ws + 16 * MiB);   // dead after conv
  float* kpre  = (float*)(ws + 32 * MiB);
  float* vpre  = (float*)(ws + 48 * MiB);
  float* qn    = (float*)(ws + 64 * MiB);   // then Qeff in-place
  float* kn    = (float*)(ws + 80 * MiB);   // then Zt in-place
  float* vn    = (float*)(ws + 96 * MiB);   // dead after prep1
  float* beta  = (float*)(ws + 112 * MiB);  // 256 KiB
  float* Wkbuf = (float*)(ws + 16 * MiB);   // over qpre, dead after prep2c
  float* U0buf = (float*)(ws + 32 * MiB);   // over kpre
  float* Lbuf  = (float*)(ws + 48 * MiB);   // over vpre; later Pt
  float* O0buf = (float*)(ws + 96 * MiB);   // over vn (after prep1)
  float* Sbuf  = (float*)(ws + 16 * MiB);   // over Wkbuf (dead after prep2c)
  ushort* ob   = (ushort*)(ws + 0);         // over xb (after QKV gemms)

  hipLaunchKernelGGL(cast_kernel, dim3(M_ * D_ / 4 / 256), dim3(256), 0, stream,
                     x, xb, M_ * D_ / 4);
  dim3 tb(32, 8);
  hipLaunchKernelGGL(transpose_cast_kernel, dim3(32, 32), tb, 0, stream, Wq, Wqt, D_, D_);
  hipLaunchKernelGGL(transpose_cast_kernel, dim3(32, 32), tb, 0, stream, Wk, Wkt, D_, D_);
  hipLaunchKernelGGL(transpose_cast_kernel, dim3(32, 32), tb, 0, stream, Wv, Wvt, D_, D_);
  hipLaunchKernelGGL(transpose_cast_kernel, dim3(32, 32), tb, 0, stream, Wo, Wot, D_, D_);

  dim3 gg(M_ / 128, D_ / 128);
  hipLaunchKernelGGL(gemm128_kernel, gg, dim3(256), 0, stream, xb, Wqt, qpre, M_, D_, D_);
  hipLaunchKernelGGL(gemm128_kernel, gg, dim3(256), 0, stream, xb, Wkt, kpre, M_, D_, D_);
  hipLaunchKernelGGL(gemm128_kernel, gg, dim3(256), 0, stream, xb, Wvt, vpre, M_, D_, D_);

  hipLaunchKernelGGL(beta_kernel, dim3(M_), dim3(256), 0, stream, x, Wb, beta);
  hipLaunchKernelGGL(conv_kernel, dim3(M_), dim3(256), 0, stream,
                     qpre, kpre, vpre, cq, ck, cv, qn, kn, vn);

  hipLaunchKernelGGL(prep1_kernel, dim3(NCH_), dim3(256), 0, stream,
                     kn, vn, beta, Wkbuf, U0buf);
  hipLaunchKernelGGL(prep2a_kernel, dim3(NCH_), dim3(256), 0, stream, qn, kn, Lbuf);
  hipLaunchKernelGGL(prep2b_kernel, dim3(NCH_), dim3(256), 0, stream,
                     Lbuf, Wkbuf, U0buf, qn, O0buf);
  hipLaunchKernelGGL(prep2c_kernel, dim3(NCH_), dim3(256), 0, stream,
                     kn, Wkbuf, U0buf, Lbuf);
  hipLaunchKernelGGL(state_kernel, dim3(B_ * H_ * 4), dim3(256), 0, stream,
                     kn, Lbuf, Sbuf);
  hipLaunchKernelGGL(ophase_kernel, dim3(NCH_), dim3(256), 0, stream,
                     qn, Sbuf, O0buf, rg, ob);
  hipLaunchKernelGGL(gemm128_kernel, gg, dim3(256), 0, stream, ob, Wot, out, M_, D_, D_);
}

// Round 6
// 523.130 us; speedup vs baseline: 1.7761x; 1.2153x over previous
//
#include <hip/hip_runtime.h>
#include <hip/hip_bf16.h>
#include <math.h>

#define B_ 2
#define T_ 2048
#define D_ 1024
#define H_ 16
#define DH_ 64
#define M_ (B_*T_)   // 4096 rows
#define NC_ 32       // chunks per sequence (T/64)
#define CS_ 64       // chunk size
#define NCH_ (B_*H_*NC_)  // 1024 chunk-heads
#define QKVN_ 3072   // fused QKV gemm N

typedef __attribute__((ext_vector_type(4))) float floatx4;
typedef __attribute__((ext_vector_type(8))) short short8;

__device__ __forceinline__ ushort f2bf(float f) {
  union { float f; unsigned u; } c; c.f = f;
  unsigned r = (c.u + 0x7FFFu + ((c.u >> 16) & 1u)) >> 16;  // RNE
  return (ushort)r;
}
__device__ __forceinline__ float siluf(float u) {
  return u / (1.f + __expf(-u));
}
__device__ __forceinline__ float f4get(const float4& v, int j) {
  return j == 0 ? v.x : j == 1 ? v.y : j == 2 ? v.z : v.w;
}

// ---------- cast f32 -> bf16, n4 = n/4 ----------
__global__ void cast_kernel(const float* __restrict__ in, ushort* __restrict__ out, int n4) {
  int i = blockIdx.x * blockDim.x + threadIdx.x;
  if (i >= n4) return;
  float4 v = ((const float4*)in)[i];
  ushort4 o;
  o.x = f2bf(v.x); o.y = f2bf(v.y); o.z = f2bf(v.z); o.w = f2bf(v.w);
  ((ushort4*)out)[i] = o;
}

// ---------- transpose + cast: W[K][N] f32 -> Wt[N][K] bf16 ----------
__global__ void transpose_cast_kernel(const float* __restrict__ W, ushort* __restrict__ Wt,
                                      int K, int N) {
  __shared__ float tile[32][33];
  int tx = threadIdx.x, ty = threadIdx.y;
  int n0 = blockIdx.x * 32, k0 = blockIdx.y * 32;
  #pragma unroll
  for (int i = 0; i < 32; i += 8)
    tile[ty + i][tx] = W[(size_t)(k0 + ty + i) * N + n0 + tx];
  __syncthreads();
  #pragma unroll
  for (int i = 0; i < 32; i += 8)
    Wt[(size_t)(n0 + ty + i) * K + k0 + tx] = f2bf(tile[tx][ty + i]);
}

// ---------- transpose Wb[1024][16] -> WbT[16][1024] (fp32) ----------
__global__ void transpose_wb_kernel(const float* __restrict__ Wb, float* __restrict__ WbT) {
  int bk = blockIdx.x;           // 64 blocks, 16 k-rows each
  int tid = threadIdx.x;
  int kl = tid >> 4, h = tid & 15;
  int k = bk * 16 + kl;
  WbT[(size_t)h * D_ + k] = Wb[(size_t)k * H_ + h];
}

// ---------- m97-style bf16 MFMA GEMM: C[M][N] = A[M][K]*B[K][N], Bt = B^T [N][K] ----------
__global__ __launch_bounds__(256) void gemm128_kernel(
    const ushort* __restrict__ A, const ushort* __restrict__ Bt,
    float* __restrict__ C, int M, int N, int K) {
  __shared__ ushort lA[128 * 32];
  __shared__ ushort lB[128 * 32];
  int tid = threadIdx.x;
  int wave = tid >> 6, lane = tid & 63;
  int wm = wave >> 1, wn = wave & 1;
  int m16 = lane & 15, q4 = lane >> 4;
  int bm = blockIdx.x, bn = blockIdx.y;
  floatx4 acc[4][4] = {};
  int srow = tid >> 2;
  int sk8 = tid & 3;
  const ushort* Ag = A + (size_t)(bm * 128 + srow) * K + sk8 * 8;
  const ushort* Bg = Bt + (size_t)(bn * 128 + srow) * K + sk8 * 8;
  ushort* lAp = lA + tid * 8;
  ushort* lBp = lB + tid * 8;
  for (int k0 = 0; k0 < K; k0 += 32) {
    __builtin_amdgcn_global_load_lds(
        (const __attribute__((address_space(1))) void*)(Ag + k0),
        (__attribute__((address_space(3))) void*)lAp, 16, 0, 0);
    __builtin_amdgcn_global_load_lds(
        (const __attribute__((address_space(1))) void*)(Ag + (size_t)64 * K + k0),
        (__attribute__((address_space(3))) void*)(lAp + 2048), 16, 0, 0);
    __builtin_amdgcn_global_load_lds(
        (const __attribute__((address_space(1))) void*)(Bg + k0),
        (__attribute__((address_space(3))) void*)lBp, 16, 0, 0);
    __builtin_amdgcn_global_load_lds(
        (const __attribute__((address_space(1))) void*)(Bg + (size_t)64 * K + k0),
        (__attribute__((address_space(3))) void*)(lBp + 2048), 16, 0, 0);
    __syncthreads();
    short8 af[4], bf[4];
    #pragma unroll
    for (int i = 0; i < 4; i++) {
      af[i] = *(short8*)&lA[(wm * 64 + i * 16 + m16) * 32 + q4 * 8];
      bf[i] = *(short8*)&lB[(wn * 64 + i * 16 + m16) * 32 + q4 * 8];
    }
    #pragma unroll
    for (int mi = 0; mi < 4; mi++)
      #pragma unroll
      for (int nj = 0; nj < 4; nj++)
        acc[mi][nj] = __builtin_amdgcn_mfma_f32_16x16x32_bf16(af[mi], bf[nj], acc[mi][nj], 0, 0, 0);
    __syncthreads();
  }
  float* Cb = C + (size_t)(bm * 128) * N + bn * 128;
  #pragma unroll
  for (int mi = 0; mi < 4; mi++) {
    #pragma unroll
    for (int nj = 0; nj < 4; nj++) {
      #pragma unroll
      for (int i = 0; i < 4; i++) {
        int row = wm * 64 + mi * 16 + q4 * 4 + i;
        int col = wn * 64 + nj * 16 + m16;
        Cb[(size_t)row * N + col] = acc[mi][nj][i];
      }
    }
  }
}

// ---------- beta = sigmoid(x @ Wb), WbT[16][1024], conflict-free ----------
__global__ __launch_bounds__(256) void beta_kernel(const float* __restrict__ x,
                                                   const float* __restrict__ WbT,
                                                   float* __restrict__ beta) {
  __shared__ __align__(16) float xs[D_];
  int row = blockIdx.x;
  int tid = threadIdx.x;
  ((float4*)xs)[tid] = ((const float4*)(x + (size_t)row * D_))[tid];
  __syncthreads();
  int h = tid >> 4;      // 0..15
  int seg = tid & 15;    // 16 segments of 64 floats
  const float4* wrow = (const float4*)(WbT + (size_t)h * D_) + seg * 16;
  const float4* xsrow = (const float4*)xs + seg * 16;
  float s = 0.f;
  #pragma unroll
  for (int j = 0; j < 16; j++) {
    int jj = (j + seg) & 15;   // rotate: 2-way LDS bank aliasing (free) instead of 16-way
    float4 xv = xsrow[jj];
    float4 wv = wrow[jj];
    s += xv.x * wv.x + xv.y * wv.y + xv.z * wv.z + xv.w * wv.w;
  }
  #pragma unroll
  for (int off = 8; off; off >>= 1) s += __shfl_down(s, off, 16);
  if (seg == 0) beta[(size_t)row * H_ + h] = 1.f / (1.f + __expf(-s));
}

// ---------- causal depthwise conv(K=4) + silu, l2norm for q,k ----------
// reads fused qkv buffer [M][3072]: q cols 0..1023, k 1024..2047, v 2048..3071
__global__ __launch_bounds__(256) void conv_kernel(
    const float* __restrict__ qkv,
    const float* __restrict__ cq, const float* __restrict__ ck, const float* __restrict__ cv,
    float* __restrict__ qo, float* __restrict__ ko, float* __restrict__ vo) {
  int row = blockIdx.x;
  int t = row & (T_ - 1);
  int tid = threadIdx.x;
  int c0 = tid * 4;
  float4 zf = {0.f, 0.f, 0.f, 0.f};
  float4 xq[4], xk[4], xv[4];
  #pragma unroll
  for (int i = 0; i < 4; i++) {
    int tt = t - 3 + i;
    if (tt >= 0) {
      const float* rp = qkv + (size_t)(row - 3 + i) * QKVN_;
      xq[i] = *(const float4*)(rp + c0);
      xk[i] = *(const float4*)(rp + 1024 + c0);
      xv[i] = *(const float4*)(rp + 2048 + c0);
    } else { xq[i] = zf; xk[i] = zf; xv[i] = zf; }
  }
  float yq[4], yk[4], yv[4];
  float pq = 0.f, pk = 0.f;
  #pragma unroll
  for (int j = 0; j < 4; j++) {
    float4 wq = ((const float4*)cq)[c0 + j];
    float4 wk = ((const float4*)ck)[c0 + j];
    float4 wv = ((const float4*)cv)[c0 + j];
    float sq = 0.f, sk = 0.f, sv = 0.f;
    #pragma unroll
    for (int i = 0; i < 4; i++) {
      sq += f4get(wq, i) * f4get(xq[i], j);
      sk += f4get(wk, i) * f4get(xk[i], j);
      sv += f4get(wv, i) * f4get(xv[i], j);
    }
    yq[j] = siluf(sq); yk[j] = siluf(sk); yv[j] = siluf(sv);
    pq += yq[j] * yq[j]; pk += yk[j] * yk[j];
  }
  #pragma unroll
  for (int off = 1; off < 16; off <<= 1) {
    pq += __shfl_xor(pq, off, 16);
    pk += __shfl_xor(pk, off, 16);
  }
  float rq = rsqrtf(pq + 1e-6f), rk = rsqrtf(pk + 1e-6f);
  float4 oq = {yq[0]*rq, yq[1]*rq, yq[2]*rq, yq[3]*rq};
  float4 okk = {yk[0]*rk, yk[1]*rk, yk[2]*rk, yk[3]*rk};
  float4 ov = {yv[0], yv[1], yv[2], yv[3]};
  *(float4*)(qo + (size_t)row * D_ + c0) = oq;
  *(float4*)(ko + (size_t)row * D_ + c0) = okk;
  *(float4*)(vo + (size_t)row * D_ + c0) = ov;
}

// ================= chunked delta rule =================
// prep1: A = strict_tril(diag(b)KK^T); solve (I+A)Wk = diag(b)K and (I+A)U0 = diag(b)V
__global__ __launch_bounds__(256) void prep1_kernel(
    const float* __restrict__ kn, const float* __restrict__ vn,
    const float* __restrict__ beta,
    float* __restrict__ Wkbuf, float* __restrict__ U0buf) {
  __shared__ float Ksh[64][68];
  __shared__ float AT[64 * 64];   // AT[i*64+t] = A[t][i] for t>i, else 0
  __shared__ float XPK[16][68];
  __shared__ float XPV[16][68];
  __shared__ float bsh[64];
  int ch = blockIdx.x;
  int b = ch >> 9, h = (ch >> 5) & 15, c = ch & 31;
  int tid = threadIdx.x;
  int t = tid >> 2, seg = tid & 3;
  const float* krow = kn + ((size_t)(b * T_ + c * 64 + t)) * D_ + h * 64;
  #pragma unroll
  for (int g = 0; g < 4; g++)
    *(float4*)&Ksh[t][seg * 16 + 4 * g] = *(const float4*)&krow[seg * 16 + 4 * g];
  if (tid < 64) bsh[tid] = beta[((size_t)(b * T_ + c * 64 + tid)) * H_ + h];
  __syncthreads();
  {
    int s0 = seg * 16;
    float acc[16];
    #pragma unroll
    for (int r = 0; r < 16; r++) acc[r] = 0.f;
    for (int d4 = 0; d4 < 16; d4++) {
      float4 kt = *(float4*)&Ksh[t][d4 * 4];
      #pragma unroll
      for (int r = 0; r < 16; r++) {
        float4 ks = *(float4*)&Ksh[s0 + r][d4 * 4];
        acc[r] += kt.x * ks.x + kt.y * ks.y + kt.z * ks.z + kt.w * ks.w;
      }
    }
    float bt = bsh[t];
    #pragma unroll
    for (int r = 0; r < 16; r++) {
      int s = s0 + r;
      AT[s * 64 + t] = (t > s) ? bt * acc[r] : 0.f;
    }
  }
  float xk[16], xv[16];
  {
    float bt = bsh[t];
    const float* vrow = vn + ((size_t)(b * T_ + c * 64 + t)) * D_ + h * 64;
    #pragma unroll
    for (int g = 0; g < 4; g++) {
      float4 kv = *(float4*)&Ksh[t][seg * 16 + 4 * g];
      float4 vv = *(const float4*)&vrow[seg * 16 + 4 * g];
      xk[4*g+0] = bt * kv.x; xk[4*g+1] = bt * kv.y; xk[4*g+2] = bt * kv.z; xk[4*g+3] = bt * kv.w;
      xv[4*g+0] = bt * vv.x; xv[4*g+1] = bt * vv.y; xv[4*g+2] = bt * vv.z; xv[4*g+3] = bt * vv.w;
    }
  }
  __syncthreads();
  int wave = tid >> 6, lane = tid & 63;
  int r_loc = lane >> 2;
  for (int p = 0; p < 4; p++) {
    if (wave == p) {
      float a[16];
      #pragma unroll
      for (int i2 = 0; i2 < 16; i2++) a[i2] = AT[(p * 16 + i2) * 64 + t];
      #pragma unroll
      for (int i2 = 0; i2 < 16; i2++) {
        int src = i2 * 4 + (lane & 3);
        #pragma unroll
        for (int cc = 0; cc < 16; cc++) {
          float xki = __shfl(xk[cc], src, 64);
          float xvi = __shfl(xv[cc], src, 64);
          if (r_loc > i2) {
            xk[cc] = fmaf(-a[i2], xki, xk[cc]);
            xv[cc] = fmaf(-a[i2], xvi, xv[cc]);
          }
        }
      }
      #pragma unroll
      for (int g = 0; g < 4; g++) {
        float4 k4 = {xk[4*g+0], xk[4*g+1], xk[4*g+2], xk[4*g+3]};
        float4 v4 = {xv[4*g+0], xv[4*g+1], xv[4*g+2], xv[4*g+3]};
        *(float4*)&XPK[r_loc][seg * 16 + 4 * g] = k4;
        *(float4*)&XPV[r_loc][seg * 16 + 4 * g] = v4;
      }
    }
    __syncthreads();
    if (wave > p) {
      float a[16];
      #pragma unroll
      for (int i2 = 0; i2 < 16; i2++) a[i2] = AT[(p * 16 + i2) * 64 + t];
      #pragma unroll
      for (int i2 = 0; i2 < 16; i2++) {
        float ai = a[i2];
        #pragma unroll
        for (int g = 0; g < 4; g++) {
          float4 xk4 = *(float4*)&XPK[i2][seg * 16 + 4 * g];
          float4 xv4 = *(float4*)&XPV[i2][seg * 16 + 4 * g];
          xk[4*g+0] -= ai * xk4.x; xk[4*g+1] -= ai * xk4.y;
          xk[4*g+2] -= ai * xk4.z; xk[4*g+3] -= ai * xk4.w;
          xv[4*g+0] -= ai * xv4.x; xv[4*g+1] -= ai * xv4.y;
          xv[4*g+2] -= ai * xv4.z; xv[4*g+3] -= ai * xv4.w;
        }
      }
    }
    __syncthreads();
  }
  #pragma unroll
  for (int g = 0; g < 4; g++) {
    float4 k4 = {xk[4*g+0], xk[4*g+1], xk[4*g+2], xk[4*g+3]};
    float4 v4 = {xv[4*g+0], xv[4*g+1], xv[4*g+2], xv[4*g+3]};
    *(float4*)&Wkbuf[(size_t)ch * 4096 + t * 64 + seg * 16 + 4 * g] = k4;
    *(float4*)&U0buf[(size_t)ch * 4096 + t * 64 + seg * 16 + 4 * g] = v4;
  }
}

// prep2a: L = tril(Q K^T) (incl diagonal)
__global__ __launch_bounds__(256) void prep2a_kernel(
    const float* __restrict__ qn, const float* __restrict__ kn,
    float* __restrict__ Lbuf) {
  __shared__ float Qsh[64][68];
  __shared__ float Ksh[64][68];
  int ch = blockIdx.x;
  int b = ch >> 9, h = (ch >> 5) & 15, c = ch & 31;
  int tid = threadIdx.x;
  int t = tid >> 2, seg = tid & 3;
  const float* qrow = qn + ((size_t)(b * T_ + c * 64 + t)) * D_ + h * 64;
  const float* krow = kn + ((size_t)(b * T_ + c * 64 + t)) * D_ + h * 64;
  #pragma unroll
  for (int g = 0; g < 4; g++) {
    *(float4*)&Qsh[t][seg * 16 + 4 * g] = *(const float4*)&qrow[seg * 16 + 4 * g];
    *(float4*)&Ksh[t][seg * 16 + 4 * g] = *(const float4*)&krow[seg * 16 + 4 * g];
  }
  __syncthreads();
  int s0 = seg * 16;
  float acc[16];
  #pragma unroll
  for (int r = 0; r < 16; r++) acc[r] = 0.f;
  for (int d4 = 0; d4 < 16; d4++) {
    float4 qt = *(float4*)&Qsh[t][d4 * 4];
    #pragma unroll
    for (int r = 0; r < 16; r++) {
      float4 ks = *(float4*)&Ksh[s0 + r][d4 * 4];
      acc[r] += qt.x * ks.x + qt.y * ks.y + qt.z * ks.z + qt.w * ks.w;
    }
  }
  #pragma unroll
  for (int g = 0; g < 4; g++) {
    float4 ov;
    ov.x = (s0 + 4*g + 0 <= t) ? acc[4*g+0] : 0.f;
    ov.y = (s0 + 4*g + 1 <= t) ? acc[4*g+1] : 0.f;
    ov.z = (s0 + 4*g + 2 <= t) ? acc[4*g+2] : 0.f;
    ov.w = (s0 + 4*g + 3 <= t) ? acc[4*g+3] : 0.f;
    *(float4*)&Lbuf[(size_t)ch * 4096 + t * 64 + s0 + 4 * g] = ov;
  }
}

// prep2b: O0 = L U0 ; Qeff = Q - L Wk (in-place over qn)
__global__ __launch_bounds__(256) void prep2b_kernel(
    const float* __restrict__ Lbuf, const float* __restrict__ Wkbuf,
    const float* __restrict__ U0buf, float* qn,
    float* __restrict__ O0buf) {
  __shared__ float Lsh[64][68];
  __shared__ float Wksh[64][68];
  __shared__ float U0sh[64][68];
  int ch = blockIdx.x;
  int b = ch >> 9, h = (ch >> 5) & 15, c = ch & 31;
  int tid = threadIdx.x;
  int t = tid >> 2, seg = tid & 3;
  #pragma unroll
  for (int g = 0; g < 4; g++) {
    int o = t * 64 + seg * 16 + 4 * g;
    *(float4*)&Lsh[t][seg * 16 + 4 * g]  = *(const float4*)&Lbuf[(size_t)ch * 4096 + o];
    *(float4*)&Wksh[t][seg * 16 + 4 * g] = *(const float4*)&Wkbuf[(size_t)ch * 4096 + o];
    *(float4*)&U0sh[t][seg * 16 + 4 * g] = *(const float4*)&U0buf[(size_t)ch * 4096 + o];
  }
  __syncthreads();
  int j0 = seg * 16;
  float o0[16], lw[16];
  #pragma unroll
  for (int r = 0; r < 16; r++) { o0[r] = 0.f; lw[r] = 0.f; }
  for (int s = 0; s <= t; s++) {
    float l = Lsh[t][s];
    #pragma unroll
    for (int g = 0; g < 4; g++) {
      float4 u = *(float4*)&U0sh[s][j0 + 4 * g];
      float4 w = *(float4*)&Wksh[s][j0 + 4 * g];
      o0[4*g+0] += l * u.x; o0[4*g+1] += l * u.y; o0[4*g+2] += l * u.z; o0[4*g+3] += l * u.w;
      lw[4*g+0] += l * w.x; lw[4*g+1] += l * w.y; lw[4*g+2] += l * w.z; lw[4*g+3] += l * w.w;
    }
  }
  float* qrow = qn + ((size_t)(b * T_ + c * 64 + t)) * D_ + h * 64;
  #pragma unroll
  for (int g = 0; g < 4; g++) {
    float4 qv = *(const float4*)&qrow[j0 + 4 * g];
    qv.x -= lw[4*g+0]; qv.y -= lw[4*g+1]; qv.z -= lw[4*g+2]; qv.w -= lw[4*g+3];
    *(float4*)&qrow[j0 + 4 * g] = qv;
    float4 ov = {o0[4*g+0], o0[4*g+1], o0[4*g+2], o0[4*g+3]};
    *(float4*)&O0buf[(size_t)ch * 4096 + t * 64 + j0 + 4 * g] = ov;
  }
}

// prep2c (TRANSPOSED outputs): Pt[e][d] = I - Wk^T K ; Zt[j][d] = U0^T K
__global__ __launch_bounds__(256) void prep2c_kernel(
    float* kn, const float* __restrict__ Wkbuf,
    const float* __restrict__ U0buf, float* __restrict__ Pbuf) {
  __shared__ float Ksh[64][68];
  __shared__ float Wksh[64][68];
  __shared__ float U0sh[64][68];
  int ch = blockIdx.x;
  int b = ch >> 9, h = (ch >> 5) & 15, c = ch & 31;
  int tid = threadIdx.x;
  int t = tid >> 2, seg = tid & 3;
  const float* krow = kn + ((size_t)(b * T_ + c * 64 + t)) * D_ + h * 64;
  #pragma unroll
  for (int g = 0; g < 4; g++) {
    int o = t * 64 + seg * 16 + 4 * g;
    *(float4*)&Ksh[t][seg * 16 + 4 * g]  = *(const float4*)&krow[seg * 16 + 4 * g];
    *(float4*)&Wksh[t][seg * 16 + 4 * g] = *(const float4*)&Wkbuf[(size_t)ch * 4096 + o];
    *(float4*)&U0sh[t][seg * 16 + 4 * g] = *(const float4*)&U0buf[(size_t)ch * 4096 + o];
  }
  __syncthreads();
  int d0 = seg * 16;
  float accP[16], accZ[16];
  #pragma unroll
  for (int r = 0; r < 16; r++) { accP[r] = 0.f; accZ[r] = 0.f; }
  for (int s = 0; s < 64; s++) {
    float w = Wksh[s][t];
    float u = U0sh[s][t];
    #pragma unroll
    for (int g = 0; g < 4; g++) {
      float4 k4 = *(float4*)&Ksh[s][d0 + 4 * g];
      accP[4*g+0] += w * k4.x; accP[4*g+1] += w * k4.y; accP[4*g+2] += w * k4.z; accP[4*g+3] += w * k4.w;
      accZ[4*g+0] += u * k4.x; accZ[4*g+1] += u * k4.y; accZ[4*g+2] += u * k4.z; accZ[4*g+3] += u * k4.w;
    }
  }
  float* zrow = kn + ((size_t)(b * T_ + c * 64 + t)) * D_ + h * 64;
  #pragma unroll
  for (int g = 0; g < 4; g++) {
    float4 pv;
    pv.x = ((d0 + 4*g + 0) == t ? 1.f : 0.f) - accP[4*g+0];
    pv.y = ((d0 + 4*g + 1) == t ? 1.f : 0.f) - accP[4*g+1];
    pv.z = ((d0 + 4*g + 2) == t ? 1.f : 0.f) - accP[4*g+2];
    pv.w = ((d0 + 4*g + 3) == t ? 1.f : 0.f) - accP[4*g+3];
    *(float4*)&Pbuf[(size_t)ch * 4096 + t * 64 + d0 + 4 * g] = pv;
    float4 zv = {accZ[4*g+0], accZ[4*g+1], accZ[4*g+2], accZ[4*g+3]};
    *(float4*)&zrow[d0 + 4 * g] = zv;
  }
}

// ---------- state scan: S_{c+1} = P_c S_c + Z_c; store S_c transposed [ch][j][d] ----------
__global__ __launch_bounds__(256) void state_kernel(
    const float* __restrict__ kn /*Zt*/, const float* __restrict__ Pbuf /*Pt*/,
    float* __restrict__ Sbuf) {
  __shared__ float PT[64][68];
  __shared__ float STt[16][68];
  int bid = blockIdx.x;
  int js = bid & 3, h = (bid >> 2) & 15, b = bid >> 6;
  int bh = b * H_ + h;
  int tid = threadIdx.x;
  int d = tid & 63, jq = tid >> 6;
  int j0 = jq * 4;
  float s[4] = {0.f, 0.f, 0.f, 0.f};
  float4 pn[4];
  #pragma unroll
  for (int g = 0; g < 4; g++)
    pn[g] = *(const float4*)&Pbuf[(size_t)(bh * NC_) * 4096 + (size_t)(tid + g * 256) * 4];
  for (int c = 0; c < NC_; c++) {
    size_t ch = (size_t)bh * NC_ + c;
    #pragma unroll
    for (int i = 0; i < 4; i++) {
      Sbuf[ch * 4096 + (size_t)(js * 16 + j0 + i) * 64 + d] = s[i];
      STt[j0 + i][d] = s[i];
    }
    #pragma unroll
    for (int g = 0; g < 4; g++) {
      int idx = tid + g * 256;
      *(float4*)&PT[idx >> 4][(idx & 15) * 4] = pn[g];
    }
    __syncthreads();
    if (c + 1 < NC_) {
      #pragma unroll
      for (int g = 0; g < 4; g++)
        pn[g] = *(const float4*)&Pbuf[(ch + 1) * 4096 + (size_t)(tid + g * 256) * 4];
    }
    float acc[4];
    #pragma unroll
    for (int i = 0; i < 4; i++)
      acc[i] = kn[((size_t)(b * T_ + c * 64 + js * 16 + j0 + i)) * D_ + h * 64 + d];
    #pragma unroll 4
    for (int e4 = 0; e4 < 16; e4++) {
      float p0 = PT[e4 * 4 + 0][d];
      float p1 = PT[e4 * 4 + 1][d];
      float p2 = PT[e4 * 4 + 2][d];
      float p3 = PT[e4 * 4 + 3][d];
      #pragma unroll
      for (int i = 0; i < 4; i++) {
        float4 st = *(float4*)&STt[j0 + i][e4 * 4];
        acc[i] += p0 * st.x + p1 * st.y + p2 * st.z + p3 * st.w;
      }
    }
    __syncthreads();
    #pragma unroll
    for (int i = 0; i < 4; i++) s[i] = acc[i];
  }
}

// ---------- O = O0 + Qeff*S_c (S transposed layout), fused RMSNorm + bf16 cast ----------
__global__ __launch_bounds__(256) void ophase_kernel(
    const float* __restrict__ qn /*Qeff*/, const float* __restrict__ Sbuf,
    const float* __restrict__ O0buf, const float* __restrict__ rms_g,
    ushort* __restrict__ ob) {
  __shared__ float Ssht[64][68];
  __shared__ float QshT[64][65];
  __shared__ float part[64][4];
  int ch = blockIdx.x;
  int b = ch >> 9, h = (ch >> 5) & 15, c = ch & 31;
  int tid = threadIdx.x;
  int t = tid & 63, jg = tid >> 6;
  #pragma unroll
  for (int g = 0; g < 4; g++) {
    int idx = tid + g * 256;
    *(float4*)&Ssht[idx >> 4][(idx & 15) * 4] =
        *(const float4*)&Sbuf[(size_t)ch * 4096 + (size_t)idx * 4];
  }
  #pragma unroll
  for (int g = 0; g < 4; g++) {
    int idx = tid + g * 256;
    int row = idx >> 4, c4 = idx & 15;
    float4 qv = *(const float4*)&qn[((size_t)(b * T_ + c * 64 + row)) * D_ + h * 64 + c4 * 4];
    QshT[c4 * 4 + 0][row] = qv.x;
    QshT[c4 * 4 + 1][row] = qv.y;
    QshT[c4 * 4 + 2][row] = qv.z;
    QshT[c4 * 4 + 3][row] = qv.w;
  }
  float o[16];
  #pragma unroll
  for (int g = 0; g < 4; g++) {
    float4 o4 = *(const float4*)&O0buf[(size_t)ch * 4096 + t * 64 + jg * 16 + g * 4];
    o[4*g+0] = o4.x; o[4*g+1] = o4.y; o[4*g+2] = o4.z; o[4*g+3] = o4.w;
  }
  __syncthreads();
  for (int d4 = 0; d4 < 16; d4++) {
    float q0 = QshT[d4 * 4 + 0][t];
    float q1 = QshT[d4 * 4 + 1][t];
    float q2 = QshT[d4 * 4 + 2][t];
    float q3 = QshT[d4 * 4 + 3][t];
    #pragma unroll
    for (int r = 0; r < 16; r++) {
      float4 s4 = *(float4*)&Ssht[jg * 16 + r][d4 * 4];
      o[r] += q0 * s4.x + q1 * s4.y + q2 * s4.z + q3 * s4.w;
    }
  }
  float ss = 0.f;
  #pragma unroll
  for (int r = 0; r < 16; r++) ss += o[r] * o[r];
  part[t][jg] = ss;
  __syncthreads();
  float tot = part[t][0] + part[t][1] + part[t][2] + part[t][3];
  float sc = rsqrtf(tot * (1.f / 64.f) + 1e-6f);
  ushort* orow = &ob[((size_t)(b * T_ + c * 64 + t)) * D_ + h * 64];
  #pragma unroll
  for (int g = 0; g < 4; g++) {
    float4 g4 = *(const float4*)&rms_g[jg * 16 + g * 4];
    ushort4 r4;
    r4.x = f2bf(o[4*g+0] * sc * g4.x); r4.y = f2bf(o[4*g+1] * sc * g4.y);
    r4.z = f2bf(o[4*g+2] * sc * g4.z); r4.w = f2bf(o[4*g+3] * sc * g4.w);
    *(ushort4*)&orow[jg * 16 + g * 4] = r4;
  }
}

extern "C" void kernel_launch(void* const* d_in, const int* in_sizes, int n_in,
                              void* d_out, int out_size, void* d_ws, size_t ws_size,
                              hipStream_t stream) {
  const float* x  = (const float*)d_in[0];
  const float* Wq = (const float*)d_in[1];
  const float* Wk = (const float*)d_in[2];
  const float* Wv = (const float*)d_in[3];
  const float* Wb = (const float*)d_in[4];
  const float* cq = (const float*)d_in[5];
  const float* ck = (const float*)d_in[6];
  const float* cv = (const float*)d_in[7];
  const float* rg = (const float*)d_in[8];
  const float* Wo = (const float*)d_in[9];
  float* out = (float*)d_out;
  char* ws = (char*)d_ws;
  const size_t MiB = 1ull << 20;
  ushort* xb   = (ushort*)(ws + 0);         // dead after QKV gemm
  ushort* Wqt  = (ushort*)(ws + 8 * MiB);   // Wqt/Wkt/Wvt contiguous = [3072][1024] bf16
  ushort* Wkt  = (ushort*)(ws + 10 * MiB);
  ushort* Wvt  = (ushort*)(ws + 12 * MiB);
  ushort* Wot  = (ushort*)(ws + 14 * MiB);  // live to end
  float* qkv   = (float*)(ws + 16 * MiB);   // [4096][3072] fp32, dead after conv
  float* qn    = (float*)(ws + 64 * MiB);   // then Qeff in-place
  float* kn    = (float*)(ws + 80 * MiB);   // then Zt in-place
  float* vn    = (float*)(ws + 96 * MiB);   // dead after prep1
  float* beta  = (float*)(ws + 112 * MiB);  // 256 KiB
  float* WbT   = (float*)(ws + 112 * MiB + 256 * 1024);  // 64 KiB
  float* Wkbuf = (float*)(ws + 16 * MiB);   // over qkv (dead after conv)
  float* U0buf = (float*)(ws + 32 * MiB);
  float* Lbuf  = (float*)(ws + 48 * MiB);   // later Pt
  float* O0buf = (float*)(ws + 96 * MiB);   // over vn (after prep1)
  float* Sbuf  = (float*)(ws + 16 * MiB);   // over Wkbuf (dead after prep2c)
  ushort* ob   = (ushort*)(ws + 0);         // over xb (after QKV gemm)

  hipLaunchKernelGGL(cast_kernel, dim3(M_ * D_ / 4 / 256), dim3(256), 0, stream,
                     x, xb, M_ * D_ / 4);
  dim3 tb(32, 8);
  hipLaunchKernelGGL(transpose_cast_kernel, dim3(32, 32), tb, 0, stream, Wq, Wqt, D_, D_);
  hipLaunchKernelGGL(transpose_cast_kernel, dim3(32, 32), tb, 0, stream, Wk, Wkt, D_, D_);
  hipLaunchKernelGGL(transpose_cast_kernel, dim3(32, 32), tb, 0, stream, Wv, Wvt, D_, D_);
  hipLaunchKernelGGL(transpose_cast_kernel, dim3(32, 32), tb, 0, stream, Wo, Wot, D_, D_);
  hipLaunchKernelGGL(transpose_wb_kernel, dim3(64), dim3(256), 0, stream, Wb, WbT);

  // fused QKV gemm: N=3072, 768 blocks (~3/CU)
  hipLaunchKernelGGL(gemm128_kernel, dim3(M_ / 128, QKVN_ / 128), dim3(256), 0, stream,
                     xb, Wqt, qkv, M_, QKVN_, D_);

  hipLaunchKernelGGL(beta_kernel, dim3(M_), dim3(256), 0, stream, x, WbT, beta);
  hipLaunchKernelGGL(conv_kernel, dim3(M_), dim3(256), 0, stream,
                     qkv, cq, ck, cv, qn, kn, vn);

  hipLaunchKernelGGL(prep1_kernel, dim3(NCH_), dim3(256), 0, stream,
                     kn, vn, beta, Wkbuf, U0buf);
  hipLaunchKernelGGL(prep2a_kernel, dim3(NCH_), dim3(256), 0, stream, qn, kn, Lbuf);
  hipLaunchKernelGGL(prep2b_kernel, dim3(NCH_), dim3(256), 0, stream,
                     Lbuf, Wkbuf, U0buf, qn, O0buf);
  hipLaunchKernelGGL(prep2c_kernel, dim3(NCH_), dim3(256), 0, stream,
                     kn, Wkbuf, U0buf, Lbuf);
  hipLaunchKernelGGL(state_kernel, dim3(B_ * H_ * 4), dim3(256), 0, stream,
                     kn, Lbuf, Sbuf);
  hipLaunchKernelGGL(ophase_kernel, dim3(NCH_), dim3(256), 0, stream,
                     qn, Sbuf, O0buf, rg, ob);
  hipLaunchKernelGGL(gemm128_kernel, dim3(M_ / 128, D_ / 128), dim3(256), 0, stream,
                     ob, Wot, out, M_, D_, D_);
}

// Round 7
// 492.694 us; speedup vs baseline: 1.8859x; 1.0618x over previous
//
#include <hip/hip_runtime.h>
#include <hip/hip_bf16.h>
#include <math.h>

#define B_ 2
#define T_ 2048
#define D_ 1024
#define H_ 16
#define DH_ 64
#define M_ (B_*T_)   // 4096 rows
#define NC_ 32       // chunks per sequence (T/64)
#define CS_ 64       // chunk size
#define NCH_ (B_*H_*NC_)  // 1024 chunk-heads
#define QKVN_ 3072   // fused QKV gemm N

typedef __attribute__((ext_vector_type(4))) float floatx4;
typedef __attribute__((ext_vector_type(8))) short short8;

__device__ __forceinline__ ushort f2bf(float f) {
  union { float f; unsigned u; } c; c.f = f;
  unsigned r = (c.u + 0x7FFFu + ((c.u >> 16) & 1u)) >> 16;  // RNE
  return (ushort)r;
}
__device__ __forceinline__ float siluf(float u) {
  return u / (1.f + __expf(-u));
}
__device__ __forceinline__ float f4get(const float4& v, int j) {
  return j == 0 ? v.x : j == 1 ? v.y : j == 2 ? v.z : v.w;
}
// swizzled chunk index for K tiles: chunk c (0..15) of row r stored at c ^ (r>>4)
__device__ __forceinline__ int ksw(int r, int c) { return ((c ^ (r >> 4)) << 2); }

// ---------- cast f32 -> bf16, n4 = n/4 ----------
__global__ void cast_kernel(const float* __restrict__ in, ushort* __restrict__ out, int n4) {
  int i = blockIdx.x * blockDim.x + threadIdx.x;
  if (i >= n4) return;
  float4 v = ((const float4*)in)[i];
  ushort4 o;
  o.x = f2bf(v.x); o.y = f2bf(v.y); o.z = f2bf(v.z); o.w = f2bf(v.w);
  ((ushort4*)out)[i] = o;
}

// ---------- transpose + cast: W[K][N] f32 -> Wt[N][K] bf16 ----------
__global__ void transpose_cast_kernel(const float* __restrict__ W, ushort* __restrict__ Wt,
                                      int K, int N) {
  __shared__ float tile[32][33];
  int tx = threadIdx.x, ty = threadIdx.y;
  int n0 = blockIdx.x * 32, k0 = blockIdx.y * 32;
  #pragma unroll
  for (int i = 0; i < 32; i += 8)
    tile[ty + i][tx] = W[(size_t)(k0 + ty + i) * N + n0 + tx];
  __syncthreads();
  #pragma unroll
  for (int i = 0; i < 32; i += 8)
    Wt[(size_t)(n0 + ty + i) * K + k0 + tx] = f2bf(tile[tx][ty + i]);
}

// ---------- transpose Wb[1024][16] -> WbT[16][1024] (fp32) ----------
__global__ void transpose_wb_kernel(const float* __restrict__ Wb, float* __restrict__ WbT) {
  int bk = blockIdx.x;
  int tid = threadIdx.x;
  int kl = tid >> 4, h = tid & 15;
  int k = bk * 16 + kl;
  WbT[(size_t)h * D_ + k] = Wb[(size_t)k * H_ + h];
}

// ---------- m97-style bf16 MFMA GEMM: C[M][N] = A[M][K]*B[K][N], Bt = B^T [N][K] ----------
__global__ __launch_bounds__(256) void gemm128_kernel(
    const ushort* __restrict__ A, const ushort* __restrict__ Bt,
    float* __restrict__ C, int M, int N, int K) {
  __shared__ ushort lA[128 * 32];
  __shared__ ushort lB[128 * 32];
  int tid = threadIdx.x;
  int wave = tid >> 6, lane = tid & 63;
  int wm = wave >> 1, wn = wave & 1;
  int m16 = lane & 15, q4 = lane >> 4;
  int bm = blockIdx.x, bn = blockIdx.y;
  floatx4 acc[4][4] = {};
  int srow = tid >> 2;
  int sk8 = tid & 3;
  const ushort* Ag = A + (size_t)(bm * 128 + srow) * K + sk8 * 8;
  const ushort* Bg = Bt + (size_t)(bn * 128 + srow) * K + sk8 * 8;
  ushort* lAp = lA + tid * 8;
  ushort* lBp = lB + tid * 8;
  for (int k0 = 0; k0 < K; k0 += 32) {
    __builtin_amdgcn_global_load_lds(
        (const __attribute__((address_space(1))) void*)(Ag + k0),
        (__attribute__((address_space(3))) void*)lAp, 16, 0, 0);
    __builtin_amdgcn_global_load_lds(
        (const __attribute__((address_space(1))) void*)(Ag + (size_t)64 * K + k0),
        (__attribute__((address_space(3))) void*)(lAp + 2048), 16, 0, 0);
    __builtin_amdgcn_global_load_lds(
        (const __attribute__((address_space(1))) void*)(Bg + k0),
        (__attribute__((address_space(3))) void*)lBp, 16, 0, 0);
    __builtin_amdgcn_global_load_lds(
        (const __attribute__((address_space(1))) void*)(Bg + (size_t)64 * K + k0),
        (__attribute__((address_space(3))) void*)(lBp + 2048), 16, 0, 0);
    __syncthreads();
    short8 af[4], bf[4];
    #pragma unroll
    for (int i = 0; i < 4; i++) {
      af[i] = *(short8*)&lA[(wm * 64 + i * 16 + m16) * 32 + q4 * 8];
      bf[i] = *(short8*)&lB[(wn * 64 + i * 16 + m16) * 32 + q4 * 8];
    }
    #pragma unroll
    for (int mi = 0; mi < 4; mi++)
      #pragma unroll
      for (int nj = 0; nj < 4; nj++)
        acc[mi][nj] = __builtin_amdgcn_mfma_f32_16x16x32_bf16(af[mi], bf[nj], acc[mi][nj], 0, 0, 0);
    __syncthreads();
  }
  float* Cb = C + (size_t)(bm * 128) * N + bn * 128;
  #pragma unroll
  for (int mi = 0; mi < 4; mi++) {
    #pragma unroll
    for (int nj = 0; nj < 4; nj++) {
      #pragma unroll
      for (int i = 0; i < 4; i++) {
        int row = wm * 64 + mi * 16 + q4 * 4 + i;
        int col = wn * 64 + nj * 16 + m16;
        Cb[(size_t)row * N + col] = acc[mi][nj][i];
      }
    }
  }
}

// ---------- beta = sigmoid(x @ Wb), WbT[16][1024], conflict-free ----------
__global__ __launch_bounds__(256) void beta_kernel(const float* __restrict__ x,
                                                   const float* __restrict__ WbT,
                                                   float* __restrict__ beta) {
  __shared__ __align__(16) float xs[D_];
  int row = blockIdx.x;
  int tid = threadIdx.x;
  ((float4*)xs)[tid] = ((const float4*)(x + (size_t)row * D_))[tid];
  __syncthreads();
  int h = tid >> 4;
  int seg = tid & 15;
  const float4* wrow = (const float4*)(WbT + (size_t)h * D_) + seg * 16;
  const float4* xsrow = (const float4*)xs + seg * 16;
  float s = 0.f;
  #pragma unroll
  for (int j = 0; j < 16; j++) {
    int jj = (j + seg) & 15;
    float4 xv = xsrow[jj];
    float4 wv = wrow[jj];
    s += xv.x * wv.x + xv.y * wv.y + xv.z * wv.z + xv.w * wv.w;
  }
  #pragma unroll
  for (int off = 8; off; off >>= 1) s += __shfl_down(s, off, 16);
  if (seg == 0) beta[(size_t)row * H_ + h] = 1.f / (1.f + __expf(-s));
}

// ---------- causal depthwise conv(K=4) + silu, l2norm for q,k ----------
__global__ __launch_bounds__(256) void conv_kernel(
    const float* __restrict__ qkv,
    const float* __restrict__ cq, const float* __restrict__ ck, const float* __restrict__ cv,
    float* __restrict__ qo, float* __restrict__ ko, float* __restrict__ vo) {
  int row = blockIdx.x;
  int t = row & (T_ - 1);
  int tid = threadIdx.x;
  int c0 = tid * 4;
  float4 zf = {0.f, 0.f, 0.f, 0.f};
  float4 xq[4], xk[4], xv[4];
  #pragma unroll
  for (int i = 0; i < 4; i++) {
    int tt = t - 3 + i;
    if (tt >= 0) {
      const float* rp = qkv + (size_t)(row - 3 + i) * QKVN_;
      xq[i] = *(const float4*)(rp + c0);
      xk[i] = *(const float4*)(rp + 1024 + c0);
      xv[i] = *(const float4*)(rp + 2048 + c0);
    } else { xq[i] = zf; xk[i] = zf; xv[i] = zf; }
  }
  float yq[4], yk[4], yv[4];
  float pq = 0.f, pk = 0.f;
  #pragma unroll
  for (int j = 0; j < 4; j++) {
    float4 wq = ((const float4*)cq)[c0 + j];
    float4 wk = ((const float4*)ck)[c0 + j];
    float4 wv = ((const float4*)cv)[c0 + j];
    float sq = 0.f, sk = 0.f, sv = 0.f;
    #pragma unroll
    for (int i = 0; i < 4; i++) {
      sq += f4get(wq, i) * f4get(xq[i], j);
      sk += f4get(wk, i) * f4get(xk[i], j);
      sv += f4get(wv, i) * f4get(xv[i], j);
    }
    yq[j] = siluf(sq); yk[j] = siluf(sk); yv[j] = siluf(sv);
    pq += yq[j] * yq[j]; pk += yk[j] * yk[j];
  }
  #pragma unroll
  for (int off = 1; off < 16; off <<= 1) {
    pq += __shfl_xor(pq, off, 16);
    pk += __shfl_xor(pk, off, 16);
  }
  float rq = rsqrtf(pq + 1e-6f), rk = rsqrtf(pk + 1e-6f);
  float4 oq = {yq[0]*rq, yq[1]*rq, yq[2]*rq, yq[3]*rq};
  float4 okk = {yk[0]*rk, yk[1]*rk, yk[2]*rk, yk[3]*rk};
  float4 ov = {yv[0], yv[1], yv[2], yv[3]};
  *(float4*)(qo + (size_t)row * D_ + c0) = oq;
  *(float4*)(ko + (size_t)row * D_ + c0) = okk;
  *(float4*)(vo + (size_t)row * D_ + c0) = ov;
}

// ================= chunked delta rule =================
// prep1: A = strict_tril(diag(b)KK^T); solve (I+A)Wk = diag(b)K and (I+A)U0 = diag(b)V
// Ksh stored with chunk swizzle (c ^ (row>>4)) so seg-strided row reads are conflict-free;
// AT stride 65 so its writes are 2-way (free) instead of 4-way.
__global__ __launch_bounds__(256) void prep1_kernel(
    const float* __restrict__ kn, const float* __restrict__ vn,
    const float* __restrict__ beta,
    float* __restrict__ Wkbuf, float* __restrict__ U0buf) {
  __shared__ float Ksh[64][68];   // swizzled chunks
  __shared__ float AT[64 * 65];   // AT[i*65+t] = A[t][i] for t>i, else 0
  __shared__ float XPK[16][68];
  __shared__ float XPV[16][68];
  __shared__ float bsh[64];
  int ch = blockIdx.x;
  int b = ch >> 9, h = (ch >> 5) & 15, c = ch & 31;
  int tid = threadIdx.x;
  int t = tid >> 2, seg = tid & 3;
  const float* krow = kn + ((size_t)(b * T_ + c * 64 + t)) * D_ + h * 64;
  #pragma unroll
  for (int g = 0; g < 4; g++)
    *(float4*)&Ksh[t][ksw(t, seg * 4 + g)] = *(const float4*)&krow[seg * 16 + 4 * g];
  if (tid < 64) bsh[tid] = beta[((size_t)(b * T_ + c * 64 + tid)) * H_ + h];
  __syncthreads();
  {
    int s0 = seg * 16;
    float acc[16];
    #pragma unroll
    for (int r = 0; r < 16; r++) acc[r] = 0.f;
    for (int d4 = 0; d4 < 16; d4++) {
      float4 kt = *(float4*)&Ksh[t][ksw(t, d4)];
      #pragma unroll
      for (int r = 0; r < 16; r++) {
        float4 ks = *(float4*)&Ksh[s0 + r][((d4 ^ seg) << 2)];   // (s0+r)>>4 == seg
        acc[r] += kt.x * ks.x + kt.y * ks.y + kt.z * ks.z + kt.w * ks.w;
      }
    }
    float bt = bsh[t];
    #pragma unroll
    for (int r = 0; r < 16; r++) {
      int s = s0 + r;
      AT[s * 65 + t] = (t > s) ? bt * acc[r] : 0.f;
    }
  }
  float xk[16], xv[16];
  {
    float bt = bsh[t];
    const float* vrow = vn + ((size_t)(b * T_ + c * 64 + t)) * D_ + h * 64;
    #pragma unroll
    for (int g = 0; g < 4; g++) {
      float4 kv = *(float4*)&Ksh[t][ksw(t, seg * 4 + g)];
      float4 vv = *(const float4*)&vrow[seg * 16 + 4 * g];
      xk[4*g+0] = bt * kv.x; xk[4*g+1] = bt * kv.y; xk[4*g+2] = bt * kv.z; xk[4*g+3] = bt * kv.w;
      xv[4*g+0] = bt * vv.x; xv[4*g+1] = bt * vv.y; xv[4*g+2] = bt * vv.z; xv[4*g+3] = bt * vv.w;
    }
  }
  __syncthreads();
  int wave = tid >> 6, lane = tid & 63;
  int r_loc = lane >> 2;
  for (int p = 0; p < 4; p++) {
    if (wave == p) {
      float a[16];
      #pragma unroll
      for (int i2 = 0; i2 < 16; i2++) a[i2] = AT[(p * 16 + i2) * 65 + t];
      #pragma unroll
      for (int i2 = 0; i2 < 16; i2++) {
        int src = i2 * 4 + (lane & 3);
        #pragma unroll
        for (int cc = 0; cc < 16; cc++) {
          float xki = __shfl(xk[cc], src, 64);
          float xvi = __shfl(xv[cc], src, 64);
          if (r_loc > i2) {
            xk[cc] = fmaf(-a[i2], xki, xk[cc]);
            xv[cc] = fmaf(-a[i2], xvi, xv[cc]);
          }
        }
      }
      #pragma unroll
      for (int g = 0; g < 4; g++) {
        float4 k4 = {xk[4*g+0], xk[4*g+1], xk[4*g+2], xk[4*g+3]};
        float4 v4 = {xv[4*g+0], xv[4*g+1], xv[4*g+2], xv[4*g+3]};
        *(float4*)&XPK[r_loc][seg * 16 + 4 * g] = k4;
        *(float4*)&XPV[r_loc][seg * 16 + 4 * g] = v4;
      }
    }
    __syncthreads();
    if (wave > p) {
      float a[16];
      #pragma unroll
      for (int i2 = 0; i2 < 16; i2++) a[i2] = AT[(p * 16 + i2) * 65 + t];
      #pragma unroll
      for (int i2 = 0; i2 < 16; i2++) {
        float ai = a[i2];
        #pragma unroll
        for (int g = 0; g < 4; g++) {
          float4 xk4 = *(float4*)&XPK[i2][seg * 16 + 4 * g];
          float4 xv4 = *(float4*)&XPV[i2][seg * 16 + 4 * g];
          xk[4*g+0] -= ai * xk4.x; xk[4*g+1] -= ai * xk4.y;
          xk[4*g+2] -= ai * xk4.z; xk[4*g+3] -= ai * xk4.w;
          xv[4*g+0] -= ai * xv4.x; xv[4*g+1] -= ai * xv4.y;
          xv[4*g+2] -= ai * xv4.z; xv[4*g+3] -= ai * xv4.w;
        }
      }
    }
    __syncthreads();
  }
  #pragma unroll
  for (int g = 0; g < 4; g++) {
    float4 k4 = {xk[4*g+0], xk[4*g+1], xk[4*g+2], xk[4*g+3]};
    float4 v4 = {xv[4*g+0], xv[4*g+1], xv[4*g+2], xv[4*g+3]};
    *(float4*)&Wkbuf[(size_t)ch * 4096 + t * 64 + seg * 16 + 4 * g] = k4;
    *(float4*)&U0buf[(size_t)ch * 4096 + t * 64 + seg * 16 + 4 * g] = v4;
  }
}

// prep2a: L = tril(Q K^T) (incl diagonal); Ksh chunk-swizzled like prep1
__global__ __launch_bounds__(256) void prep2a_kernel(
    const float* __restrict__ qn, const float* __restrict__ kn,
    float* __restrict__ Lbuf) {
  __shared__ float Qsh[64][68];
  __shared__ float Ksh[64][68];   // swizzled
  int ch = blockIdx.x;
  int b = ch >> 9, h = (ch >> 5) & 15, c = ch & 31;
  int tid = threadIdx.x;
  int t = tid >> 2, seg = tid & 3;
  const float* qrow = qn + ((size_t)(b * T_ + c * 64 + t)) * D_ + h * 64;
  const float* krow = kn + ((size_t)(b * T_ + c * 64 + t)) * D_ + h * 64;
  #pragma unroll
  for (int g = 0; g < 4; g++) {
    *(float4*)&Qsh[t][seg * 16 + 4 * g] = *(const float4*)&qrow[seg * 16 + 4 * g];
    *(float4*)&Ksh[t][ksw(t, seg * 4 + g)] = *(const float4*)&krow[seg * 16 + 4 * g];
  }
  __syncthreads();
  int s0 = seg * 16;
  float acc[16];
  #pragma unroll
  for (int r = 0; r < 16; r++) acc[r] = 0.f;
  for (int d4 = 0; d4 < 16; d4++) {
    float4 qt = *(float4*)&Qsh[t][d4 * 4];
    #pragma unroll
    for (int r = 0; r < 16; r++) {
      float4 ks = *(float4*)&Ksh[s0 + r][((d4 ^ seg) << 2)];
      acc[r] += qt.x * ks.x + qt.y * ks.y + qt.z * ks.z + qt.w * ks.w;
    }
  }
  #pragma unroll
  for (int g = 0; g < 4; g++) {
    float4 ov;
    ov.x = (s0 + 4*g + 0 <= t) ? acc[4*g+0] : 0.f;
    ov.y = (s0 + 4*g + 1 <= t) ? acc[4*g+1] : 0.f;
    ov.z = (s0 + 4*g + 2 <= t) ? acc[4*g+2] : 0.f;
    ov.w = (s0 + 4*g + 3 <= t) ? acc[4*g+3] : 0.f;
    *(float4*)&Lbuf[(size_t)ch * 4096 + t * 64 + s0 + 4 * g] = ov;
  }
}

// prep2b: O0 = L U0 ; Qeff = Q - L Wk (in-place over qn)
__global__ __launch_bounds__(256) void prep2b_kernel(
    const float* __restrict__ Lbuf, const float* __restrict__ Wkbuf,
    const float* __restrict__ U0buf, float* qn,
    float* __restrict__ O0buf) {
  __shared__ float Lsh[64][68];
  __shared__ float Wksh[64][68];
  __shared__ float U0sh[64][68];
  int ch = blockIdx.x;
  int b = ch >> 9, h = (ch >> 5) & 15, c = ch & 31;
  int tid = threadIdx.x;
  int t = tid >> 2, seg = tid & 3;
  #pragma unroll
  for (int g = 0; g < 4; g++) {
    int o = t * 64 + seg * 16 + 4 * g;
    *(float4*)&Lsh[t][seg * 16 + 4 * g]  = *(const float4*)&Lbuf[(size_t)ch * 4096 + o];
    *(float4*)&Wksh[t][seg * 16 + 4 * g] = *(const float4*)&Wkbuf[(size_t)ch * 4096 + o];
    *(float4*)&U0sh[t][seg * 16 + 4 * g] = *(const float4*)&U0buf[(size_t)ch * 4096 + o];
  }
  __syncthreads();
  int j0 = seg * 16;
  float o0[16], lw[16];
  #pragma unroll
  for (int r = 0; r < 16; r++) { o0[r] = 0.f; lw[r] = 0.f; }
  for (int s = 0; s <= t; s++) {
    float l = Lsh[t][s];
    #pragma unroll
    for (int g = 0; g < 4; g++) {
      float4 u = *(float4*)&U0sh[s][j0 + 4 * g];
      float4 w = *(float4*)&Wksh[s][j0 + 4 * g];
      o0[4*g+0] += l * u.x; o0[4*g+1] += l * u.y; o0[4*g+2] += l * u.z; o0[4*g+3] += l * u.w;
      lw[4*g+0] += l * w.x; lw[4*g+1] += l * w.y; lw[4*g+2] += l * w.z; lw[4*g+3] += l * w.w;
    }
  }
  float* qrow = qn + ((size_t)(b * T_ + c * 64 + t)) * D_ + h * 64;
  #pragma unroll
  for (int g = 0; g < 4; g++) {
    float4 qv = *(const float4*)&qrow[j0 + 4 * g];
    qv.x -= lw[4*g+0]; qv.y -= lw[4*g+1]; qv.z -= lw[4*g+2]; qv.w -= lw[4*g+3];
    *(float4*)&qrow[j0 + 4 * g] = qv;
    float4 ov = {o0[4*g+0], o0[4*g+1], o0[4*g+2], o0[4*g+3]};
    *(float4*)&O0buf[(size_t)ch * 4096 + t * 64 + j0 + 4 * g] = ov;
  }
}

// prep2c (TRANSPOSED outputs): Pt[e][d] = I - Wk^T K ; Zt[j][d] = U0^T K
__global__ __launch_bounds__(256) void prep2c_kernel(
    float* kn, const float* __restrict__ Wkbuf,
    const float* __restrict__ U0buf, float* __restrict__ Pbuf) {
  __shared__ float Ksh[64][68];
  __shared__ float Wksh[64][68];
  __shared__ float U0sh[64][68];
  int ch = blockIdx.x;
  int b = ch >> 9, h = (ch >> 5) & 15, c = ch & 31;
  int tid = threadIdx.x;
  int t = tid >> 2, seg = tid & 3;
  const float* krow = kn + ((size_t)(b * T_ + c * 64 + t)) * D_ + h * 64;
  #pragma unroll
  for (int g = 0; g < 4; g++) {
    int o = t * 64 + seg * 16 + 4 * g;
    *(float4*)&Ksh[t][seg * 16 + 4 * g]  = *(const float4*)&krow[seg * 16 + 4 * g];
    *(float4*)&Wksh[t][seg * 16 + 4 * g] = *(const float4*)&Wkbuf[(size_t)ch * 4096 + o];
    *(float4*)&U0sh[t][seg * 16 + 4 * g] = *(const float4*)&U0buf[(size_t)ch * 4096 + o];
  }
  __syncthreads();
  int d0 = seg * 16;
  float accP[16], accZ[16];
  #pragma unroll
  for (int r = 0; r < 16; r++) { accP[r] = 0.f; accZ[r] = 0.f; }
  for (int s = 0; s < 64; s++) {
    float w = Wksh[s][t];
    float u = U0sh[s][t];
    #pragma unroll
    for (int g = 0; g < 4; g++) {
      float4 k4 = *(float4*)&Ksh[s][d0 + 4 * g];
      accP[4*g+0] += w * k4.x; accP[4*g+1] += w * k4.y; accP[4*g+2] += w * k4.z; accP[4*g+3] += w * k4.w;
      accZ[4*g+0] += u * k4.x; accZ[4*g+1] += u * k4.y; accZ[4*g+2] += u * k4.z; accZ[4*g+3] += u * k4.w;
    }
  }
  float* zrow = kn + ((size_t)(b * T_ + c * 64 + t)) * D_ + h * 64;
  #pragma unroll
  for (int g = 0; g < 4; g++) {
    float4 pv;
    pv.x = ((d0 + 4*g + 0) == t ? 1.f : 0.f) - accP[4*g+0];
    pv.y = ((d0 + 4*g + 1) == t ? 1.f : 0.f) - accP[4*g+1];
    pv.z = ((d0 + 4*g + 2) == t ? 1.f : 0.f) - accP[4*g+2];
    pv.w = ((d0 + 4*g + 3) == t ? 1.f : 0.f) - accP[4*g+3];
    *(float4*)&Pbuf[(size_t)ch * 4096 + t * 64 + d0 + 4 * g] = pv;
    float4 zv = {accZ[4*g+0], accZ[4*g+1], accZ[4*g+2], accZ[4*g+3]};
    *(float4*)&zrow[d0 + 4 * g] = zv;
  }
}

// ---------- state scan: S_{c+1} = P_c S_c + Z_c; store S_c transposed [ch][j][d] ----------
__global__ __launch_bounds__(256) void state_kernel(
    const float* __restrict__ kn /*Zt*/, const float* __restrict__ Pbuf /*Pt*/,
    float* __restrict__ Sbuf) {
  __shared__ float PT[64][68];
  __shared__ float STt[16][68];
  int bid = blockIdx.x;
  int js = bid & 3, h = (bid >> 2) & 15, b = bid >> 6;
  int bh = b * H_ + h;
  int tid = threadIdx.x;
  int d = tid & 63, jq = tid >> 6;
  int j0 = jq * 4;
  float s[4] = {0.f, 0.f, 0.f, 0.f};
  float4 pn[4];
  #pragma unroll
  for (int g = 0; g < 4; g++)
    pn[g] = *(const float4*)&Pbuf[(size_t)(bh * NC_) * 4096 + (size_t)(tid + g * 256) * 4];
  for (int c = 0; c < NC_; c++) {
    size_t ch = (size_t)bh * NC_ + c;
    #pragma unroll
    for (int i = 0; i < 4; i++) {
      Sbuf[ch * 4096 + (size_t)(js * 16 + j0 + i) * 64 + d] = s[i];
      STt[j0 + i][d] = s[i];
    }
    #pragma unroll
    for (int g = 0; g < 4; g++) {
      int idx = tid + g * 256;
      *(float4*)&PT[idx >> 4][(idx & 15) * 4] = pn[g];
    }
    __syncthreads();
    if (c + 1 < NC_) {
      #pragma unroll
      for (int g = 0; g < 4; g++)
        pn[g] = *(const float4*)&Pbuf[(ch + 1) * 4096 + (size_t)(tid + g * 256) * 4];
    }
    float acc[4];
    #pragma unroll
    for (int i = 0; i < 4; i++)
      acc[i] = kn[((size_t)(b * T_ + c * 64 + js * 16 + j0 + i)) * D_ + h * 64 + d];
    #pragma unroll 4
    for (int e4 = 0; e4 < 16; e4++) {
      float p0 = PT[e4 * 4 + 0][d];
      float p1 = PT[e4 * 4 + 1][d];
      float p2 = PT[e4 * 4 + 2][d];
      float p3 = PT[e4 * 4 + 3][d];
      #pragma unroll
      for (int i = 0; i < 4; i++) {
        float4 st = *(float4*)&STt[j0 + i][e4 * 4];
        acc[i] += p0 * st.x + p1 * st.y + p2 * st.z + p3 * st.w;
      }
    }
    __syncthreads();
    #pragma unroll
    for (int i = 0; i < 4; i++) s[i] = acc[i];
  }
}

// ---------- O = O0 + Qeff*S_c (S transposed layout), fused RMSNorm + bf16 cast ----------
__global__ __launch_bounds__(256) void ophase_kernel(
    const float* __restrict__ qn /*Qeff*/, const float* __restrict__ Sbuf,
    const float* __restrict__ O0buf, const float* __restrict__ rms_g,
    ushort* __restrict__ ob) {
  __shared__ float Ssht[64][68];
  __shared__ float QshT[64][65];
  __shared__ float part[64][4];
  int ch = blockIdx.x;
  int b = ch >> 9, h = (ch >> 5) & 15, c = ch & 31;
  int tid = threadIdx.x;
  int t = tid & 63, jg = tid >> 6;
  #pragma unroll
  for (int g = 0; g < 4; g++) {
    int idx = tid + g * 256;
    *(float4*)&Ssht[idx >> 4][(idx & 15) * 4] =
        *(const float4*)&Sbuf[(size_t)ch * 4096 + (size_t)idx * 4];
  }
  #pragma unroll
  for (int g = 0; g < 4; g++) {
    int idx = tid + g * 256;
    int row = idx >> 4, c4 = idx & 15;
    float4 qv = *(const float4*)&qn[((size_t)(b * T_ + c * 64 + row)) * D_ + h * 64 + c4 * 4];
    QshT[c4 * 4 + 0][row] = qv.x;
    QshT[c4 * 4 + 1][row] = qv.y;
    QshT[c4 * 4 + 2][row] = qv.z;
    QshT[c4 * 4 + 3][row] = qv.w;
  }
  float o[16];
  #pragma unroll
  for (int g = 0; g < 4; g++) {
    float4 o4 = *(const float4*)&O0buf[(size_t)ch * 4096 + t * 64 + jg * 16 + g * 4];
    o[4*g+0] = o4.x; o[4*g+1] = o4.y; o[4*g+2] = o4.z; o[4*g+3] = o4.w;
  }
  __syncthreads();
  for (int d4 = 0; d4 < 16; d4++) {
    float q0 = QshT[d4 * 4 + 0][t];
    float q1 = QshT[d4 * 4 + 1][t];
    float q2 = QshT[d4 * 4 + 2][t];
    float q3 = QshT[d4 * 4 + 3][t];
    #pragma unroll
    for (int r = 0; r < 16; r++) {
      float4 s4 = *(float4*)&Ssht[jg * 16 + r][d4 * 4];
      o[r] += q0 * s4.x + q1 * s4.y + q2 * s4.z + q3 * s4.w;
    }
  }
  float ss = 0.f;
  #pragma unroll
  for (int r = 0; r < 16; r++) ss += o[r] * o[r];
  part[t][jg] = ss;
  __syncthreads();
  float tot = part[t][0] + part[t][1] + part[t][2] + part[t][3];
  float sc = rsqrtf(tot * (1.f / 64.f) + 1e-6f);
  ushort* orow = &ob[((size_t)(b * T_ + c * 64 + t)) * D_ + h * 64];
  #pragma unroll
  for (int g = 0; g < 4; g++) {
    float4 g4 = *(const float4*)&rms_g[jg * 16 + g * 4];
    ushort4 r4;
    r4.x = f2bf(o[4*g+0] * sc * g4.x); r4.y = f2bf(o[4*g+1] * sc * g4.y);
    r4.z = f2bf(o[4*g+2] * sc * g4.z); r4.w = f2bf(o[4*g+3] * sc * g4.w);
    *(ushort4*)&orow[jg * 16 + g * 4] = r4;
  }
}

extern "C" void kernel_launch(void* const* d_in, const int* in_sizes, int n_in,
                              void* d_out, int out_size, void* d_ws, size_t ws_size,
                              hipStream_t stream) {
  const float* x  = (const float*)d_in[0];
  const float* Wq = (const float*)d_in[1];
  const float* Wk = (const float*)d_in[2];
  const float* Wv = (const float*)d_in[3];
  const float* Wb = (const float*)d_in[4];
  const float* cq = (const float*)d_in[5];
  const float* ck = (const float*)d_in[6];
  const float* cv = (const float*)d_in[7];
  const float* rg = (const float*)d_in[8];
  const float* Wo = (const float*)d_in[9];
  float* out = (float*)d_out;
  char* ws = (char*)d_ws;
  const size_t MiB = 1ull << 20;
  ushort* xb   = (ushort*)(ws + 0);         // dead after QKV gemm
  ushort* Wqt  = (ushort*)(ws + 8 * MiB);   // Wqt/Wkt/Wvt contiguous = [3072][1024] bf16
  ushort* Wkt  = (ushort*)(ws + 10 * MiB);
  ushort* Wvt  = (ushort*)(ws + 12 * MiB);
  ushort* Wot  = (ushort*)(ws + 14 * MiB);  // live to end
  float* qkv   = (float*)(ws + 16 * MiB);   // [4096][3072] fp32, dead after conv
  float* qn    = (float*)(ws + 64 * MiB);   // then Qeff in-place
  float* kn    = (float*)(ws + 80 * MiB);   // then Zt in-place
  float* vn    = (float*)(ws + 96 * MiB);   // dead after prep1
  float* beta  = (float*)(ws + 112 * MiB);  // 256 KiB
  float* WbT   = (float*)(ws + 112 * MiB + 256 * 1024);  // 64 KiB
  float* Wkbuf = (float*)(ws + 16 * MiB);   // over qkv (dead after conv)
  float* U0buf = (float*)(ws + 32 * MiB);
  float* Lbuf  = (float*)(ws + 48 * MiB);   // later Pt
  float* O0buf = (float*)(ws + 96 * MiB);   // over vn (after prep1)
  float* Sbuf  = (float*)(ws + 16 * MiB);   // over Wkbuf (dead after prep2c)
  ushort* ob   = (ushort*)(ws + 0);         // over xb (after QKV gemm)

  hipLaunchKernelGGL(cast_kernel, dim3(M_ * D_ / 4 / 256), dim3(256), 0, stream,
                     x, xb, M_ * D_ / 4);
  dim3 tb(32, 8);
  hipLaunchKernelGGL(transpose_cast_kernel, dim3(32, 32), tb, 0, stream, Wq, Wqt, D_, D_);
  hipLaunchKernelGGL(transpose_cast_kernel, dim3(32, 32), tb, 0, stream, Wk, Wkt, D_, D_);
  hipLaunchKernelGGL(transpose_cast_kernel, dim3(32, 32), tb, 0, stream, Wv, Wvt, D_, D_);
  hipLaunchKernelGGL(transpose_cast_kernel, dim3(32, 32), tb, 0, stream, Wo, Wot, D_, D_);
  hipLaunchKernelGGL(transpose_wb_kernel, dim3(64), dim3(256), 0, stream, Wb, WbT);

  hipLaunchKernelGGL(gemm128_kernel, dim3(M_ / 128, QKVN_ / 128), dim3(256), 0, stream,
                     xb, Wqt, qkv, M_, QKVN_, D_);

  hipLaunchKernelGGL(beta_kernel, dim3(M_), dim3(256), 0, stream, x, WbT, beta);
  hipLaunchKernelGGL(conv_kernel, dim3(M_), dim3(256), 0, stream,
                     qkv, cq, ck, cv, qn, kn, vn);

  hipLaunchKernelGGL(prep1_kernel, dim3(NCH_), dim3(256), 0, stream,
                     kn, vn, beta, Wkbuf, U0buf);
  hipLaunchKernelGGL(prep2a_kernel, dim3(NCH_), dim3(256), 0, stream, qn, kn, Lbuf);
  hipLaunchKernelGGL(prep2b_kernel, dim3(NCH_), dim3(256), 0, stream,
                     Lbuf, Wkbuf, U0buf, qn, O0buf);
  hipLaunchKernelGGL(prep2c_kernel, dim3(NCH_), dim3(256), 0, stream,
                     kn, Wkbuf, U0buf, Lbuf);
  hipLaunchKernelGGL(state_kernel, dim3(B_ * H_ * 4), dim3(256), 0, stream,
                     kn, Lbuf, Sbuf);
  hipLaunchKernelGGL(ophase_kernel, dim3(NCH_), dim3(256), 0, stream,
                     qn, Sbuf, O0buf, rg, ob);
  hipLaunchKernelGGL(gemm128_kernel, dim3(M_ / 128, D_ / 128), dim3(256), 0, stream,
                     ob, Wot, out, M_, D_, D_);
}

// Round 8
// 472.251 us; speedup vs baseline: 1.9675x; 1.0433x over previous
//
#include <hip/hip_runtime.h>
#include <hip/hip_bf16.h>
#include <math.h>

#define B_ 2
#define T_ 2048
#define D_ 1024
#define H_ 16
#define DH_ 64
#define M_ (B_*T_)   // 4096 rows
#define NC_ 32       // chunks per sequence (T/64)
#define CS_ 64       // chunk size
#define NCH_ (B_*H_*NC_)  // 1024 chunk-heads
#define QKVN_ 3072   // fused QKV gemm N

typedef __attribute__((ext_vector_type(4))) float floatx4;
typedef __attribute__((ext_vector_type(8))) short short8;

__device__ __forceinline__ ushort f2bf(float f) {
  union { float f; unsigned u; } c; c.f = f;
  unsigned r = (c.u + 0x7FFFu + ((c.u >> 16) & 1u)) >> 16;  // RNE
  return (ushort)r;
}
__device__ __forceinline__ float siluf(float u) {
  return u / (1.f + __expf(-u));
}
__device__ __forceinline__ float f4get(const float4& v, int j) {
  return j == 0 ? v.x : j == 1 ? v.y : j == 2 ? v.z : v.w;
}
__device__ __forceinline__ float rdlane(float v, int l) {
  return __int_as_float(__builtin_amdgcn_readlane(__float_as_int(v), l));
}
// swizzled chunk index for K tiles: chunk c (0..15) of row r stored at c ^ (r>>4)
__device__ __forceinline__ int ksw(int r, int c) { return ((c ^ (r >> 4)) << 2); }

// ---------- cast f32 -> bf16, n4 = n/4 ----------
__global__ void cast_kernel(const float* __restrict__ in, ushort* __restrict__ out, int n4) {
  int i = blockIdx.x * blockDim.x + threadIdx.x;
  if (i >= n4) return;
  float4 v = ((const float4*)in)[i];
  ushort4 o;
  o.x = f2bf(v.x); o.y = f2bf(v.y); o.z = f2bf(v.z); o.w = f2bf(v.w);
  ((ushort4*)out)[i] = o;
}

// ---------- transpose + cast: W[K][N] f32 -> Wt[N][K] bf16 ----------
__global__ void transpose_cast_kernel(const float* __restrict__ W, ushort* __restrict__ Wt,
                                      int K, int N) {
  __shared__ float tile[32][33];
  int tx = threadIdx.x, ty = threadIdx.y;
  int n0 = blockIdx.x * 32, k0 = blockIdx.y * 32;
  #pragma unroll
  for (int i = 0; i < 32; i += 8)
    tile[ty + i][tx] = W[(size_t)(k0 + ty + i) * N + n0 + tx];
  __syncthreads();
  #pragma unroll
  for (int i = 0; i < 32; i += 8)
    Wt[(size_t)(n0 + ty + i) * K + k0 + tx] = f2bf(tile[tx][ty + i]);
}

// ---------- transpose Wb[1024][16] -> WbT[16][1024] (fp32) ----------
__global__ void transpose_wb_kernel(const float* __restrict__ Wb, float* __restrict__ WbT) {
  int bk = blockIdx.x;
  int tid = threadIdx.x;
  int kl = tid >> 4, h = tid & 15;
  int k = bk * 16 + kl;
  WbT[(size_t)h * D_ + k] = Wb[(size_t)k * H_ + h];
}

// ---------- m97-style bf16 MFMA GEMM: C[M][N] = A[M][K]*B[K][N], Bt = B^T [N][K] ----------
__global__ __launch_bounds__(256) void gemm128_kernel(
    const ushort* __restrict__ A, const ushort* __restrict__ Bt,
    float* __restrict__ C, int M, int N, int K) {
  __shared__ ushort lA[128 * 32];
  __shared__ ushort lB[128 * 32];
  int tid = threadIdx.x;
  int wave = tid >> 6, lane = tid & 63;
  int wm = wave >> 1, wn = wave & 1;
  int m16 = lane & 15, q4 = lane >> 4;
  int bm = blockIdx.x, bn = blockIdx.y;
  floatx4 acc[4][4] = {};
  int srow = tid >> 2;
  int sk8 = tid & 3;
  const ushort* Ag = A + (size_t)(bm * 128 + srow) * K + sk8 * 8;
  const ushort* Bg = Bt + (size_t)(bn * 128 + srow) * K + sk8 * 8;
  ushort* lAp = lA + tid * 8;
  ushort* lBp = lB + tid * 8;
  for (int k0 = 0; k0 < K; k0 += 32) {
    __builtin_amdgcn_global_load_lds(
        (const __attribute__((address_space(1))) void*)(Ag + k0),
        (__attribute__((address_space(3))) void*)lAp, 16, 0, 0);
    __builtin_amdgcn_global_load_lds(
        (const __attribute__((address_space(1))) void*)(Ag + (size_t)64 * K + k0),
        (__attribute__((address_space(3))) void*)(lAp + 2048), 16, 0, 0);
    __builtin_amdgcn_global_load_lds(
        (const __attribute__((address_space(1))) void*)(Bg + k0),
        (__attribute__((address_space(3))) void*)lBp, 16, 0, 0);
    __builtin_amdgcn_global_load_lds(
        (const __attribute__((address_space(1))) void*)(Bg + (size_t)64 * K + k0),
        (__attribute__((address_space(3))) void*)(lBp + 2048), 16, 0, 0);
    __syncthreads();
    short8 af[4], bf[4];
    #pragma unroll
    for (int i = 0; i < 4; i++) {
      af[i] = *(short8*)&lA[(wm * 64 + i * 16 + m16) * 32 + q4 * 8];
      bf[i] = *(short8*)&lB[(wn * 64 + i * 16 + m16) * 32 + q4 * 8];
    }
    #pragma unroll
    for (int mi = 0; mi < 4; mi++)
      #pragma unroll
      for (int nj = 0; nj < 4; nj++)
        acc[mi][nj] = __builtin_amdgcn_mfma_f32_16x16x32_bf16(af[mi], bf[nj], acc[mi][nj], 0, 0, 0);
    __syncthreads();
  }
  float* Cb = C + (size_t)(bm * 128) * N + bn * 128;
  #pragma unroll
  for (int mi = 0; mi < 4; mi++) {
    #pragma unroll
    for (int nj = 0; nj < 4; nj++) {
      #pragma unroll
      for (int i = 0; i < 4; i++) {
        int row = wm * 64 + mi * 16 + q4 * 4 + i;
        int col = wn * 64 + nj * 16 + m16;
        Cb[(size_t)row * N + col] = acc[mi][nj][i];
      }
    }
  }
}

// ---------- beta = sigmoid(x @ Wb), WbT[16][1024], conflict-free ----------
__global__ __launch_bounds__(256) void beta_kernel(const float* __restrict__ x,
                                                   const float* __restrict__ WbT,
                                                   float* __restrict__ beta) {
  __shared__ __align__(16) float xs[D_];
  int row = blockIdx.x;
  int tid = threadIdx.x;
  ((float4*)xs)[tid] = ((const float4*)(x + (size_t)row * D_))[tid];
  __syncthreads();
  int h = tid >> 4;
  int seg = tid & 15;
  const float4* wrow = (const float4*)(WbT + (size_t)h * D_) + seg * 16;
  const float4* xsrow = (const float4*)xs + seg * 16;
  float s = 0.f;
  #pragma unroll
  for (int j = 0; j < 16; j++) {
    int jj = (j + seg) & 15;
    float4 xv = xsrow[jj];
    float4 wv = wrow[jj];
    s += xv.x * wv.x + xv.y * wv.y + xv.z * wv.z + xv.w * wv.w;
  }
  #pragma unroll
  for (int off = 8; off; off >>= 1) s += __shfl_down(s, off, 16);
  if (seg == 0) beta[(size_t)row * H_ + h] = 1.f / (1.f + __expf(-s));
}

// ---------- causal depthwise conv(K=4) + silu, l2norm for q,k ----------
__global__ __launch_bounds__(256) void conv_kernel(
    const float* __restrict__ qkv,
    const float* __restrict__ cq, const float* __restrict__ ck, const float* __restrict__ cv,
    float* __restrict__ qo, float* __restrict__ ko, float* __restrict__ vo) {
  int row = blockIdx.x;
  int t = row & (T_ - 1);
  int tid = threadIdx.x;
  int c0 = tid * 4;
  float4 zf = {0.f, 0.f, 0.f, 0.f};
  float4 xq[4], xk[4], xv[4];
  #pragma unroll
  for (int i = 0; i < 4; i++) {
    int tt = t - 3 + i;
    if (tt >= 0) {
      const float* rp = qkv + (size_t)(row - 3 + i) * QKVN_;
      xq[i] = *(const float4*)(rp + c0);
      xk[i] = *(const float4*)(rp + 1024 + c0);
      xv[i] = *(const float4*)(rp + 2048 + c0);
    } else { xq[i] = zf; xk[i] = zf; xv[i] = zf; }
  }
  float yq[4], yk[4], yv[4];
  float pq = 0.f, pk = 0.f;
  #pragma unroll
  for (int j = 0; j < 4; j++) {
    float4 wq = ((const float4*)cq)[c0 + j];
    float4 wk = ((const float4*)ck)[c0 + j];
    float4 wv = ((const float4*)cv)[c0 + j];
    float sq = 0.f, sk = 0.f, sv = 0.f;
    #pragma unroll
    for (int i = 0; i < 4; i++) {
      sq += f4get(wq, i) * f4get(xq[i], j);
      sk += f4get(wk, i) * f4get(xk[i], j);
      sv += f4get(wv, i) * f4get(xv[i], j);
    }
    yq[j] = siluf(sq); yk[j] = siluf(sk); yv[j] = siluf(sv);
    pq += yq[j] * yq[j]; pk += yk[j] * yk[j];
  }
  #pragma unroll
  for (int off = 1; off < 16; off <<= 1) {
    pq += __shfl_xor(pq, off, 16);
    pk += __shfl_xor(pk, off, 16);
  }
  float rq = rsqrtf(pq + 1e-6f), rk = rsqrtf(pk + 1e-6f);
  float4 oq = {yq[0]*rq, yq[1]*rq, yq[2]*rq, yq[3]*rq};
  float4 okk = {yk[0]*rk, yk[1]*rk, yk[2]*rk, yk[3]*rk};
  float4 ov = {yv[0], yv[1], yv[2], yv[3]};
  *(float4*)(qo + (size_t)row * D_ + c0) = oq;
  *(float4*)(ko + (size_t)row * D_ + c0) = okk;
  *(float4*)(vo + (size_t)row * D_ + c0) = ov;
}

// ================= chunked delta rule =================
// prep1: A = strict_tril(diag(b)KK^T); solve (I+A)Wk = diag(b)K and (I+A)U0 = diag(b)V
__global__ __launch_bounds__(256) void prep1_kernel(
    const float* __restrict__ kn, const float* __restrict__ vn,
    const float* __restrict__ beta,
    float* __restrict__ Wkbuf, float* __restrict__ U0buf) {
  __shared__ float Ksh[64][68];   // swizzled chunks
  __shared__ float AT[64 * 65];   // AT[i*65+t] = A[t][i] for t>i, else 0
  __shared__ float XPK[16][68];
  __shared__ float XPV[16][68];
  __shared__ float bsh[64];
  int ch = blockIdx.x;
  int b = ch >> 9, h = (ch >> 5) & 15, c = ch & 31;
  int tid = threadIdx.x;
  int t = tid >> 2, seg = tid & 3;
  const float* krow = kn + ((size_t)(b * T_ + c * 64 + t)) * D_ + h * 64;
  #pragma unroll
  for (int g = 0; g < 4; g++)
    *(float4*)&Ksh[t][ksw(t, seg * 4 + g)] = *(const float4*)&krow[seg * 16 + 4 * g];
  if (tid < 64) bsh[tid] = beta[((size_t)(b * T_ + c * 64 + tid)) * H_ + h];
  __syncthreads();
  {
    int s0 = seg * 16;
    float acc[16];
    #pragma unroll
    for (int r = 0; r < 16; r++) acc[r] = 0.f;
    for (int d4 = 0; d4 < 16; d4++) {
      float4 kt = *(float4*)&Ksh[t][ksw(t, d4)];
      #pragma unroll
      for (int r = 0; r < 16; r++) {
        float4 ks = *(float4*)&Ksh[s0 + r][((d4 ^ seg) << 2)];   // (s0+r)>>4 == seg
        acc[r] += kt.x * ks.x + kt.y * ks.y + kt.z * ks.z + kt.w * ks.w;
      }
    }
    float bt = bsh[t];
    #pragma unroll
    for (int r = 0; r < 16; r++) {
      int s = s0 + r;
      AT[s * 65 + t] = (t > s) ? bt * acc[r] : 0.f;
    }
  }
  float xk[16], xv[16];
  {
    float bt = bsh[t];
    const float* vrow = vn + ((size_t)(b * T_ + c * 64 + t)) * D_ + h * 64;
    #pragma unroll
    for (int g = 0; g < 4; g++) {
      float4 kv = *(float4*)&Ksh[t][ksw(t, seg * 4 + g)];
      float4 vv = *(const float4*)&vrow[seg * 16 + 4 * g];
      xk[4*g+0] = bt * kv.x; xk[4*g+1] = bt * kv.y; xk[4*g+2] = bt * kv.z; xk[4*g+3] = bt * kv.w;
      xv[4*g+0] = bt * vv.x; xv[4*g+1] = bt * vv.y; xv[4*g+2] = bt * vv.z; xv[4*g+3] = bt * vv.w;
    }
  }
  __syncthreads();
  int wave = tid >> 6, lane = tid & 63;
  int r_loc = lane >> 2;
  for (int p = 0; p < 4; p++) {
    if (wave == p) {
      float a[16];
      #pragma unroll
      for (int i2 = 0; i2 < 16; i2++) a[i2] = AT[(p * 16 + i2) * 65 + t];
      #pragma unroll
      for (int i2 = 0; i2 < 16; i2++) {
        int src = i2 * 4 + (lane & 3);
        #pragma unroll
        for (int cc = 0; cc < 16; cc++) {
          float xki = __shfl(xk[cc], src, 64);
          float xvi = __shfl(xv[cc], src, 64);
          if (r_loc > i2) {
            xk[cc] = fmaf(-a[i2], xki, xk[cc]);
            xv[cc] = fmaf(-a[i2], xvi, xv[cc]);
          }
        }
      }
      #pragma unroll
      for (int g = 0; g < 4; g++) {
        float4 k4 = {xk[4*g+0], xk[4*g+1], xk[4*g+2], xk[4*g+3]};
        float4 v4 = {xv[4*g+0], xv[4*g+1], xv[4*g+2], xv[4*g+3]};
        *(float4*)&XPK[r_loc][seg * 16 + 4 * g] = k4;
        *(float4*)&XPV[r_loc][seg * 16 + 4 * g] = v4;
      }
    }
    __syncthreads();
    if (wave > p) {
      float a[16];
      #pragma unroll
      for (int i2 = 0; i2 < 16; i2++) a[i2] = AT[(p * 16 + i2) * 65 + t];
      #pragma unroll
      for (int i2 = 0; i2 < 16; i2++) {
        float ai = a[i2];
        #pragma unroll
        for (int g = 0; g < 4; g++) {
          float4 xk4 = *(float4*)&XPK[i2][seg * 16 + 4 * g];
          float4 xv4 = *(float4*)&XPV[i2][seg * 16 + 4 * g];
          xk[4*g+0] -= ai * xk4.x; xk[4*g+1] -= ai * xk4.y;
          xk[4*g+2] -= ai * xk4.z; xk[4*g+3] -= ai * xk4.w;
          xv[4*g+0] -= ai * xv4.x; xv[4*g+1] -= ai * xv4.y;
          xv[4*g+2] -= ai * xv4.z; xv[4*g+3] -= ai * xv4.w;
        }
      }
    }
    __syncthreads();
  }
  #pragma unroll
  for (int g = 0; g < 4; g++) {
    float4 k4 = {xk[4*g+0], xk[4*g+1], xk[4*g+2], xk[4*g+3]};
    float4 v4 = {xv[4*g+0], xv[4*g+1], xv[4*g+2], xv[4*g+3]};
    *(float4*)&Wkbuf[(size_t)ch * 4096 + t * 64 + seg * 16 + 4 * g] = k4;
    *(float4*)&U0buf[(size_t)ch * 4096 + t * 64 + seg * 16 + 4 * g] = v4;
  }
}

// prep2a: L = tril(Q K^T) (incl diagonal); Ksh chunk-swizzled like prep1
__global__ __launch_bounds__(256) void prep2a_kernel(
    const float* __restrict__ qn, const float* __restrict__ kn,
    float* __restrict__ Lbuf) {
  __shared__ float Qsh[64][68];
  __shared__ float Ksh[64][68];   // swizzled
  int ch = blockIdx.x;
  int b = ch >> 9, h = (ch >> 5) & 15, c = ch & 31;
  int tid = threadIdx.x;
  int t = tid >> 2, seg = tid & 3;
  const float* qrow = qn + ((size_t)(b * T_ + c * 64 + t)) * D_ + h * 64;
  const float* krow = kn + ((size_t)(b * T_ + c * 64 + t)) * D_ + h * 64;
  #pragma unroll
  for (int g = 0; g < 4; g++) {
    *(float4*)&Qsh[t][seg * 16 + 4 * g] = *(const float4*)&qrow[seg * 16 + 4 * g];
    *(float4*)&Ksh[t][ksw(t, seg * 4 + g)] = *(const float4*)&krow[seg * 16 + 4 * g];
  }
  __syncthreads();
  int s0 = seg * 16;
  float acc[16];
  #pragma unroll
  for (int r = 0; r < 16; r++) acc[r] = 0.f;
  for (int d4 = 0; d4 < 16; d4++) {
    float4 qt = *(float4*)&Qsh[t][d4 * 4];
    #pragma unroll
    for (int r = 0; r < 16; r++) {
      float4 ks = *(float4*)&Ksh[s0 + r][((d4 ^ seg) << 2)];
      acc[r] += qt.x * ks.x + qt.y * ks.y + qt.z * ks.z + qt.w * ks.w;
    }
  }
  #pragma unroll
  for (int g = 0; g < 4; g++) {
    float4 ov;
    ov.x = (s0 + 4*g + 0 <= t) ? acc[4*g+0] : 0.f;
    ov.y = (s0 + 4*g + 1 <= t) ? acc[4*g+1] : 0.f;
    ov.z = (s0 + 4*g + 2 <= t) ? acc[4*g+2] : 0.f;
    ov.w = (s0 + 4*g + 3 <= t) ? acc[4*g+3] : 0.f;
    *(float4*)&Lbuf[(size_t)ch * 4096 + t * 64 + s0 + 4 * g] = ov;
  }
}

// prep2b: O0 = L U0 ; Qeff = Q - L Wk (in-place over qn)
__global__ __launch_bounds__(256) void prep2b_kernel(
    const float* __restrict__ Lbuf, const float* __restrict__ Wkbuf,
    const float* __restrict__ U0buf, float* qn,
    float* __restrict__ O0buf) {
  __shared__ float Lsh[64][68];
  __shared__ float Wksh[64][68];
  __shared__ float U0sh[64][68];
  int ch = blockIdx.x;
  int b = ch >> 9, h = (ch >> 5) & 15, c = ch & 31;
  int tid = threadIdx.x;
  int t = tid >> 2, seg = tid & 3;
  #pragma unroll
  for (int g = 0; g < 4; g++) {
    int o = t * 64 + seg * 16 + 4 * g;
    *(float4*)&Lsh[t][seg * 16 + 4 * g]  = *(const float4*)&Lbuf[(size_t)ch * 4096 + o];
    *(float4*)&Wksh[t][seg * 16 + 4 * g] = *(const float4*)&Wkbuf[(size_t)ch * 4096 + o];
    *(float4*)&U0sh[t][seg * 16 + 4 * g] = *(const float4*)&U0buf[(size_t)ch * 4096 + o];
  }
  __syncthreads();
  int j0 = seg * 16;
  float o0[16], lw[16];
  #pragma unroll
  for (int r = 0; r < 16; r++) { o0[r] = 0.f; lw[r] = 0.f; }
  for (int s = 0; s <= t; s++) {
    float l = Lsh[t][s];
    #pragma unroll
    for (int g = 0; g < 4; g++) {
      float4 u = *(float4*)&U0sh[s][j0 + 4 * g];
      float4 w = *(float4*)&Wksh[s][j0 + 4 * g];
      o0[4*g+0] += l * u.x; o0[4*g+1] += l * u.y; o0[4*g+2] += l * u.z; o0[4*g+3] += l * u.w;
      lw[4*g+0] += l * w.x; lw[4*g+1] += l * w.y; lw[4*g+2] += l * w.z; lw[4*g+3] += l * w.w;
    }
  }
  float* qrow = qn + ((size_t)(b * T_ + c * 64 + t)) * D_ + h * 64;
  #pragma unroll
  for (int g = 0; g < 4; g++) {
    float4 qv = *(const float4*)&qrow[j0 + 4 * g];
    qv.x -= lw[4*g+0]; qv.y -= lw[4*g+1]; qv.z -= lw[4*g+2]; qv.w -= lw[4*g+3];
    *(float4*)&qrow[j0 + 4 * g] = qv;
    float4 ov = {o0[4*g+0], o0[4*g+1], o0[4*g+2], o0[4*g+3]};
    *(float4*)&O0buf[(size_t)ch * 4096 + t * 64 + j0 + 4 * g] = ov;
  }
}

// prep2c: P natural layout P[d][e] = I - (K^T Wk)[d][e]  (row d contiguous in e);
//         Zt[j][d] = (U0^T K)[j][d] -> kn rows j (coalesced), unchanged.
__global__ __launch_bounds__(256) void prep2c_kernel(
    float* kn, const float* __restrict__ Wkbuf,
    const float* __restrict__ U0buf, float* __restrict__ Pbuf) {
  __shared__ float Ksh[64][68];
  __shared__ float Wksh[64][68];
  __shared__ float U0sh[64][68];
  int ch = blockIdx.x;
  int b = ch >> 9, h = (ch >> 5) & 15, c = ch & 31;
  int tid = threadIdx.x;
  int t = tid >> 2, seg = tid & 3;   // t = output row (d for P, j for Zt)
  const float* krow = kn + ((size_t)(b * T_ + c * 64 + t)) * D_ + h * 64;
  #pragma unroll
  for (int g = 0; g < 4; g++) {
    int o = t * 64 + seg * 16 + 4 * g;
    *(float4*)&Ksh[t][seg * 16 + 4 * g]  = *(const float4*)&krow[seg * 16 + 4 * g];
    *(float4*)&Wksh[t][seg * 16 + 4 * g] = *(const float4*)&Wkbuf[(size_t)ch * 4096 + o];
    *(float4*)&U0sh[t][seg * 16 + 4 * g] = *(const float4*)&U0buf[(size_t)ch * 4096 + o];
  }
  __syncthreads();
  int d0 = seg * 16;
  float accP[16], accZ[16];
  #pragma unroll
  for (int r = 0; r < 16; r++) { accP[r] = 0.f; accZ[r] = 0.f; }
  for (int s = 0; s < 64; s++) {
    float kt = Ksh[s][t];    // scalar for P row d=t
    float u  = U0sh[s][t];   // scalar for Z row j=t
    #pragma unroll
    for (int g = 0; g < 4; g++) {
      float4 w4 = *(float4*)&Wksh[s][d0 + 4 * g];
      float4 k4 = *(float4*)&Ksh[s][d0 + 4 * g];
      accP[4*g+0] += kt * w4.x; accP[4*g+1] += kt * w4.y; accP[4*g+2] += kt * w4.z; accP[4*g+3] += kt * w4.w;
      accZ[4*g+0] += u * k4.x;  accZ[4*g+1] += u * k4.y;  accZ[4*g+2] += u * k4.z;  accZ[4*g+3] += u * k4.w;
    }
  }
  float* zrow = kn + ((size_t)(b * T_ + c * 64 + t)) * D_ + h * 64;
  #pragma unroll
  for (int g = 0; g < 4; g++) {
    float4 pv;
    pv.x = ((d0 + 4*g + 0) == t ? 1.f : 0.f) - accP[4*g+0];
    pv.y = ((d0 + 4*g + 1) == t ? 1.f : 0.f) - accP[4*g+1];
    pv.z = ((d0 + 4*g + 2) == t ? 1.f : 0.f) - accP[4*g+2];
    pv.w = ((d0 + 4*g + 3) == t ? 1.f : 0.f) - accP[4*g+3];
    *(float4*)&Pbuf[(size_t)ch * 4096 + t * 64 + d0 + 4 * g] = pv;
    float4 zv = {accZ[4*g+0], accZ[4*g+1], accZ[4*g+2], accZ[4*g+3]};
    *(float4*)&zrow[d0 + 4 * g] = zv;
  }
}

// ---------- state scan: S_{c+1} = P_c S_c + Z_c; Sbuf transposed [ch][j][d] ----------
// Barrier-free, LDS-free: lane = d holds S[d][j0..j0+3] in regs; broadcasts of S[e][j]
// via v_readlane (whole column lives in the wave); P row per lane in registers,
// double-buffered prefetch. 128 blocks = (b,h,js); wave jq owns j = js*16+jq*4 ..+3.
__global__ __launch_bounds__(256) void state_kernel(
    const float* __restrict__ kn /*Zt*/, const float* __restrict__ Pbuf /*P[d][e]*/,
    float* __restrict__ Sbuf) {
  int bid = blockIdx.x;
  int js = bid & 3, h = (bid >> 2) & 15, b = bid >> 6;
  int bh = b * H_ + h;
  int lane = threadIdx.x & 63;   // d
  int jq = threadIdx.x >> 6;
  int j0 = js * 16 + jq * 4;
  float s[4] = {0.f, 0.f, 0.f, 0.f};
  float4 p[16], pn[16];
  {
    const float4* Prow = (const float4*)&Pbuf[(size_t)(bh * NC_) * 4096 + lane * 64];
    #pragma unroll
    for (int g = 0; g < 16; g++) p[g] = Prow[g];
  }
  for (int c = 0; c < NC_; c++) {
    size_t ch = (size_t)bh * NC_ + c;
    // store S_c (pre-update), coalesced 256B rows
    #pragma unroll
    for (int i = 0; i < 4; i++)
      Sbuf[ch * 4096 + (size_t)(j0 + i) * 64 + lane] = s[i];
    // prefetch next-chunk P row into registers
    if (c + 1 < NC_) {
      const float4* Prow = (const float4*)&Pbuf[(ch + 1) * 4096 + lane * 64];
      #pragma unroll
      for (int g = 0; g < 16; g++) pn[g] = Prow[g];
    }
    float acc[4];
    #pragma unroll
    for (int i = 0; i < 4; i++)
      acc[i] = kn[((size_t)(b * T_ + c * 64 + j0 + i)) * D_ + h * 64 + lane];
    #pragma unroll
    for (int e4 = 0; e4 < 16; e4++) {
      float4 pv = p[e4];
      #pragma unroll
      for (int i = 0; i < 4; i++) {
        float s0 = rdlane(s[i], e4 * 4 + 0);
        float s1 = rdlane(s[i], e4 * 4 + 1);
        float s2 = rdlane(s[i], e4 * 4 + 2);
        float s3 = rdlane(s[i], e4 * 4 + 3);
        acc[i] += pv.x * s0 + pv.y * s1 + pv.z * s2 + pv.w * s3;
      }
    }
    #pragma unroll
    for (int i = 0; i < 4; i++) s[i] = acc[i];
    if (c + 1 < NC_) {
      #pragma unroll
      for (int g = 0; g < 16; g++) p[g] = pn[g];
    }
  }
}

// ---------- O = O0 + Qeff*S_c (S transposed layout), fused RMSNorm + bf16 cast ----------
__global__ __launch_bounds__(256) void ophase_kernel(
    const float* __restrict__ qn /*Qeff*/, const float* __restrict__ Sbuf,
    const float* __restrict__ O0buf, const float* __restrict__ rms_g,
    ushort* __restrict__ ob) {
  __shared__ float Ssht[64][68];
  __shared__ float QshT[64][65];
  __shared__ float part[64][4];
  int ch = blockIdx.x;
  int b = ch >> 9, h = (ch >> 5) & 15, c = ch & 31;
  int tid = threadIdx.x;
  int t = tid & 63, jg = tid >> 6;
  #pragma unroll
  for (int g = 0; g < 4; g++) {
    int idx = tid + g * 256;
    *(float4*)&Ssht[idx >> 4][(idx & 15) * 4] =
        *(const float4*)&Sbuf[(size_t)ch * 4096 + (size_t)idx * 4];
  }
  #pragma unroll
  for (int g = 0; g < 4; g++) {
    int idx = tid + g * 256;
    int row = idx >> 4, c4 = idx & 15;
    float4 qv = *(const float4*)&qn[((size_t)(b * T_ + c * 64 + row)) * D_ + h * 64 + c4 * 4];
    QshT[c4 * 4 + 0][row] = qv.x;
    QshT[c4 * 4 + 1][row] = qv.y;
    QshT[c4 * 4 + 2][row] = qv.z;
    QshT[c4 * 4 + 3][row] = qv.w;
  }
  float o[16];
  #pragma unroll
  for (int g = 0; g < 4; g++) {
    float4 o4 = *(const float4*)&O0buf[(size_t)ch * 4096 + t * 64 + jg * 16 + g * 4];
    o[4*g+0] = o4.x; o[4*g+1] = o4.y; o[4*g+2] = o4.z; o[4*g+3] = o4.w;
  }
  __syncthreads();
  for (int d4 = 0; d4 < 16; d4++) {
    float q0 = QshT[d4 * 4 + 0][t];
    float q1 = QshT[d4 * 4 + 1][t];
    float q2 = QshT[d4 * 4 + 2][t];
    float q3 = QshT[d4 * 4 + 3][t];
    #pragma unroll
    for (int r = 0; r < 16; r++) {
      float4 s4 = *(float4*)&Ssht[jg * 16 + r][d4 * 4];
      o[r] += q0 * s4.x + q1 * s4.y + q2 * s4.z + q3 * s4.w;
    }
  }
  float ss = 0.f;
  #pragma unroll
  for (int r = 0; r < 16; r++) ss += o[r] * o[r];
  part[t][jg] = ss;
  __syncthreads();
  float tot = part[t][0] + part[t][1] + part[t][2] + part[t][3];
  float sc = rsqrtf(tot * (1.f / 64.f) + 1e-6f);
  ushort* orow = &ob[((size_t)(b * T_ + c * 64 + t)) * D_ + h * 64];
  #pragma unroll
  for (int g = 0; g < 4; g++) {
    float4 g4 = *(const float4*)&rms_g[jg * 16 + g * 4];
    ushort4 r4;
    r4.x = f2bf(o[4*g+0] * sc * g4.x); r4.y = f2bf(o[4*g+1] * sc * g4.y);
    r4.z = f2bf(o[4*g+2] * sc * g4.z); r4.w = f2bf(o[4*g+3] * sc * g4.w);
    *(ushort4*)&orow[jg * 16 + g * 4] = r4;
  }
}

extern "C" void kernel_launch(void* const* d_in, const int* in_sizes, int n_in,
                              void* d_out, int out_size, void* d_ws, size_t ws_size,
                              hipStream_t stream) {
  const float* x  = (const float*)d_in[0];
  const float* Wq = (const float*)d_in[1];
  const float* Wk = (const float*)d_in[2];
  const float* Wv = (const float*)d_in[3];
  const float* Wb = (const float*)d_in[4];
  const float* cq = (const float*)d_in[5];
  const float* ck = (const float*)d_in[6];
  const float* cv = (const float*)d_in[7];
  const float* rg = (const float*)d_in[8];
  const float* Wo = (const float*)d_in[9];
  float* out = (float*)d_out;
  char* ws = (char*)d_ws;
  const size_t MiB = 1ull << 20;
  ushort* xb   = (ushort*)(ws + 0);         // dead after QKV gemm
  ushort* Wqt  = (ushort*)(ws + 8 * MiB);   // Wqt/Wkt/Wvt contiguous = [3072][1024] bf16
  ushort* Wkt  = (ushort*)(ws + 10 * MiB);
  ushort* Wvt  = (ushort*)(ws + 12 * MiB);
  ushort* Wot  = (ushort*)(ws + 14 * MiB);  // live to end
  float* qkv   = (float*)(ws + 16 * MiB);   // [4096][3072] fp32, dead after conv
  float* qn    = (float*)(ws + 64 * MiB);   // then Qeff in-place
  float* kn    = (float*)(ws + 80 * MiB);   // then Zt in-place
  float* vn    = (float*)(ws + 96 * MiB);   // dead after prep1
  float* beta  = (float*)(ws + 112 * MiB);  // 256 KiB
  float* WbT   = (float*)(ws + 112 * MiB + 256 * 1024);  // 64 KiB
  float* Wkbuf = (float*)(ws + 16 * MiB);   // over qkv (dead after conv)
  float* U0buf = (float*)(ws + 32 * MiB);
  float* Lbuf  = (float*)(ws + 48 * MiB);   // later P
  float* O0buf = (float*)(ws + 96 * MiB);   // over vn (after prep1)
  float* Sbuf  = (float*)(ws + 16 * MiB);   // over Wkbuf (dead after prep2c)
  ushort* ob   = (ushort*)(ws + 0);         // over xb (after QKV gemm)

  hipLaunchKernelGGL(cast_kernel, dim3(M_ * D_ / 4 / 256), dim3(256), 0, stream,
                     x, xb, M_ * D_ / 4);
  dim3 tb(32, 8);
  hipLaunchKernelGGL(transpose_cast_kernel, dim3(32, 32), tb, 0, stream, Wq, Wqt, D_, D_);
  hipLaunchKernelGGL(transpose_cast_kernel, dim3(32, 32), tb, 0, stream, Wk, Wkt, D_, D_);
  hipLaunchKernelGGL(transpose_cast_kernel, dim3(32, 32), tb, 0, stream, Wv, Wvt, D_, D_);
  hipLaunchKernelGGL(transpose_cast_kernel, dim3(32, 32), tb, 0, stream, Wo, Wot, D_, D_);
  hipLaunchKernelGGL(transpose_wb_kernel, dim3(64), dim3(256), 0, stream, Wb, WbT);

  hipLaunchKernelGGL(gemm128_kernel, dim3(M_ / 128, QKVN_ / 128), dim3(256), 0, stream,
                     xb, Wqt, qkv, M_, QKVN_, D_);

  hipLaunchKernelGGL(beta_kernel, dim3(M_), dim3(256), 0, stream, x, WbT, beta);
  hipLaunchKernelGGL(conv_kernel, dim3(M_), dim3(256), 0, stream,
                     qkv, cq, ck, cv, qn, kn, vn);

  hipLaunchKernelGGL(prep1_kernel, dim3(NCH_), dim3(256), 0, stream,
                     kn, vn, beta, Wkbuf, U0buf);
  hipLaunchKernelGGL(prep2a_kernel, dim3(NCH_), dim3(256), 0, stream, qn, kn, Lbuf);
  hipLaunchKernelGGL(prep2b_kernel, dim3(NCH_), dim3(256), 0, stream,
                     Lbuf, Wkbuf, U0buf, qn, O0buf);
  hipLaunchKernelGGL(prep2c_kernel, dim3(NCH_), dim3(256), 0, stream,
                     kn, Wkbuf, U0buf, Lbuf);
  hipLaunchKernelGGL(state_kernel, dim3(B_ * H_ * 4), dim3(256), 0, stream,
                     kn, Lbuf, Sbuf);
  hipLaunchKernelGGL(ophase_kernel, dim3(NCH_), dim3(256), 0, stream,
                     qn, Sbuf, O0buf, rg, ob);
  hipLaunchKernelGGL(gemm128_kernel, dim3(M_ / 128, D_ / 128), dim3(256), 0, stream,
                     ob, Wot, out, M_, D_, D_);
}